// Round 20
// baseline (237.848 us; speedup 1.0000x reference)
//
#include <hip/hip_runtime.h>
#include <math.h>

#define L_SEQ 16384
#define DIM 256
#define NST 8
#define RNK 16
#define S_TOT 32768   // B*L
#define NCH 512
#define CLH 32

typedef __attribute__((ext_vector_type(8))) short bf16x8;
typedef __attribute__((ext_vector_type(4))) float f32x4;

__device__ __forceinline__ float bf2f(unsigned short u) {
  union { unsigned int i; float f; } v; v.i = ((unsigned int)u) << 16; return v.f;
}
__device__ __forceinline__ unsigned short f2bf(float x) {
  union { float f; unsigned int i; } v; v.f = x;
  unsigned int r = v.i + 0x7fffu + ((v.i >> 16) & 1u);
  return (unsigned short)(r >> 16);
}
__device__ __forceinline__ float rcpf(float x) {
  return __builtin_amdgcn_rcpf(x);
}

// ---- fused LayerNorm -> bf16 (wave/row, 4 rows/blk) + weight conversion ----
__global__ __launch_bounds__(256) void ln_norm(
    const float* __restrict__ in0, const float* __restrict__ in1,
    const float* __restrict__ w0, const float* __restrict__ b0,
    const float* __restrict__ w1, const float* __restrict__ b1,
    unsigned short* __restrict__ h0, unsigned short* __restrict__ h1,
    const float* __restrict__ pw0, const float* __restrict__ pw1,
    const float* __restrict__ pw2, unsigned short* __restrict__ wbout) {
  int which = blockIdx.y;
  if (which == 0 && blockIdx.x < 1024) {
    int i = blockIdx.x * 256 + threadIdx.x;
    if (i < 131072) wbout[i] = f2bf(pw0[i]);
    else if (i < 196608) wbout[i] = f2bf(pw1[i - 131072]);
    else wbout[i] = f2bf(pw2[i - 196608]);
  }
  int row = blockIdx.x * 4 + (threadIdx.x >> 6);
  int lane = threadIdx.x & 63;
  const float* x = (which ? in1 : in0) + (size_t)row * DIM;
  const float* w = which ? w1 : w0;
  const float* b = which ? b1 : b0;
  unsigned short* h = which ? h1 : h0;
  float4 v = *(const float4*)&x[lane * 4];
  float s = v.x + v.y + v.z + v.w;
  float s2 = v.x * v.x + v.y * v.y + v.z * v.z + v.w * v.w;
  for (int off = 32; off; off >>= 1) {
    s += __shfl_xor(s, off);
    s2 += __shfl_xor(s2, off);
  }
  float mean = s * (1.0f / DIM);
  float var = s2 * (1.0f / DIM) - mean * mean;
  float rstd = rsqrtf(var + 1e-5f);
  float4 wv = *(const float4*)&w[lane * 4];
  float4 bv = *(const float4*)&b[lane * 4];
  ushort4 out;
  out.x = f2bf((v.x - mean) * rstd * wv.x + bv.x);
  out.y = f2bf((v.y - mean) * rstd * wv.y + bv.y);
  out.z = f2bf((v.z - mean) * rstd * wv.z + bv.z);
  out.w = f2bf((v.w - mean) * rstd * wv.w + bv.w);
  *(ushort4*)&h[(size_t)row * DIM + lane * 4] = out;
}

// ------- streaming bf16 GEMM, 64x64 tile, full K=256 staged once -------
template <int BF16C, int ADDIN>
__global__ __launch_bounds__(256) void gemm64(
    const unsigned short* __restrict__ A, int lda,
    const unsigned short* __restrict__ Wb,
    void* __restrict__ Cv, const float* __restrict__ addp, int Nn) {
  __shared__ unsigned short As[64 * 256];
  __shared__ unsigned short Ws[64 * 256];
  int tid = threadIdx.x;
  int n0 = blockIdx.x * 64, m0 = blockIdx.y * 64;
  for (int i = 0; i < 8; ++i) {
    int f8 = tid + i * 256;
    int r = f8 >> 5, c8 = (f8 & 31) * 8;
    int sc = c8 ^ ((r & 7) << 3);
    *(uint4*)&As[r * 256 + sc] = *(const uint4*)&A[(size_t)(m0 + r) * lda + c8];
    *(uint4*)&Ws[r * 256 + sc] = *(const uint4*)&Wb[(size_t)(n0 + r) * 256 + c8];
  }
  __syncthreads();
  int wid = tid >> 6, lane = tid & 63;
  int wm = wid >> 1, wn = wid & 1;
  int l15 = lane & 15, lk = (lane >> 4) * 8;
  f32x4 acc[2][2] = {};
  for (int ks = 0; ks < 8; ++ks) {
    int kcol = ks * 32 + lk;
    bf16x8 af[2], bf_[2];
    for (int mf = 0; mf < 2; ++mf) {
      int row = wm * 32 + mf * 16 + l15;
      af[mf] = *(const bf16x8*)&As[row * 256 + (kcol ^ ((row & 7) << 3))];
    }
    for (int nf = 0; nf < 2; ++nf) {
      int row = wn * 32 + nf * 16 + l15;
      bf_[nf] = *(const bf16x8*)&Ws[row * 256 + (kcol ^ ((row & 7) << 3))];
    }
    for (int mf = 0; mf < 2; ++mf)
      for (int nf = 0; nf < 2; ++nf)
        acc[mf][nf] = __builtin_amdgcn_mfma_f32_16x16x32_bf16(
            af[mf], bf_[nf], acc[mf][nf], 0, 0, 0);
  }
  for (int mf = 0; mf < 2; ++mf)
    for (int nf = 0; nf < 2; ++nf) {
      int row = m0 + wm * 32 + mf * 16 + (lane >> 4) * 4;
      int col = n0 + wn * 32 + nf * 16 + l15;
      for (int v = 0; v < 4; ++v) {
        size_t off = (size_t)(row + v) * Nn + col;
        float val = acc[mf][nf][v];
        if (ADDIN) val += addp[off];
        if (BF16C) ((unsigned short*)Cv)[off] = f2bf(val);
        else       ((float*)Cv)[off] = val;
      }
    }
}

// ---- merged input GEMMs: blocks x<4 -> xe = h1@wb_ex^T; x>=4 -> xz = h0@wb_in^T
__global__ __launch_bounds__(256) void gemm_in(
    const unsigned short* __restrict__ h0, const unsigned short* __restrict__ h1,
    const unsigned short* __restrict__ wb_in, const unsigned short* __restrict__ wb_ex,
    unsigned short* __restrict__ xzOut, unsigned short* __restrict__ xeOut) {
  __shared__ unsigned short As[64 * 256];
  __shared__ unsigned short Ws[64 * 256];
  int tid = threadIdx.x;
  bool isX = blockIdx.x >= 4;
  const unsigned short* A = isX ? h0 : h1;
  const unsigned short* Wb = isX ? wb_in : wb_ex;
  unsigned short* Cv = isX ? xzOut : xeOut;
  int Nn = isX ? 512 : 256;
  int n0 = (isX ? (int)blockIdx.x - 4 : (int)blockIdx.x) * 64;
  int m0 = blockIdx.y * 64;
  for (int i = 0; i < 8; ++i) {
    int f8 = tid + i * 256;
    int r = f8 >> 5, c8 = (f8 & 31) * 8;
    int sc = c8 ^ ((r & 7) << 3);
    *(uint4*)&As[r * 256 + sc] = *(const uint4*)&A[(size_t)(m0 + r) * 256 + c8];
    *(uint4*)&Ws[r * 256 + sc] = *(const uint4*)&Wb[(size_t)(n0 + r) * 256 + c8];
  }
  __syncthreads();
  int wid = tid >> 6, lane = tid & 63;
  int wm = wid >> 1, wn = wid & 1;
  int l15 = lane & 15, lk = (lane >> 4) * 8;
  f32x4 acc[2][2] = {};
  for (int ks = 0; ks < 8; ++ks) {
    int kcol = ks * 32 + lk;
    bf16x8 af[2], bf_[2];
    for (int mf = 0; mf < 2; ++mf) {
      int row = wm * 32 + mf * 16 + l15;
      af[mf] = *(const bf16x8*)&As[row * 256 + (kcol ^ ((row & 7) << 3))];
    }
    for (int nf = 0; nf < 2; ++nf) {
      int row = wn * 32 + nf * 16 + l15;
      bf_[nf] = *(const bf16x8*)&Ws[row * 256 + (kcol ^ ((row & 7) << 3))];
    }
    for (int mf = 0; mf < 2; ++mf)
      for (int nf = 0; nf < 2; ++nf)
        acc[mf][nf] = __builtin_amdgcn_mfma_f32_16x16x32_bf16(
            af[mf], bf_[nf], acc[mf][nf], 0, 0, 0);
  }
  for (int mf = 0; mf < 2; ++mf)
    for (int nf = 0; nf < 2; ++nf) {
      int row = m0 + wm * 32 + mf * 16 + (lane >> 4) * 4;
      int col = n0 + wn * 32 + nf * 16 + l15;
      for (int v = 0; v < 4; ++v) {
        size_t off = (size_t)(row + v) * Nn + col;
        Cv[off] = f2bf(acc[mf][nf][v]);
      }
    }
}

// ---- fused: combine (yf+yb)/2 -> LN -> *silu(z) in A-staging, then GEMM+res
__global__ __launch_bounds__(256) void gemm_out_fused(
    const unsigned short* __restrict__ ycomb,
    const unsigned short* __restrict__ ybu,
    const unsigned short* __restrict__ xz,
    const float* __restrict__ onw, const float* __restrict__ onb,
    const unsigned short* __restrict__ Wb,
    float* __restrict__ outp, const float* __restrict__ addp) {
  __shared__ unsigned short As[64 * 256];
  __shared__ unsigned short Ws[64 * 256];
  __shared__ float muS[64], rsS[64];
  int tid = threadIdx.x;
  int n0 = blockIdx.x * 64, m0 = blockIdx.y * 64;
  // stage Ws + phase A: v = (yf+yb)/2, row stats, pack v into As
  for (int i = 0; i < 8; ++i) {
    int f8 = tid + i * 256;
    int r = f8 >> 5, c8 = (f8 & 31) * 8;
    int sc = c8 ^ ((r & 7) << 3);
    *(uint4*)&Ws[r * 256 + sc] = *(const uint4*)&Wb[(size_t)(n0 + r) * 256 + c8];
    int m = m0 + r;
    int b = m >> 14, l = m & (L_SEQ - 1);
    const unsigned short* pf = &ycomb[(size_t)m * DIM + c8];
    const unsigned short* pb =
        &ybu[((size_t)S_TOT + ((size_t)b << 14) + (L_SEQ - 1 - l)) * DIM + c8];
    ushort4 f0 = *(const ushort4*)pf, f1 = *(const ushort4*)(pf + 4);
    ushort4 b0 = *(const ushort4*)pb, b1 = *(const ushort4*)(pb + 4);
    float v[8];
    v[0] = 0.5f * (bf2f(f0.x) + bf2f(b0.x));
    v[1] = 0.5f * (bf2f(f0.y) + bf2f(b0.y));
    v[2] = 0.5f * (bf2f(f0.z) + bf2f(b0.z));
    v[3] = 0.5f * (bf2f(f0.w) + bf2f(b0.w));
    v[4] = 0.5f * (bf2f(f1.x) + bf2f(b1.x));
    v[5] = 0.5f * (bf2f(f1.y) + bf2f(b1.y));
    v[6] = 0.5f * (bf2f(f1.z) + bf2f(b1.z));
    v[7] = 0.5f * (bf2f(f1.w) + bf2f(b1.w));
    float s = 0.f, s2 = 0.f;
    for (int j = 0; j < 8; ++j) { s += v[j]; s2 += v[j] * v[j]; }
    for (int off = 16; off; off >>= 1) {   // 32-lane row-group (within wave)
      s += __shfl_xor(s, off);
      s2 += __shfl_xor(s2, off);
    }
    if ((tid & 31) == 0) {
      float mean = s * (1.0f / DIM);
      float var = s2 * (1.0f / DIM) - mean * mean;
      muS[r] = mean;
      rsS[r] = rsqrtf(var + 1e-5f);
    }
    uint4 pk;
    pk.x = (unsigned int)f2bf(v[0]) | ((unsigned int)f2bf(v[1]) << 16);
    pk.y = (unsigned int)f2bf(v[2]) | ((unsigned int)f2bf(v[3]) << 16);
    pk.z = (unsigned int)f2bf(v[4]) | ((unsigned int)f2bf(v[5]) << 16);
    pk.w = (unsigned int)f2bf(v[6]) | ((unsigned int)f2bf(v[7]) << 16);
    *(uint4*)&As[r * 256 + sc] = pk;
  }
  __syncthreads();
  // phase B: apply LN * silu(z) to own entries
  for (int i = 0; i < 8; ++i) {
    int f8 = tid + i * 256;
    int r = f8 >> 5, c8 = (f8 & 31) * 8;
    int sc = c8 ^ ((r & 7) << 3);
    int m = m0 + r;
    uint4 pk = *(const uint4*)&As[r * 256 + sc];
    float v[8];
    v[0] = bf2f((unsigned short)(pk.x & 0xffff));
    v[1] = bf2f((unsigned short)(pk.x >> 16));
    v[2] = bf2f((unsigned short)(pk.y & 0xffff));
    v[3] = bf2f((unsigned short)(pk.y >> 16));
    v[4] = bf2f((unsigned short)(pk.z & 0xffff));
    v[5] = bf2f((unsigned short)(pk.z >> 16));
    v[6] = bf2f((unsigned short)(pk.w & 0xffff));
    v[7] = bf2f((unsigned short)(pk.w >> 16));
    const unsigned short* pz = &xz[(size_t)m * 512 + 256 + c8];
    ushort4 z0 = *(const ushort4*)pz, z1 = *(const ushort4*)(pz + 4);
    float zf[8] = {bf2f(z0.x), bf2f(z0.y), bf2f(z0.z), bf2f(z0.w),
                   bf2f(z1.x), bf2f(z1.y), bf2f(z1.z), bf2f(z1.w)};
    float4 w0 = *(const float4*)&onw[c8];
    float4 w1 = *(const float4*)&onw[c8 + 4];
    float4 bb0 = *(const float4*)&onb[c8];
    float4 bb1 = *(const float4*)&onb[c8 + 4];
    float wv[8] = {w0.x, w0.y, w0.z, w0.w, w1.x, w1.y, w1.z, w1.w};
    float bv[8] = {bb0.x, bb0.y, bb0.z, bb0.w, bb1.x, bb1.y, bb1.z, bb1.w};
    float mean = muS[r], rstd = rsS[r];
    unsigned int o[4];
    for (int jj = 0; jj < 4; ++jj) {
      int j0 = jj * 2, j1 = jj * 2 + 1;
      float ln0 = (v[j0] - mean) * rstd * wv[j0] + bv[j0];
      float ln1 = (v[j1] - mean) * rstd * wv[j1] + bv[j1];
      float g0 = ln0 * (zf[j0] * rcpf(1.f + __expf(-zf[j0])));
      float g1 = ln1 * (zf[j1] * rcpf(1.f + __expf(-zf[j1])));
      o[jj] = (unsigned int)f2bf(g0) | ((unsigned int)f2bf(g1) << 16);
    }
    uint4 w4; w4.x = o[0]; w4.y = o[1]; w4.z = o[2]; w4.w = o[3];
    *(uint4*)&As[r * 256 + sc] = w4;
  }
  __syncthreads();
  int wid = tid >> 6, lane = tid & 63;
  int wm = wid >> 1, wn = wid & 1;
  int l15 = lane & 15, lk = (lane >> 4) * 8;
  f32x4 acc[2][2] = {};
  for (int ks = 0; ks < 8; ++ks) {
    int kcol = ks * 32 + lk;
    bf16x8 af[2], bf_[2];
    for (int mf = 0; mf < 2; ++mf) {
      int row = wm * 32 + mf * 16 + l15;
      af[mf] = *(const bf16x8*)&As[row * 256 + (kcol ^ ((row & 7) << 3))];
    }
    for (int nf = 0; nf < 2; ++nf) {
      int row = wn * 32 + nf * 16 + l15;
      bf_[nf] = *(const bf16x8*)&Ws[row * 256 + (kcol ^ ((row & 7) << 3))];
    }
    for (int mf = 0; mf < 2; ++mf)
      for (int nf = 0; nf < 2; ++nf)
        acc[mf][nf] = __builtin_amdgcn_mfma_f32_16x16x32_bf16(
            af[mf], bf_[nf], acc[mf][nf], 0, 0, 0);
  }
  for (int mf = 0; mf < 2; ++mf)
    for (int nf = 0; nf < 2; ++nf) {
      int row = m0 + wm * 32 + mf * 16 + (lane >> 4) * 4;
      int col = n0 + wn * 32 + nf * 16 + l15;
      for (int v = 0; v < 4; ++v) {
        size_t off = (size_t)(row + v) * 256 + col;
        outp[off] = acc[mf][nf][v] + addp[off];
      }
    }
}

// -------- conv(xe)+silu -> MFMA projection to dbl(32) bf16, 64 rows/block --
__global__ __launch_bounds__(256) void xproj_mfma(
    const unsigned short* __restrict__ xe,
    const float* __restrict__ conve_w, const float* __restrict__ conve_b,
    const float* __restrict__ conve_w_r, const float* __restrict__ conve_b_r,
    const float* __restrict__ xproj_w, const float* __restrict__ xproj_w_r,
    unsigned short* __restrict__ dbl2) {
  __shared__ unsigned short ecS[64 * 256];
  __shared__ unsigned short xwS[32 * 256];
  int chunk = blockIdx.x;
  int dir = blockIdx.y;
  int b = chunk >> 8;
  int t0 = (chunk & 255) * 64;
  int tid = threadIdx.x;
  const float* cw = dir ? conve_w_r : conve_w;
  const float* cb = dir ? conve_b_r : conve_b;
  const float* xw = dir ? xproj_w_r : xproj_w;

  for (int i = tid; i < 32 * 256; i += 256) {
    int o = i >> 8, dd = i & 255;
    xwS[o * 256 + (((dd & ~7) ^ ((o & 7) << 3)) | (dd & 7))] = f2bf(xw[i]);
  }

  {
    int c = tid;
    float w0 = cw[c * 4 + 0], w1 = cw[c * 4 + 1], w2 = cw[c * 4 + 2],
          w3 = cw[c * 4 + 3], bias = cb[c];
    size_t bL = (size_t)b * L_SEQ;
    auto loadx = [&](int t) -> float {
      if (t < 0) return 0.f;
      int src = dir ? (L_SEQ - 1 - t) : t;
      return bf2f(xe[(bL + src) * DIM + c]);
    };
    float xm3 = loadx(t0 - 3), xm2 = loadx(t0 - 2), xm1 = loadx(t0 - 1);
    const unsigned short* xp =
        &xe[(bL + (dir ? (L_SEQ - 1 - t0) : t0)) * DIM + c];
    int xstep = dir ? -DIM : DIM;
    int cbase = c & ~7, clow = c & 7;
    for (int t4 = 0; t4 < 64; t4 += 4) {
      float xin4[4];
      for (int j = 0; j < 4; ++j) xin4[j] = bf2f(xp[(ptrdiff_t)j * xstep]);
      xp += (ptrdiff_t)4 * xstep;
      for (int j = 0; j < 4; ++j) {
        int tl = t4 + j;
        float xin = xin4[j];
        float pre = w0 * xm3 + w1 * xm2 + w2 * xm1 + w3 * xin + bias;
        float u = pre * rcpf(1.f + __expf(-pre));
        xm3 = xm2; xm2 = xm1; xm1 = xin;
        ecS[tl * 256 + ((cbase ^ ((tl & 7) << 3)) | clow)] = f2bf(u);
      }
    }
  }
  __syncthreads();

  int wid = tid >> 6, lane = tid & 63;
  int l15 = lane & 15, lk = (lane >> 4) * 8;
  f32x4 acc[2] = {};
  for (int kk = 0; kk < 8; ++kk) {
    int kcol = kk * 32 + lk;
    int row = wid * 16 + l15;
    bf16x8 af = *(const bf16x8*)&ecS[row * 256 + (kcol ^ ((row & 7) << 3))];
    for (int ni = 0; ni < 2; ++ni) {
      int o = ni * 16 + l15;
      bf16x8 bfr = *(const bf16x8*)&xwS[o * 256 + (kcol ^ ((o & 7) << 3))];
      acc[ni] = __builtin_amdgcn_mfma_f32_16x16x32_bf16(af, bfr, acc[ni], 0, 0, 0);
    }
  }
  size_t mbase = (size_t)dir * S_TOT + (size_t)chunk * 64;
  int rloc = wid * 16 + (lane >> 4) * 4;
  for (int ni = 0; ni < 2; ++ni) {
    int o = ni * 16 + l15;
    for (int v = 0; v < 4; ++v)
      dbl2[(mbase + rloc + v) * 32 + o] = f2bf(acc[ni][v]);
  }
}

// ---- merged: blocks 0..1023 = dt_mfma; blocks 1024..2047 = u_compute ------
__global__ __launch_bounds__(256) void dtu_compute(
    const unsigned short* __restrict__ dbl2,
    const float* __restrict__ dtw, const float* __restrict__ dtw_r,
    const float* __restrict__ dtb, const float* __restrict__ dtb_r,
    unsigned short* __restrict__ dt_arr,
    const unsigned short* __restrict__ xz,
    const float* __restrict__ convx_w, const float* __restrict__ convx_b,
    const float* __restrict__ convx_w_r, const float* __restrict__ convx_b_r,
    unsigned short* __restrict__ u_arr) {
  __shared__ unsigned short dtwS[256 * 32];
  __shared__ unsigned short dtrS[64 * 32];
  __shared__ unsigned short outS[64 * 256];
  int tid = threadIdx.x;
  if (blockIdx.x < 1024) {
    int m0 = blockIdx.x * 64;
    int dir = (blockIdx.x >= 512) ? 1 : 0;
    const float* dw = dir ? dtw_r : dtw;
    const float* db = dir ? dtb_r : dtb;
    {
      uint4 z; z.x = 0; z.y = 0; z.z = 0; z.w = 0;
      for (int i = tid; i < 1280; i += 256) {
        if (i < 1024) ((uint4*)dtwS)[i] = z;
        else          ((uint4*)dtrS)[i - 1024] = z;
      }
    }
    __syncthreads();
    for (int it = 0; it < 4; ++it) {
      int idx = tid + it * 256;
      int c = idx >> 2, k4 = idx & 3;
      float4 v = *(const float4*)&dw[c * 16 + k4 * 4];
      uint2 pk;
      pk.x = (unsigned int)f2bf(v.x) | ((unsigned int)f2bf(v.y) << 16);
      pk.y = (unsigned int)f2bf(v.z) | ((unsigned int)f2bf(v.w) << 16);
      int byte = c * 64 + (((k4 >> 1) ^ (c & 3)) << 4) + ((k4 & 1) << 3);
      *(uint2*)((char*)dtwS + byte) = pk;
    }
    {
      int r = tid >> 2, k4 = tid & 3;
      uint2 pk = *(const uint2*)&dbl2[(size_t)(m0 + r) * 32 + k4 * 4];
      int byte = r * 64 + (((k4 >> 1) ^ (r & 3)) << 4) + ((k4 & 1) << 3);
      *(uint2*)((char*)dtrS + byte) = pk;
    }
    __syncthreads();
    int wid = tid >> 6, lane = tid & 63;
    int l15 = lane & 15, lkc = lane >> 4;
    bf16x8 af[4];
    for (int mi = 0; mi < 4; ++mi) {
      int r = mi * 16 + l15;
      af[mi] = *(const bf16x8*)((char*)dtrS + r * 64 + ((lkc ^ (r & 3)) << 4));
    }
    f32x4 acc[4][4] = {};
    for (int ni = 0; ni < 4; ++ni) {
      int c = (wid * 4 + ni) * 16 + l15;
      bf16x8 bfr = *(const bf16x8*)((char*)dtwS + c * 64 + ((lkc ^ (c & 3)) << 4));
      for (int mi = 0; mi < 4; ++mi)
        acc[mi][ni] = __builtin_amdgcn_mfma_f32_16x16x32_bf16(
            af[mi], bfr, acc[mi][ni], 0, 0, 0);
    }
    for (int ni = 0; ni < 4; ++ni) {
      int c = (wid * 4 + ni) * 16 + l15;
      float bias_ = db[c];
      int cb_ = c & ~7, cl_ = c & 7;
      for (int mi = 0; mi < 4; ++mi) {
        int rb = mi * 16 + (lane >> 4) * 4;
        for (int v = 0; v < 4; ++v) {
          int r = rb + v;
          float xdt = acc[mi][ni][v] + bias_;
          float dtv = (xdt > 15.f) ? xdt : __logf(1.f + __expf(xdt));
          outS[r * 256 + ((cb_ ^ ((r & 7) << 3)) | cl_)] = f2bf(dtv);
        }
      }
    }
    __syncthreads();
    for (int it = 0; it < 8; ++it) {
      int i = tid + it * 256;
      int r = i >> 5, cg = (i & 31) * 8;
      uint4 val = *(const uint4*)&outS[r * 256 + (cg ^ ((r & 7) << 3))];
      *(uint4*)&dt_arr[(size_t)(m0 + r) * 256 + cg] = val;
    }
  } else {
    int chunk = blockIdx.x - 1024;
    int b = chunk >> 9;
    int t0 = (chunk & 511) * 32;
    int c = tid;
    float w0 = convx_w[c * 4 + 0], w1 = convx_w[c * 4 + 1],
          w2 = convx_w[c * 4 + 2], w3 = convx_w[c * 4 + 3], bias = convx_b[c];
    float w0r = convx_w_r[c * 4 + 0], w1r = convx_w_r[c * 4 + 1],
          w2r = convx_w_r[c * 4 + 2], w3r = convx_w_r[c * 4 + 3],
          biasr = convx_b_r[c];
    size_t bL = (size_t)b * L_SEQ;
    auto ld = [&](int t) -> float {
      if (t < 0 || t >= L_SEQ) return 0.f;
      return bf2f(xz[(bL + t) * 512 + c]);
    };
    float x3 = ld(t0 - 3), x2 = ld(t0 - 2), x1 = ld(t0 - 1);
    unsigned short* op0 = &u_arr[(bL + t0) * DIM + c];
    unsigned short* op1 =
        &u_arr[((size_t)S_TOT + bL + (L_SEQ - 1 - t0)) * DIM + c];
    for (int tg = 0; tg < 36; tg += 4) {
      float xin4[4];
      for (int j = 0; j < 4; ++j) xin4[j] = ld(t0 + tg + j);
      for (int j = 0; j < 4; ++j) {
        int tl = tg + j;
        float xin = xin4[j];
        if (tl < 32) {
          float pre = w0 * x3 + w1 * x2 + w2 * x1 + w3 * xin + bias;
          op0[(size_t)tl * DIM] = f2bf(pre * rcpf(1.f + __expf(-pre)));
        }
        if (tl >= 3 && tl < 35) {
          float prer = w0r * xin + w1r * x1 + w2r * x2 + w3r * x3 + biasr;
          int s = tl - 3;
          *(op1 - (ptrdiff_t)s * DIM) = f2bf(prer * rcpf(1.f + __expf(-prer)));
        }
        x3 = x2; x2 = x1; x1 = xin;
      }
    }
  }
}

// dA[0..7] = exp(dtv*Ar[n]); FASTA: Ar[n] == -(n+1) verified
#define DA8(FASTA)                                                    \
  float dA[NST];                                                      \
  if (FASTA) {                                                        \
    float e1 = __expf(-dtv);                                          \
    dA[0] = e1;                                                       \
    for (int n = 1; n < NST; ++n) dA[n] = dA[n - 1] * e1;             \
  } else {                                                            \
    for (int n = 0; n < NST; ++n) dA[n] = __expf(dtv * Ar[n]);        \
  }

// ---------------- scan pass 1: per-chunk affine summaries ----------------
template <int USE_UDT>
__global__ __launch_bounds__(256) void scan_pass1(
    const unsigned short* __restrict__ xz, const unsigned short* __restrict__ dbl2,
    const unsigned short* __restrict__ u_arr,
    const unsigned short* __restrict__ dt_arr,
    const float* __restrict__ convx_w, const float* __restrict__ convx_b,
    const float* __restrict__ convx_w_r, const float* __restrict__ convx_b_r,
    const float* __restrict__ dtproj_w, const float* __restrict__ dtproj_b,
    const float* __restrict__ dtproj_w_r, const float* __restrict__ dtproj_b_r,
    const float* __restrict__ A_log, const float* __restrict__ A_log_r,
    float* __restrict__ Pc, float* __restrict__ Qc) {
  int chunk = blockIdx.x, b = blockIdx.y, dir = blockIdx.z;
  int d = threadIdx.x;
  const float* al = dir ? A_log_r : A_log;
  float w0 = 0.f, w1 = 0.f, w2 = 0.f, w3 = 0.f, bias = 0.f, dbias = 0.f;
  float dwreg[RNK];
  if (!USE_UDT) {
    const float* cw = dir ? convx_w_r : convx_w;
    const float* cb = dir ? convx_b_r : convx_b;
    const float* dw = dir ? dtproj_w_r : dtproj_w;
    const float* dbp = dir ? dtproj_b_r : dtproj_b;
    w0 = cw[d * 4 + 0]; w1 = cw[d * 4 + 1]; w2 = cw[d * 4 + 2];
    w3 = cw[d * 4 + 3]; bias = cb[d]; dbias = dbp[d];
    for (int r = 0; r < RNK; ++r) dwreg[r] = dw[d * RNK + r];
  }
  float Ar[NST];
  bool fa = true;
  for (int n = 0; n < NST; ++n) {
    Ar[n] = -__expf(al[d * NST + n]);
    fa = fa && (fabsf(Ar[n] + (float)(n + 1)) < 1e-4f * (float)(n + 1));
  }
  bool fastA = (__ballot(fa) == ~0ULL);

  __shared__ float dblS[CLH][32];
  int t0 = chunk * CLH;
  size_t dtbase = (size_t)dir * S_TOT + (size_t)b * L_SEQ;
  if (USE_UDT) {
    int i = d;
    dblS[i >> 3][i & 7] =
        bf2f(dbl2[(dtbase + t0 + (i >> 3)) * 32 + 16 + (i & 7)]);
  } else {
    for (int i = d; i < CLH * 32; i += 256)
      dblS[i >> 5][i & 31] = bf2f(dbl2[(dtbase + t0) * 32 + i]);
  }
  __syncthreads();
  auto loadx = [&](int t) -> float {
    if (t < 0) return 0.f;
    int srct = dir ? (L_SEQ - 1 - t) : t;
    return bf2f(xz[((size_t)b * L_SEQ + srct) * 512 + d]);
  };
  float xm3 = 0.f, xm2 = 0.f, xm1 = 0.f;
  if (!USE_UDT) { xm3 = loadx(t0 - 3); xm2 = loadx(t0 - 2); xm1 = loadx(t0 - 1); }
  const unsigned short* up = &u_arr[(dtbase + t0) * DIM + d];
  const unsigned short* dtp = &dt_arr[(dtbase + t0) * DIM + d];
  float Q[NST];
  for (int n = 0; n < NST; ++n) Q[n] = 0.f;
  float sdt = 0.f;
  const int BOFF = USE_UDT ? 0 : 16;

#define P1_GRP(FASTA)                                                      \
  for (int t8 = 0; t8 < CLH; t8 += 8) {                                    \
    float uu[8], dd[8];                                                    \
    for (int j = 0; j < 8; ++j) {                                          \
      uu[j] = bf2f(up[(size_t)j * DIM]);                                   \
      dd[j] = bf2f(dtp[(size_t)j * DIM]);                                  \
    }                                                                      \
    up += 8 * DIM; dtp += 8 * DIM;                                         \
    for (int j = 0; j < 8; ++j) {                                          \
      const float* row = dblS[t8 + j];                                     \
      float u = uu[j], dtv = dd[j];                                        \
      float du = dtv * u;                                                  \
      sdt += dtv;                                                          \
      DA8(FASTA)                                                           \
      float4 B0 = *(const float4*)(row);                                   \
      float4 B1 = *(const float4*)(row + 4);                               \
      Q[0] = dA[0] * Q[0] + du * B0.x; Q[1] = dA[1] * Q[1] + du * B0.y;    \
      Q[2] = dA[2] * Q[2] + du * B0.z; Q[3] = dA[3] * Q[3] + du * B0.w;    \
      Q[4] = dA[4] * Q[4] + du * B1.x; Q[5] = dA[5] * Q[5] + du * B1.y;    \
      Q[6] = dA[6] * Q[6] + du * B1.z; Q[7] = dA[7] * Q[7] + du * B1.w;    \
    }                                                                      \
  }

#define P1_STEP(FASTA)                                                     \
  {                                                                        \
    const float* row = dblS[tl];                                           \
    float u, dtv;                                                          \
    {                                                                      \
      float xin = loadx(t0 + tl);                                          \
      float pre = w0 * xm3 + w1 * xm2 + w2 * xm1 + w3 * xin + bias;        \
      u = pre * rcpf(1.f + __expf(-pre));                                  \
      xm3 = xm2; xm2 = xm1; xm1 = xin;                                     \
      float4 q0 = *(const float4*)(row);                                   \
      float4 q1 = *(const float4*)(row + 4);                               \
      float4 q2 = *(const float4*)(row + 8);                               \
      float4 q3 = *(const float4*)(row + 12);                              \
      float xdt = dbias + q0.x * dwreg[0] + q0.y * dwreg[1] +              \
                  q0.z * dwreg[2] + q0.w * dwreg[3] + q1.x * dwreg[4] +    \
                  q1.y * dwreg[5] + q1.z * dwreg[6] + q1.w * dwreg[7] +    \
                  q2.x * dwreg[8] + q2.y * dwreg[9] + q2.z * dwreg[10] +   \
                  q2.w * dwreg[11] + q3.x * dwreg[12] + q3.y * dwreg[13] + \
                  q3.z * dwreg[14] + q3.w * dwreg[15];                     \
      dtv = (xdt > 15.f) ? xdt : __logf(1.f + __expf(xdt));                \
    }                                                                      \
    float du = dtv * u;                                                    \
    sdt += dtv;                                                            \
    DA8(FASTA)                                                             \
    float4 B0 = *(const float4*)(row + BOFF);                              \
    float4 B1 = *(const float4*)(row + BOFF + 4);                          \
    Q[0] = dA[0] * Q[0] + du * B0.x; Q[1] = dA[1] * Q[1] + du * B0.y;      \
    Q[2] = dA[2] * Q[2] + du * B0.z; Q[3] = dA[3] * Q[3] + du * B0.w;      \
    Q[4] = dA[4] * Q[4] + du * B1.x; Q[5] = dA[5] * Q[5] + du * B1.y;      \
    Q[6] = dA[6] * Q[6] + du * B1.z; Q[7] = dA[7] * Q[7] + du * B1.w;      \
  }

  if (USE_UDT) {
    if (fastA) { P1_GRP(1) } else { P1_GRP(0) }
  } else {
    if (fastA) {
      for (int tl = 0; tl < CLH; ++tl) P1_STEP(1)
    } else {
      for (int tl = 0; tl < CLH; ++tl) P1_STEP(0)
    }
  }
#undef P1_STEP
#undef P1_GRP

  float P[NST];
  if (fastA) {
    float E = __expf(-sdt);
    P[0] = E;
    for (int n = 1; n < NST; ++n) P[n] = P[n - 1] * E;
  } else {
    for (int n = 0; n < NST; ++n) P[n] = __expf(Ar[n] * sdt);
  }
  size_t obase = ((((size_t)(dir * 2 + b)) * NCH + chunk) * DIM + d) * NST;
  for (int n = 0; n < NST; ++n) { Pc[obase + n] = P[n]; Qc[obase + n] = Q[n]; }
}

// -------- scan mid: sequential over chunk summaries; Hinit in-place in Pc --
__global__ __launch_bounds__(256) void scan_mid(
    float* __restrict__ Pc, const float* __restrict__ Qc) {
  int idx = blockIdx.x * 256 + threadIdx.x;
  int dn = idx & 2047;
  int db_ = idx >> 11;
  size_t base = (size_t)db_ * NCH * 2048 + dn;
  float h = 0.f;
  for (int c0 = 0; c0 < NCH; c0 += 8) {
    size_t off = base + (size_t)c0 * 2048;
    float P[8], Q[8];
#pragma unroll
    for (int j = 0; j < 8; ++j) {
      P[j] = Pc[off + (size_t)j * 2048];
      Q[j] = Qc[off + (size_t)j * 2048];
    }
#pragma unroll
    for (int j = 0; j < 8; ++j) {
      Pc[off + (size_t)j * 2048] = h;
      h = P[j] * h + Q[j];
    }
  }
}

// ---------------- scan pass 2 ----------------
template <int MODE>
__global__ __launch_bounds__(256) void scan_pass2(
    const unsigned short* __restrict__ xz, const unsigned short* __restrict__ dbl2,
    unsigned short* __restrict__ u_arr,
    const unsigned short* __restrict__ dt_arr,
    const float* __restrict__ convx_w, const float* __restrict__ convx_b,
    const float* __restrict__ convx_w_r, const float* __restrict__ convx_b_r,
    const float* __restrict__ dtproj_w, const float* __restrict__ dtproj_b,
    const float* __restrict__ dtproj_w_r, const float* __restrict__ dtproj_b_r,
    const float* __restrict__ A_log, const float* __restrict__ A_log_r,
    const float* __restrict__ Dp, const float* __restrict__ Dp_r,
    const float* __restrict__ Hinit, unsigned short* __restrict__ ycomb,
    int dirParam) {
  int chunk = blockIdx.x, b = blockIdx.y;
  int dir = MODE ? blockIdx.z : dirParam;
  int d = threadIdx.x;
  const float* al = dir ? A_log_r : A_log;
  float Dv = (dir ? Dp_r : Dp)[d];
  float w0 = 0.f, w1 = 0.f, w2 = 0.f, w3 = 0.f, bias = 0.f, dbias = 0.f;
  float dwreg[RNK];
  if (!MODE) {
    const float* cw = dir ? convx_w_r : convx_w;
    const float* cb = dir ? convx_b_r : convx_b;
    const float* dw = dir ? dtproj_w_r : dtproj_w;
    const float* dbp = dir ? dtproj_b_r : dtproj_b;
    w0 = cw[d * 4 + 0]; w1 = cw[d * 4 + 1]; w2 = cw[d * 4 + 2];
    w3 = cw[d * 4 + 3]; bias = cb[d];
    dbias = dbp[d];
    for (int r = 0; r < RNK; ++r) dwreg[r] = dw[d * RNK + r];
  }
  float Ar[NST];
  bool fa = true;
  for (int n = 0; n < NST; ++n) {
    Ar[n] = -__expf(al[d * NST + n]);
    fa = fa && (fabsf(Ar[n] + (float)(n + 1)) < 1e-4f * (float)(n + 1));
  }
  bool fastA = (__ballot(fa) == ~0ULL);

  __shared__ float dblS[CLH][32];
  int t0 = chunk * CLH;
  size_t dtbase = (size_t)dir * S_TOT + (size_t)b * L_SEQ;
  if (MODE) {
    for (int i = d; i < CLH * 16; i += 256)
      dblS[i >> 4][i & 15] =
          bf2f(dbl2[(dtbase + t0 + (i >> 4)) * 32 + 16 + (i & 15)]);
  } else {
    for (int i = d; i < CLH * 32; i += 256)
      dblS[i >> 5][i & 31] = bf2f(dbl2[(dtbase + t0) * 32 + i]);
  }
  __syncthreads();
  auto loadx = [&](int t) -> float {
    if (t < 0) return 0.f;
    int srct = dir ? (L_SEQ - 1 - t) : t;
    return bf2f(xz[((size_t)b * L_SEQ + srct) * 512 + d]);
  };
  float xm3 = 0.f, xm2 = 0.f, xm1 = 0.f;
  if (!MODE) { xm3 = loadx(t0 - 3); xm2 = loadx(t0 - 2); xm1 = loadx(t0 - 1); }
  float h[NST];
  size_t hbase = ((((size_t)(dir * 2 + b)) * NCH + chunk) * DIM + d) * NST;
  for (int n = 0; n < NST; ++n) h[n] = Hinit[hbase + n];
  unsigned short* up = &u_arr[(dtbase + t0) * DIM + d];
  const unsigned short* dtp = &dt_arr[(dtbase + t0) * DIM + d];
  unsigned short* yc = &ycomb[((size_t)b * L_SEQ + t0) * DIM + d];

#define P2_GRP(FASTA)                                                      \
  for (int t8 = 0; t8 < CLH; t8 += 8) {                                    \
    float uu[8], dd[8];                                                    \
    for (int j = 0; j < 8; ++j) {                                          \
      uu[j] = bf2f(up[(size_t)j * DIM]);                                   \
      dd[j] = bf2f(dtp[(size_t)j * DIM]);                                  \
    }                                                                      \
    for (int j = 0; j < 8; ++j) {                                          \
      const float* row = dblS[t8 + j];                                     \
      float u = uu[j], dtv = dd[j];                                        \
      float du = dtv * u;                                                  \
      DA8(FASTA)                                                           \
      float4 B0 = *(const float4*)(row);                                   \
      float4 B1 = *(const float4*)(row + 4);                               \
      float4 C0 = *(const float4*)(row + 8);                               \
      float4 C1 = *(const float4*)(row + 12);                              \
      h[0] = dA[0] * h[0] + du * B0.x; h[1] = dA[1] * h[1] + du * B0.y;    \
      h[2] = dA[2] * h[2] + du * B0.z; h[3] = dA[3] * h[3] + du * B0.w;    \
      h[4] = dA[4] * h[4] + du * B1.x; h[5] = dA[5] * h[5] + du * B1.y;    \
      h[6] = dA[6] * h[6] + du * B1.z; h[7] = dA[7] * h[7] + du * B1.w;    \
      float y = C0.x * h[0] + C0.y * h[1] + C0.z * h[2] + C0.w * h[3] +    \
                C1.x * h[4] + C1.y * h[5] + C1.z * h[6] + C1.w * h[7] +    \
                u * Dv;                                                    \
      if (dir == 0) yc[(size_t)j * DIM] = f2bf(y);                         \
      else          up[(size_t)j * DIM] = f2bf(y);                         \
    }                                                                      \
    up += 8 * DIM; dtp += 8 * DIM; yc += 8 * DIM;                          \
  }

#define P2_STEP(FASTA)                                                     \
  {                                                                        \
    int t = t0 + tl;                                                       \
    const float* row = dblS[tl];                                           \
    float u, dtv;                                                          \
    {                                                                      \
      float xin = loadx(t);                                                \
      float pre = w0 * xm3 + w1 * xm2 + w2 * xm1 + w3 * xin + bias;        \
      u = pre * rcpf(1.f + __expf(-pre));                                  \
      xm3 = xm2; xm2 = xm1; xm1 = xin;                                     \
      float4 q0 = *(const float4*)(row);                                   \
      float4 q1 = *(const float4*)(row + 4);                               \
      float4 q2 = *(const float4*)(row + 8);                               \
      float4 q3 = *(const float4*)(row + 12);                              \
      float xdt = dbias + q0.x * dwreg[0] + q0.y * dwreg[1] +              \
                  q0.z * dwreg[2] + q0.w * dwreg[3] + q1.x * dwreg[4] +    \
                  q1.y * dwreg[5] + q1.z * dwreg[6] + q1.w * dwreg[7] +    \
                  q2.x * dwreg[8] + q2.y * dwreg[9] + q2.z * dwreg[10] +   \
                  q2.w * dwreg[11] + q3.x * dwreg[12] + q3.y * dwreg[13] + \
                  q3.z * dwreg[14] + q3.w * dwreg[15];                     \
      dtv = (xdt > 15.f) ? xdt : __logf(1.f + __expf(xdt));                \
    }                                                                      \
    float du = dtv * u;                                                    \
    DA8(FASTA)                                                             \
    float4 B0 = *(const float4*)(row + 16);                                \
    float4 B1 = *(const float4*)(row + 20);                                \
    float4 C0 = *(const float4*)(row + 24);                                \
    float4 C1 = *(const float4*)(row + 28);                                \
    h[0] = dA[0] * h[0] + du * B0.x; h[1] = dA[1] * h[1] + du * B0.y;      \
    h[2] = dA[2] * h[2] + du * B0.z; h[3] = dA[3] * h[3] + du * B0.w;      \
    h[4] = dA[4] * h[4] + du * B1.x; h[5] = dA[5] * h[5] + du * B1.y;      \
    h[6] = dA[6] * h[6] + du * B1.z; h[7] = dA[7] * h[7] + du * B1.w;      \
    float y = C0.x * h[0] + C0.y * h[1] + C0.z * h[2] + C0.w * h[3] +      \
              C1.x * h[4] + C1.y * h[5] + C1.z * h[6] + C1.w * h[7] +      \
              u * Dv;                                                      \
    if (dir == 0) {                                                        \
      ycomb[((size_t)b * L_SEQ + t) * DIM + d] = f2bf(y);                  \
    } else {                                                               \
      size_t o = ((size_t)b * L_SEQ + (L_SEQ - 1 - t)) * DIM + d;          \
      float prev = bf2f(ycomb[o]);                                         \
      ycomb[o] = f2bf(0.5f * (prev + y));                                  \
    }                                                                      \
  }

  if (MODE) {
    if (fastA) { P2_GRP(1) } else { P2_GRP(0) }
  } else {
    if (fastA) {
      for (int tl = 0; tl < CLH; ++tl) P2_STEP(1)
    } else {
      for (int tl = 0; tl < CLH; ++tl) P2_STEP(0)
    }
  }
#undef P2_STEP
#undef P2_GRP
}

// ------- combine (tier A only): LN(ycomb)*silu(z) -> xz x-cols -------------
__global__ __launch_bounds__(256) void combine_ln(
    const unsigned short* __restrict__ ycomb,
    unsigned short* __restrict__ xz,
    const float* __restrict__ onw, const float* __restrict__ onb) {
  int m = blockIdx.x * 4 + (threadIdx.x >> 6);
  int lane = threadIdx.x & 63;
  ushort4 y4 = *(const ushort4*)&ycomb[(size_t)m * DIM + lane * 4];
  float v0 = bf2f(y4.x), v1 = bf2f(y4.y), v2 = bf2f(y4.z), v3 = bf2f(y4.w);
  float s = v0 + v1 + v2 + v3;
  float s2 = v0 * v0 + v1 * v1 + v2 * v2 + v3 * v3;
  for (int off = 32; off; off >>= 1) {
    s += __shfl_xor(s, off);
    s2 += __shfl_xor(s2, off);
  }
  float mean = s * (1.0f / DIM);
  float var = s2 * (1.0f / DIM) - mean * mean;
  float rstd = rsqrtf(var + 1e-5f);
  ushort4 z4 = *(const ushort4*)&xz[(size_t)m * 512 + 256 + lane * 4];
  float zf[4] = {bf2f(z4.x), bf2f(z4.y), bf2f(z4.z), bf2f(z4.w)};
  float vf[4] = {v0, v1, v2, v3};
  ushort4 out;
  unsigned short* op = (unsigned short*)&out;
  for (int j = 0; j < 4; ++j) {
    int c = lane * 4 + j;
    float ln = (vf[j] - mean) * rstd * onw[c] + onb[c];
    op[j] = f2bf(ln * (zf[j] * rcpf(1.f + __expf(-zf[j]))));
  }
  *(ushort4*)&xz[(size_t)m * 512 + lane * 4] = out;
}

extern "C" void kernel_launch(void* const* d_in, const int* in_sizes, int n_in,
                              void* d_out, int out_size, void* d_ws, size_t ws_size,
                              hipStream_t stream) {
  const float* input0 = (const float*)d_in[0];
  const float* input1 = (const float*)d_in[1];
  const float* norm0_w = (const float*)d_in[2];
  const float* norm0_b = (const float*)d_in[3];
  const float* norm1_w = (const float*)d_in[4];
  const float* norm1_b = (const float*)d_in[5];
  const float* in_proj_w = (const float*)d_in[6];
  const float* in_proj_extra_w = (const float*)d_in[7];
  const float* convx_w = (const float*)d_in[8];
  const float* convx_b = (const float*)d_in[9];
  const float* conve_w = (const float*)d_in[10];
  const float* conve_b = (const float*)d_in[11];
  const float* convx_w_r = (const float*)d_in[12];
  const float* convx_b_r = (const float*)d_in[13];
  const float* conve_w_r = (const float*)d_in[14];
  const float* conve_b_r = (const float*)d_in[15];
  const float* xproj_w = (const float*)d_in[16];
  const float* xproj_w_r = (const float*)d_in[17];
  const float* dtproj_w = (const float*)d_in[18];
  const float* dtproj_b = (const float*)d_in[19];
  const float* dtproj_w_r = (const float*)d_in[20];
  const float* dtproj_b_r = (const float*)d_in[21];
  const float* A_log = (const float*)d_in[22];
  const float* A_log_r = (const float*)d_in[23];
  const float* Dp = (const float*)d_in[24];
  const float* Dp_r = (const float*)d_in[25];
  const float* outnorm_w = (const float*)d_in[26];
  const float* outnorm_b = (const float*)d_in[27];
  const float* outproj_w = (const float*)d_in[28];

  // ---- workspace layout (bytes); base 76,021,760 + tier B 67,108,864 ----
  char* w = (char*)d_ws;
  unsigned short* xz    = (unsigned short*)(w + 0);          // 33,554,432 B
  unsigned short* h0    = (unsigned short*)(w + 33554432);   // 16,777,216 B
  unsigned short* ycomb = (unsigned short*)(w + 33554432);   // same region, later
  float* Qc   = (float*)(w + 33554432);                      // pass1->mid
  unsigned short* xe    = (unsigned short*)(w + 50331648);   // 16,777,216 B
  float* Pc   = (float*)(w + 50331648);                      // aliases xe after xproj
  unsigned short* dbl2 = (unsigned short*)(w + 67108864);    // 4,194,304 B (bf16)
  unsigned short* wb = (unsigned short*)(w + 75497472);      // 524,288 B bf16 weights
  unsigned short* wb_in  = wb;
  unsigned short* wb_ex  = wb + 131072;
  unsigned short* wb_out = wb + 196608;
  unsigned short* u_arr  = (unsigned short*)(w + 76021760);  // 33,554,432 B (tier B)
  unsigned short* dt_arr = (unsigned short*)(w + 109576192); // 33,554,432 B (tier B)
  const bool big = ws_size >= 76021760ULL + 67108864ULL;     // 143,130,624
  // h1: tier B -> parked in u_arr region (dead until dtu); tier A -> xz region
  unsigned short* h1 = big ? u_arr : xz;

  ln_norm<<<dim3(S_TOT / 4, 2), 256, 0, stream>>>(
      input0, input1, norm0_w, norm0_b, norm1_w, norm1_b, h0, h1,
      in_proj_w, in_proj_extra_w, outproj_w, wb);
  if (big) {
    gemm_in<<<dim3(12, 512), 256, 0, stream>>>(h0, h1, wb_in, wb_ex, xz, xe);
  } else {
    gemm64<1, 0><<<dim3(4, 512), 256, 0, stream>>>(h1, DIM, wb_ex, xe, nullptr, 256);
    gemm64<1, 0><<<dim3(8, 512), 256, 0, stream>>>(h0, DIM, wb_in, xz, nullptr, 512);
  }
  xproj_mfma<<<dim3(512, 2), 256, 0, stream>>>(
      xe, conve_w, conve_b, conve_w_r, conve_b_r, xproj_w, xproj_w_r, dbl2);
  if (big) {
    dtu_compute<<<dim3(2048), 256, 0, stream>>>(
        dbl2, dtproj_w, dtproj_w_r, dtproj_b, dtproj_b_r, dt_arr,
        xz, convx_w, convx_b, convx_w_r, convx_b_r, u_arr);
    scan_pass1<1><<<dim3(NCH, 2, 2), 256, 0, stream>>>(
        xz, dbl2, u_arr, dt_arr, convx_w, convx_b, convx_w_r, convx_b_r,
        dtproj_w, dtproj_b, dtproj_w_r, dtproj_b_r, A_log, A_log_r, Pc, Qc);
  } else {
    scan_pass1<0><<<dim3(NCH, 2, 2), 256, 0, stream>>>(
        xz, dbl2, u_arr, dt_arr, convx_w, convx_b, convx_w_r, convx_b_r,
        dtproj_w, dtproj_b, dtproj_w_r, dtproj_b_r, A_log, A_log_r, Pc, Qc);
  }
  scan_mid<<<dim3(32), 256, 0, stream>>>(Pc, Qc);
  if (big) {
    scan_pass2<1><<<dim3(NCH, 2, 2), 256, 0, stream>>>(
        xz, dbl2, u_arr, dt_arr, convx_w, convx_b, convx_w_r, convx_b_r,
        dtproj_w, dtproj_b, dtproj_w_r, dtproj_b_r, A_log, A_log_r,
        Dp, Dp_r, Pc, ycomb, 0);
    // fused combine + out_proj + residual
    gemm_out_fused<<<dim3(4, 512), 256, 0, stream>>>(
        ycomb, u_arr, xz, outnorm_w, outnorm_b, wb_out, (float*)d_out, input0);
  } else {
    for (int dir = 0; dir < 2; ++dir)
      scan_pass2<0><<<dim3(NCH, 2), 256, 0, stream>>>(
          xz, dbl2, u_arr, dt_arr, convx_w, convx_b, convx_w_r, convx_b_r,
          dtproj_w, dtproj_b, dtproj_w_r, dtproj_b_r, A_log, A_log_r,
          Dp, Dp_r, Pc, ycomb, dir);
    combine_ln<<<dim3(S_TOT / 4), 256, 0, stream>>>(ycomb, xz, outnorm_w, outnorm_b);
    gemm64<0, 1><<<dim3(4, 512), 256, 0, stream>>>(
        xz, 512, wb_out, d_out, input0, 256);
  }
}

// Round 21
// 214.757 us; speedup vs baseline: 1.1075x; 1.1075x over previous
//
#include <hip/hip_runtime.h>
#include <math.h>

#define L_SEQ 16384
#define DIM 256
#define NST 8
#define RNK 16
#define S_TOT 32768   // B*L
#define NCH 512
#define CLH 32

typedef __attribute__((ext_vector_type(8))) short bf16x8;
typedef __attribute__((ext_vector_type(4))) float f32x4;

__device__ __forceinline__ float bf2f(unsigned short u) {
  union { unsigned int i; float f; } v; v.i = ((unsigned int)u) << 16; return v.f;
}
__device__ __forceinline__ unsigned short f2bf(float x) {
  union { float f; unsigned int i; } v; v.f = x;
  unsigned int r = v.i + 0x7fffu + ((v.i >> 16) & 1u);
  return (unsigned short)(r >> 16);
}
__device__ __forceinline__ float rcpf(float x) {
  return __builtin_amdgcn_rcpf(x);
}

// ---- fused LayerNorm -> bf16 (wave/row, 4 rows/blk) + weight conversion ----
__global__ __launch_bounds__(256) void ln_norm(
    const float* __restrict__ in0, const float* __restrict__ in1,
    const float* __restrict__ w0, const float* __restrict__ b0,
    const float* __restrict__ w1, const float* __restrict__ b1,
    unsigned short* __restrict__ h0, unsigned short* __restrict__ h1,
    const float* __restrict__ pw0, const float* __restrict__ pw1,
    const float* __restrict__ pw2, unsigned short* __restrict__ wbout) {
  int which = blockIdx.y;
  if (which == 0 && blockIdx.x < 1024) {
    int i = blockIdx.x * 256 + threadIdx.x;
    if (i < 131072) wbout[i] = f2bf(pw0[i]);
    else if (i < 196608) wbout[i] = f2bf(pw1[i - 131072]);
    else wbout[i] = f2bf(pw2[i - 196608]);
  }
  int row = blockIdx.x * 4 + (threadIdx.x >> 6);
  int lane = threadIdx.x & 63;
  const float* x = (which ? in1 : in0) + (size_t)row * DIM;
  const float* w = which ? w1 : w0;
  const float* b = which ? b1 : b0;
  unsigned short* h = which ? h1 : h0;
  float4 v = *(const float4*)&x[lane * 4];
  float s = v.x + v.y + v.z + v.w;
  float s2 = v.x * v.x + v.y * v.y + v.z * v.z + v.w * v.w;
  for (int off = 32; off; off >>= 1) {
    s += __shfl_xor(s, off);
    s2 += __shfl_xor(s2, off);
  }
  float mean = s * (1.0f / DIM);
  float var = s2 * (1.0f / DIM) - mean * mean;
  float rstd = rsqrtf(var + 1e-5f);
  float4 wv = *(const float4*)&w[lane * 4];
  float4 bv = *(const float4*)&b[lane * 4];
  ushort4 out;
  out.x = f2bf((v.x - mean) * rstd * wv.x + bv.x);
  out.y = f2bf((v.y - mean) * rstd * wv.y + bv.y);
  out.z = f2bf((v.z - mean) * rstd * wv.z + bv.z);
  out.w = f2bf((v.w - mean) * rstd * wv.w + bv.w);
  *(ushort4*)&h[(size_t)row * DIM + lane * 4] = out;
}

// ------- streaming bf16 GEMM, 64x64 tile, full K=256 staged once -------
template <int BF16C, int ADDIN>
__global__ __launch_bounds__(256) void gemm64(
    const unsigned short* __restrict__ A, int lda,
    const unsigned short* __restrict__ Wb,
    void* __restrict__ Cv, const float* __restrict__ addp, int Nn) {
  __shared__ unsigned short As[64 * 256];
  __shared__ unsigned short Ws[64 * 256];
  int tid = threadIdx.x;
  int n0 = blockIdx.x * 64, m0 = blockIdx.y * 64;
  for (int i = 0; i < 8; ++i) {
    int f8 = tid + i * 256;
    int r = f8 >> 5, c8 = (f8 & 31) * 8;
    int sc = c8 ^ ((r & 7) << 3);
    *(uint4*)&As[r * 256 + sc] = *(const uint4*)&A[(size_t)(m0 + r) * lda + c8];
    *(uint4*)&Ws[r * 256 + sc] = *(const uint4*)&Wb[(size_t)(n0 + r) * 256 + c8];
  }
  __syncthreads();
  int wid = tid >> 6, lane = tid & 63;
  int wm = wid >> 1, wn = wid & 1;
  int l15 = lane & 15, lk = (lane >> 4) * 8;
  f32x4 acc[2][2] = {};
  for (int ks = 0; ks < 8; ++ks) {
    int kcol = ks * 32 + lk;
    bf16x8 af[2], bf_[2];
    for (int mf = 0; mf < 2; ++mf) {
      int row = wm * 32 + mf * 16 + l15;
      af[mf] = *(const bf16x8*)&As[row * 256 + (kcol ^ ((row & 7) << 3))];
    }
    for (int nf = 0; nf < 2; ++nf) {
      int row = wn * 32 + nf * 16 + l15;
      bf_[nf] = *(const bf16x8*)&Ws[row * 256 + (kcol ^ ((row & 7) << 3))];
    }
    for (int mf = 0; mf < 2; ++mf)
      for (int nf = 0; nf < 2; ++nf)
        acc[mf][nf] = __builtin_amdgcn_mfma_f32_16x16x32_bf16(
            af[mf], bf_[nf], acc[mf][nf], 0, 0, 0);
  }
  for (int mf = 0; mf < 2; ++mf)
    for (int nf = 0; nf < 2; ++nf) {
      int row = m0 + wm * 32 + mf * 16 + (lane >> 4) * 4;
      int col = n0 + wn * 32 + nf * 16 + l15;
      for (int v = 0; v < 4; ++v) {
        size_t off = (size_t)(row + v) * Nn + col;
        float val = acc[mf][nf][v];
        if (ADDIN) val += addp[off];
        if (BF16C) ((unsigned short*)Cv)[off] = f2bf(val);
        else       ((float*)Cv)[off] = val;
      }
    }
}

// ---- merged input GEMMs: blocks x<4 -> xe = h1@wb_ex^T; x>=4 -> xz = h0@wb_in^T
__global__ __launch_bounds__(256) void gemm_in(
    const unsigned short* __restrict__ h0, const unsigned short* __restrict__ h1,
    const unsigned short* __restrict__ wb_in, const unsigned short* __restrict__ wb_ex,
    unsigned short* __restrict__ xzOut, unsigned short* __restrict__ xeOut) {
  __shared__ unsigned short As[64 * 256];
  __shared__ unsigned short Ws[64 * 256];
  int tid = threadIdx.x;
  bool isX = blockIdx.x >= 4;
  const unsigned short* A = isX ? h0 : h1;
  const unsigned short* Wb = isX ? wb_in : wb_ex;
  unsigned short* Cv = isX ? xzOut : xeOut;
  int Nn = isX ? 512 : 256;
  int n0 = (isX ? (int)blockIdx.x - 4 : (int)blockIdx.x) * 64;
  int m0 = blockIdx.y * 64;
  for (int i = 0; i < 8; ++i) {
    int f8 = tid + i * 256;
    int r = f8 >> 5, c8 = (f8 & 31) * 8;
    int sc = c8 ^ ((r & 7) << 3);
    *(uint4*)&As[r * 256 + sc] = *(const uint4*)&A[(size_t)(m0 + r) * 256 + c8];
    *(uint4*)&Ws[r * 256 + sc] = *(const uint4*)&Wb[(size_t)(n0 + r) * 256 + c8];
  }
  __syncthreads();
  int wid = tid >> 6, lane = tid & 63;
  int wm = wid >> 1, wn = wid & 1;
  int l15 = lane & 15, lk = (lane >> 4) * 8;
  f32x4 acc[2][2] = {};
  for (int ks = 0; ks < 8; ++ks) {
    int kcol = ks * 32 + lk;
    bf16x8 af[2], bf_[2];
    for (int mf = 0; mf < 2; ++mf) {
      int row = wm * 32 + mf * 16 + l15;
      af[mf] = *(const bf16x8*)&As[row * 256 + (kcol ^ ((row & 7) << 3))];
    }
    for (int nf = 0; nf < 2; ++nf) {
      int row = wn * 32 + nf * 16 + l15;
      bf_[nf] = *(const bf16x8*)&Ws[row * 256 + (kcol ^ ((row & 7) << 3))];
    }
    for (int mf = 0; mf < 2; ++mf)
      for (int nf = 0; nf < 2; ++nf)
        acc[mf][nf] = __builtin_amdgcn_mfma_f32_16x16x32_bf16(
            af[mf], bf_[nf], acc[mf][nf], 0, 0, 0);
  }
  for (int mf = 0; mf < 2; ++mf)
    for (int nf = 0; nf < 2; ++nf) {
      int row = m0 + wm * 32 + mf * 16 + (lane >> 4) * 4;
      int col = n0 + wn * 32 + nf * 16 + l15;
      for (int v = 0; v < 4; ++v) {
        size_t off = (size_t)(row + v) * Nn + col;
        Cv[off] = f2bf(acc[mf][nf][v]);
      }
    }
}

// -------- conv(xe)+silu -> MFMA projection to dbl(32) bf16, 64 rows/block --
__global__ __launch_bounds__(256) void xproj_mfma(
    const unsigned short* __restrict__ xe,
    const float* __restrict__ conve_w, const float* __restrict__ conve_b,
    const float* __restrict__ conve_w_r, const float* __restrict__ conve_b_r,
    const float* __restrict__ xproj_w, const float* __restrict__ xproj_w_r,
    unsigned short* __restrict__ dbl2) {
  __shared__ unsigned short ecS[64 * 256];
  __shared__ unsigned short xwS[32 * 256];
  int chunk = blockIdx.x;
  int dir = blockIdx.y;
  int b = chunk >> 8;
  int t0 = (chunk & 255) * 64;
  int tid = threadIdx.x;
  const float* cw = dir ? conve_w_r : conve_w;
  const float* cb = dir ? conve_b_r : conve_b;
  const float* xw = dir ? xproj_w_r : xproj_w;

  for (int i = tid; i < 32 * 256; i += 256) {
    int o = i >> 8, dd = i & 255;
    xwS[o * 256 + (((dd & ~7) ^ ((o & 7) << 3)) | (dd & 7))] = f2bf(xw[i]);
  }

  {
    int c = tid;
    float w0 = cw[c * 4 + 0], w1 = cw[c * 4 + 1], w2 = cw[c * 4 + 2],
          w3 = cw[c * 4 + 3], bias = cb[c];
    size_t bL = (size_t)b * L_SEQ;
    auto loadx = [&](int t) -> float {
      if (t < 0) return 0.f;
      int src = dir ? (L_SEQ - 1 - t) : t;
      return bf2f(xe[(bL + src) * DIM + c]);
    };
    float xm3 = loadx(t0 - 3), xm2 = loadx(t0 - 2), xm1 = loadx(t0 - 1);
    const unsigned short* xp =
        &xe[(bL + (dir ? (L_SEQ - 1 - t0) : t0)) * DIM + c];
    int xstep = dir ? -DIM : DIM;
    int cbase = c & ~7, clow = c & 7;
    for (int t4 = 0; t4 < 64; t4 += 4) {
      float xin4[4];
      for (int j = 0; j < 4; ++j) xin4[j] = bf2f(xp[(ptrdiff_t)j * xstep]);
      xp += (ptrdiff_t)4 * xstep;
      for (int j = 0; j < 4; ++j) {
        int tl = t4 + j;
        float xin = xin4[j];
        float pre = w0 * xm3 + w1 * xm2 + w2 * xm1 + w3 * xin + bias;
        float u = pre * rcpf(1.f + __expf(-pre));
        xm3 = xm2; xm2 = xm1; xm1 = xin;
        ecS[tl * 256 + ((cbase ^ ((tl & 7) << 3)) | clow)] = f2bf(u);
      }
    }
  }
  __syncthreads();

  int wid = tid >> 6, lane = tid & 63;
  int l15 = lane & 15, lk = (lane >> 4) * 8;
  f32x4 acc[2] = {};
  for (int kk = 0; kk < 8; ++kk) {
    int kcol = kk * 32 + lk;
    int row = wid * 16 + l15;
    bf16x8 af = *(const bf16x8*)&ecS[row * 256 + (kcol ^ ((row & 7) << 3))];
    for (int ni = 0; ni < 2; ++ni) {
      int o = ni * 16 + l15;
      bf16x8 bfr = *(const bf16x8*)&xwS[o * 256 + (kcol ^ ((o & 7) << 3))];
      acc[ni] = __builtin_amdgcn_mfma_f32_16x16x32_bf16(af, bfr, acc[ni], 0, 0, 0);
    }
  }
  size_t mbase = (size_t)dir * S_TOT + (size_t)chunk * 64;
  int rloc = wid * 16 + (lane >> 4) * 4;
  for (int ni = 0; ni < 2; ++ni) {
    int o = ni * 16 + l15;
    for (int v = 0; v < 4; ++v)
      dbl2[(mbase + rloc + v) * 32 + o] = f2bf(acc[ni][v]);
  }
}

// ---- merged: blocks 0..1023 = dt_mfma; blocks 1024..2047 = u_compute ------
__global__ __launch_bounds__(256) void dtu_compute(
    const unsigned short* __restrict__ dbl2,
    const float* __restrict__ dtw, const float* __restrict__ dtw_r,
    const float* __restrict__ dtb, const float* __restrict__ dtb_r,
    unsigned short* __restrict__ dt_arr,
    const unsigned short* __restrict__ xz,
    const float* __restrict__ convx_w, const float* __restrict__ convx_b,
    const float* __restrict__ convx_w_r, const float* __restrict__ convx_b_r,
    unsigned short* __restrict__ u_arr) {
  __shared__ unsigned short dtwS[256 * 32];
  __shared__ unsigned short dtrS[64 * 32];
  __shared__ unsigned short outS[64 * 256];
  int tid = threadIdx.x;
  if (blockIdx.x < 1024) {
    int m0 = blockIdx.x * 64;
    int dir = (blockIdx.x >= 512) ? 1 : 0;
    const float* dw = dir ? dtw_r : dtw;
    const float* db = dir ? dtb_r : dtb;
    {
      uint4 z; z.x = 0; z.y = 0; z.z = 0; z.w = 0;
      for (int i = tid; i < 1280; i += 256) {
        if (i < 1024) ((uint4*)dtwS)[i] = z;
        else          ((uint4*)dtrS)[i - 1024] = z;
      }
    }
    __syncthreads();
    for (int it = 0; it < 4; ++it) {
      int idx = tid + it * 256;
      int c = idx >> 2, k4 = idx & 3;
      float4 v = *(const float4*)&dw[c * 16 + k4 * 4];
      uint2 pk;
      pk.x = (unsigned int)f2bf(v.x) | ((unsigned int)f2bf(v.y) << 16);
      pk.y = (unsigned int)f2bf(v.z) | ((unsigned int)f2bf(v.w) << 16);
      int byte = c * 64 + (((k4 >> 1) ^ (c & 3)) << 4) + ((k4 & 1) << 3);
      *(uint2*)((char*)dtwS + byte) = pk;
    }
    {
      int r = tid >> 2, k4 = tid & 3;
      uint2 pk = *(const uint2*)&dbl2[(size_t)(m0 + r) * 32 + k4 * 4];
      int byte = r * 64 + (((k4 >> 1) ^ (r & 3)) << 4) + ((k4 & 1) << 3);
      *(uint2*)((char*)dtrS + byte) = pk;
    }
    __syncthreads();
    int wid = tid >> 6, lane = tid & 63;
    int l15 = lane & 15, lkc = lane >> 4;
    bf16x8 af[4];
    for (int mi = 0; mi < 4; ++mi) {
      int r = mi * 16 + l15;
      af[mi] = *(const bf16x8*)((char*)dtrS + r * 64 + ((lkc ^ (r & 3)) << 4));
    }
    f32x4 acc[4][4] = {};
    for (int ni = 0; ni < 4; ++ni) {
      int c = (wid * 4 + ni) * 16 + l15;
      bf16x8 bfr = *(const bf16x8*)((char*)dtwS + c * 64 + ((lkc ^ (c & 3)) << 4));
      for (int mi = 0; mi < 4; ++mi)
        acc[mi][ni] = __builtin_amdgcn_mfma_f32_16x16x32_bf16(
            af[mi], bfr, acc[mi][ni], 0, 0, 0);
    }
    for (int ni = 0; ni < 4; ++ni) {
      int c = (wid * 4 + ni) * 16 + l15;
      float bias_ = db[c];
      int cb_ = c & ~7, cl_ = c & 7;
      for (int mi = 0; mi < 4; ++mi) {
        int rb = mi * 16 + (lane >> 4) * 4;
        for (int v = 0; v < 4; ++v) {
          int r = rb + v;
          float xdt = acc[mi][ni][v] + bias_;
          float dtv = (xdt > 15.f) ? xdt : __logf(1.f + __expf(xdt));
          outS[r * 256 + ((cb_ ^ ((r & 7) << 3)) | cl_)] = f2bf(dtv);
        }
      }
    }
    __syncthreads();
    for (int it = 0; it < 8; ++it) {
      int i = tid + it * 256;
      int r = i >> 5, cg = (i & 31) * 8;
      uint4 val = *(const uint4*)&outS[r * 256 + (cg ^ ((r & 7) << 3))];
      *(uint4*)&dt_arr[(size_t)(m0 + r) * 256 + cg] = val;
    }
  } else {
    int chunk = blockIdx.x - 1024;
    int b = chunk >> 9;
    int t0 = (chunk & 511) * 32;
    int c = tid;
    float w0 = convx_w[c * 4 + 0], w1 = convx_w[c * 4 + 1],
          w2 = convx_w[c * 4 + 2], w3 = convx_w[c * 4 + 3], bias = convx_b[c];
    float w0r = convx_w_r[c * 4 + 0], w1r = convx_w_r[c * 4 + 1],
          w2r = convx_w_r[c * 4 + 2], w3r = convx_w_r[c * 4 + 3],
          biasr = convx_b_r[c];
    size_t bL = (size_t)b * L_SEQ;
    auto ld = [&](int t) -> float {
      if (t < 0 || t >= L_SEQ) return 0.f;
      return bf2f(xz[(bL + t) * 512 + c]);
    };
    float x3 = ld(t0 - 3), x2 = ld(t0 - 2), x1 = ld(t0 - 1);
    unsigned short* op0 = &u_arr[(bL + t0) * DIM + c];
    unsigned short* op1 =
        &u_arr[((size_t)S_TOT + bL + (L_SEQ - 1 - t0)) * DIM + c];
    for (int tg = 0; tg < 36; tg += 4) {
      float xin4[4];
      for (int j = 0; j < 4; ++j) xin4[j] = ld(t0 + tg + j);
      for (int j = 0; j < 4; ++j) {
        int tl = tg + j;
        float xin = xin4[j];
        if (tl < 32) {
          float pre = w0 * x3 + w1 * x2 + w2 * x1 + w3 * xin + bias;
          op0[(size_t)tl * DIM] = f2bf(pre * rcpf(1.f + __expf(-pre)));
        }
        if (tl >= 3 && tl < 35) {
          float prer = w0r * xin + w1r * x1 + w2r * x2 + w3r * x3 + biasr;
          int s = tl - 3;
          *(op1 - (ptrdiff_t)s * DIM) = f2bf(prer * rcpf(1.f + __expf(-prer)));
        }
        x3 = x2; x2 = x1; x1 = xin;
      }
    }
  }
}

// dA[0..7] = exp(dtv*Ar[n]); FASTA: Ar[n] == -(n+1) verified
#define DA8(FASTA)                                                    \
  float dA[NST];                                                      \
  if (FASTA) {                                                        \
    float e1 = __expf(-dtv);                                          \
    dA[0] = e1;                                                       \
    for (int n = 1; n < NST; ++n) dA[n] = dA[n - 1] * e1;             \
  } else {                                                            \
    for (int n = 0; n < NST; ++n) dA[n] = __expf(dtv * Ar[n]);        \
  }

// ---------------- scan pass 1: per-chunk affine summaries ----------------
template <int USE_UDT>
__global__ __launch_bounds__(256) void scan_pass1(
    const unsigned short* __restrict__ xz, const unsigned short* __restrict__ dbl2,
    const unsigned short* __restrict__ u_arr,
    const unsigned short* __restrict__ dt_arr,
    const float* __restrict__ convx_w, const float* __restrict__ convx_b,
    const float* __restrict__ convx_w_r, const float* __restrict__ convx_b_r,
    const float* __restrict__ dtproj_w, const float* __restrict__ dtproj_b,
    const float* __restrict__ dtproj_w_r, const float* __restrict__ dtproj_b_r,
    const float* __restrict__ A_log, const float* __restrict__ A_log_r,
    float* __restrict__ Pc, float* __restrict__ Qc) {
  int chunk = blockIdx.x, b = blockIdx.y, dir = blockIdx.z;
  int d = threadIdx.x;
  const float* al = dir ? A_log_r : A_log;
  float w0 = 0.f, w1 = 0.f, w2 = 0.f, w3 = 0.f, bias = 0.f, dbias = 0.f;
  float dwreg[RNK];
  if (!USE_UDT) {
    const float* cw = dir ? convx_w_r : convx_w;
    const float* cb = dir ? convx_b_r : convx_b;
    const float* dw = dir ? dtproj_w_r : dtproj_w;
    const float* dbp = dir ? dtproj_b_r : dtproj_b;
    w0 = cw[d * 4 + 0]; w1 = cw[d * 4 + 1]; w2 = cw[d * 4 + 2];
    w3 = cw[d * 4 + 3]; bias = cb[d]; dbias = dbp[d];
    for (int r = 0; r < RNK; ++r) dwreg[r] = dw[d * RNK + r];
  }
  float Ar[NST];
  bool fa = true;
  for (int n = 0; n < NST; ++n) {
    Ar[n] = -__expf(al[d * NST + n]);
    fa = fa && (fabsf(Ar[n] + (float)(n + 1)) < 1e-4f * (float)(n + 1));
  }
  bool fastA = (__ballot(fa) == ~0ULL);

  __shared__ float dblS[CLH][32];
  int t0 = chunk * CLH;
  size_t dtbase = (size_t)dir * S_TOT + (size_t)b * L_SEQ;
  if (USE_UDT) {
    int i = d;
    dblS[i >> 3][i & 7] =
        bf2f(dbl2[(dtbase + t0 + (i >> 3)) * 32 + 16 + (i & 7)]);
  } else {
    for (int i = d; i < CLH * 32; i += 256)
      dblS[i >> 5][i & 31] = bf2f(dbl2[(dtbase + t0) * 32 + i]);
  }
  __syncthreads();
  auto loadx = [&](int t) -> float {
    if (t < 0) return 0.f;
    int srct = dir ? (L_SEQ - 1 - t) : t;
    return bf2f(xz[((size_t)b * L_SEQ + srct) * 512 + d]);
  };
  float xm3 = 0.f, xm2 = 0.f, xm1 = 0.f;
  if (!USE_UDT) { xm3 = loadx(t0 - 3); xm2 = loadx(t0 - 2); xm1 = loadx(t0 - 1); }
  const unsigned short* up = &u_arr[(dtbase + t0) * DIM + d];
  const unsigned short* dtp = &dt_arr[(dtbase + t0) * DIM + d];
  float Q[NST];
  for (int n = 0; n < NST; ++n) Q[n] = 0.f;
  float sdt = 0.f;
  const int BOFF = USE_UDT ? 0 : 16;

#define P1_GRP(FASTA)                                                      \
  for (int t8 = 0; t8 < CLH; t8 += 8) {                                    \
    float uu[8], dd[8];                                                    \
    for (int j = 0; j < 8; ++j) {                                          \
      uu[j] = bf2f(up[(size_t)j * DIM]);                                   \
      dd[j] = bf2f(dtp[(size_t)j * DIM]);                                  \
    }                                                                      \
    up += 8 * DIM; dtp += 8 * DIM;                                         \
    for (int j = 0; j < 8; ++j) {                                          \
      const float* row = dblS[t8 + j];                                     \
      float u = uu[j], dtv = dd[j];                                        \
      float du = dtv * u;                                                  \
      sdt += dtv;                                                          \
      DA8(FASTA)                                                           \
      float4 B0 = *(const float4*)(row);                                   \
      float4 B1 = *(const float4*)(row + 4);                               \
      Q[0] = dA[0] * Q[0] + du * B0.x; Q[1] = dA[1] * Q[1] + du * B0.y;    \
      Q[2] = dA[2] * Q[2] + du * B0.z; Q[3] = dA[3] * Q[3] + du * B0.w;    \
      Q[4] = dA[4] * Q[4] + du * B1.x; Q[5] = dA[5] * Q[5] + du * B1.y;    \
      Q[6] = dA[6] * Q[6] + du * B1.z; Q[7] = dA[7] * Q[7] + du * B1.w;    \
    }                                                                      \
  }

#define P1_STEP(FASTA)                                                     \
  {                                                                        \
    const float* row = dblS[tl];                                           \
    float u, dtv;                                                          \
    {                                                                      \
      float xin = loadx(t0 + tl);                                          \
      float pre = w0 * xm3 + w1 * xm2 + w2 * xm1 + w3 * xin + bias;        \
      u = pre * rcpf(1.f + __expf(-pre));                                  \
      xm3 = xm2; xm2 = xm1; xm1 = xin;                                     \
      float4 q0 = *(const float4*)(row);                                   \
      float4 q1 = *(const float4*)(row + 4);                               \
      float4 q2 = *(const float4*)(row + 8);                               \
      float4 q3 = *(const float4*)(row + 12);                              \
      float xdt = dbias + q0.x * dwreg[0] + q0.y * dwreg[1] +              \
                  q0.z * dwreg[2] + q0.w * dwreg[3] + q1.x * dwreg[4] +    \
                  q1.y * dwreg[5] + q1.z * dwreg[6] + q1.w * dwreg[7] +    \
                  q2.x * dwreg[8] + q2.y * dwreg[9] + q2.z * dwreg[10] +   \
                  q2.w * dwreg[11] + q3.x * dwreg[12] + q3.y * dwreg[13] + \
                  q3.z * dwreg[14] + q3.w * dwreg[15];                     \
      dtv = (xdt > 15.f) ? xdt : __logf(1.f + __expf(xdt));                \
    }                                                                      \
    float du = dtv * u;                                                    \
    sdt += dtv;                                                            \
    DA8(FASTA)                                                             \
    float4 B0 = *(const float4*)(row + BOFF);                              \
    float4 B1 = *(const float4*)(row + BOFF + 4);                          \
    Q[0] = dA[0] * Q[0] + du * B0.x; Q[1] = dA[1] * Q[1] + du * B0.y;      \
    Q[2] = dA[2] * Q[2] + du * B0.z; Q[3] = dA[3] * Q[3] + du * B0.w;      \
    Q[4] = dA[4] * Q[4] + du * B1.x; Q[5] = dA[5] * Q[5] + du * B1.y;      \
    Q[6] = dA[6] * Q[6] + du * B1.z; Q[7] = dA[7] * Q[7] + du * B1.w;      \
  }

  if (USE_UDT) {
    if (fastA) { P1_GRP(1) } else { P1_GRP(0) }
  } else {
    if (fastA) {
      for (int tl = 0; tl < CLH; ++tl) P1_STEP(1)
    } else {
      for (int tl = 0; tl < CLH; ++tl) P1_STEP(0)
    }
  }
#undef P1_STEP
#undef P1_GRP

  float P[NST];
  if (fastA) {
    float E = __expf(-sdt);
    P[0] = E;
    for (int n = 1; n < NST; ++n) P[n] = P[n - 1] * E;
  } else {
    for (int n = 0; n < NST; ++n) P[n] = __expf(Ar[n] * sdt);
  }
  size_t obase = ((((size_t)(dir * 2 + b)) * NCH + chunk) * DIM + d) * NST;
  for (int n = 0; n < NST; ++n) { Pc[obase + n] = P[n]; Qc[obase + n] = Q[n]; }
}

// -------- scan mid: sequential over chunk summaries; Hinit in-place in Pc --
__global__ __launch_bounds__(256) void scan_mid(
    float* __restrict__ Pc, const float* __restrict__ Qc) {
  int idx = blockIdx.x * 256 + threadIdx.x;
  int dn = idx & 2047;
  int db_ = idx >> 11;
  size_t base = (size_t)db_ * NCH * 2048 + dn;
  float h = 0.f;
  for (int c0 = 0; c0 < NCH; c0 += 8) {
    size_t off = base + (size_t)c0 * 2048;
    float P[8], Q[8];
#pragma unroll
    for (int j = 0; j < 8; ++j) {
      P[j] = Pc[off + (size_t)j * 2048];
      Q[j] = Qc[off + (size_t)j * 2048];
    }
#pragma unroll
    for (int j = 0; j < 8; ++j) {
      Pc[off + (size_t)j * 2048] = h;
      h = P[j] * h + Q[j];
    }
  }
}

// ---------------- scan pass 2 ----------------
template <int MODE>
__global__ __launch_bounds__(256) void scan_pass2(
    const unsigned short* __restrict__ xz, const unsigned short* __restrict__ dbl2,
    unsigned short* __restrict__ u_arr,
    const unsigned short* __restrict__ dt_arr,
    const float* __restrict__ convx_w, const float* __restrict__ convx_b,
    const float* __restrict__ convx_w_r, const float* __restrict__ convx_b_r,
    const float* __restrict__ dtproj_w, const float* __restrict__ dtproj_b,
    const float* __restrict__ dtproj_w_r, const float* __restrict__ dtproj_b_r,
    const float* __restrict__ A_log, const float* __restrict__ A_log_r,
    const float* __restrict__ Dp, const float* __restrict__ Dp_r,
    const float* __restrict__ Hinit, unsigned short* __restrict__ ycomb,
    int dirParam) {
  int chunk = blockIdx.x, b = blockIdx.y;
  int dir = MODE ? blockIdx.z : dirParam;
  int d = threadIdx.x;
  const float* al = dir ? A_log_r : A_log;
  float Dv = (dir ? Dp_r : Dp)[d];
  float w0 = 0.f, w1 = 0.f, w2 = 0.f, w3 = 0.f, bias = 0.f, dbias = 0.f;
  float dwreg[RNK];
  if (!MODE) {
    const float* cw = dir ? convx_w_r : convx_w;
    const float* cb = dir ? convx_b_r : convx_b;
    const float* dw = dir ? dtproj_w_r : dtproj_w;
    const float* dbp = dir ? dtproj_b_r : dtproj_b;
    w0 = cw[d * 4 + 0]; w1 = cw[d * 4 + 1]; w2 = cw[d * 4 + 2];
    w3 = cw[d * 4 + 3]; bias = cb[d];
    dbias = dbp[d];
    for (int r = 0; r < RNK; ++r) dwreg[r] = dw[d * RNK + r];
  }
  float Ar[NST];
  bool fa = true;
  for (int n = 0; n < NST; ++n) {
    Ar[n] = -__expf(al[d * NST + n]);
    fa = fa && (fabsf(Ar[n] + (float)(n + 1)) < 1e-4f * (float)(n + 1));
  }
  bool fastA = (__ballot(fa) == ~0ULL);

  __shared__ float dblS[CLH][32];
  int t0 = chunk * CLH;
  size_t dtbase = (size_t)dir * S_TOT + (size_t)b * L_SEQ;
  if (MODE) {
    for (int i = d; i < CLH * 16; i += 256)
      dblS[i >> 4][i & 15] =
          bf2f(dbl2[(dtbase + t0 + (i >> 4)) * 32 + 16 + (i & 15)]);
  } else {
    for (int i = d; i < CLH * 32; i += 256)
      dblS[i >> 5][i & 31] = bf2f(dbl2[(dtbase + t0) * 32 + i]);
  }
  __syncthreads();
  auto loadx = [&](int t) -> float {
    if (t < 0) return 0.f;
    int srct = dir ? (L_SEQ - 1 - t) : t;
    return bf2f(xz[((size_t)b * L_SEQ + srct) * 512 + d]);
  };
  float xm3 = 0.f, xm2 = 0.f, xm1 = 0.f;
  if (!MODE) { xm3 = loadx(t0 - 3); xm2 = loadx(t0 - 2); xm1 = loadx(t0 - 1); }
  float h[NST];
  size_t hbase = ((((size_t)(dir * 2 + b)) * NCH + chunk) * DIM + d) * NST;
  for (int n = 0; n < NST; ++n) h[n] = Hinit[hbase + n];
  unsigned short* up = &u_arr[(dtbase + t0) * DIM + d];
  const unsigned short* dtp = &dt_arr[(dtbase + t0) * DIM + d];
  unsigned short* yc = &ycomb[((size_t)b * L_SEQ + t0) * DIM + d];

#define P2_GRP(FASTA)                                                      \
  for (int t8 = 0; t8 < CLH; t8 += 8) {                                    \
    float uu[8], dd[8];                                                    \
    for (int j = 0; j < 8; ++j) {                                          \
      uu[j] = bf2f(up[(size_t)j * DIM]);                                   \
      dd[j] = bf2f(dtp[(size_t)j * DIM]);                                  \
    }                                                                      \
    for (int j = 0; j < 8; ++j) {                                          \
      const float* row = dblS[t8 + j];                                     \
      float u = uu[j], dtv = dd[j];                                        \
      float du = dtv * u;                                                  \
      DA8(FASTA)                                                           \
      float4 B0 = *(const float4*)(row);                                   \
      float4 B1 = *(const float4*)(row + 4);                               \
      float4 C0 = *(const float4*)(row + 8);                               \
      float4 C1 = *(const float4*)(row + 12);                              \
      h[0] = dA[0] * h[0] + du * B0.x; h[1] = dA[1] * h[1] + du * B0.y;    \
      h[2] = dA[2] * h[2] + du * B0.z; h[3] = dA[3] * h[3] + du * B0.w;    \
      h[4] = dA[4] * h[4] + du * B1.x; h[5] = dA[5] * h[5] + du * B1.y;    \
      h[6] = dA[6] * h[6] + du * B1.z; h[7] = dA[7] * h[7] + du * B1.w;    \
      float y = C0.x * h[0] + C0.y * h[1] + C0.z * h[2] + C0.w * h[3] +    \
                C1.x * h[4] + C1.y * h[5] + C1.z * h[6] + C1.w * h[7] +    \
                u * Dv;                                                    \
      if (dir == 0) yc[(size_t)j * DIM] = f2bf(y);                         \
      else          up[(size_t)j * DIM] = f2bf(y);                         \
    }                                                                      \
    up += 8 * DIM; dtp += 8 * DIM; yc += 8 * DIM;                          \
  }

#define P2_STEP(FASTA)                                                     \
  {                                                                        \
    int t = t0 + tl;                                                       \
    const float* row = dblS[tl];                                           \
    float u, dtv;                                                          \
    {                                                                      \
      float xin = loadx(t);                                                \
      float pre = w0 * xm3 + w1 * xm2 + w2 * xm1 + w3 * xin + bias;        \
      u = pre * rcpf(1.f + __expf(-pre));                                  \
      xm3 = xm2; xm2 = xm1; xm1 = xin;                                     \
      float4 q0 = *(const float4*)(row);                                   \
      float4 q1 = *(const float4*)(row + 4);                               \
      float4 q2 = *(const float4*)(row + 8);                               \
      float4 q3 = *(const float4*)(row + 12);                              \
      float xdt = dbias + q0.x * dwreg[0] + q0.y * dwreg[1] +              \
                  q0.z * dwreg[2] + q0.w * dwreg[3] + q1.x * dwreg[4] +    \
                  q1.y * dwreg[5] + q1.z * dwreg[6] + q1.w * dwreg[7] +    \
                  q2.x * dwreg[8] + q2.y * dwreg[9] + q2.z * dwreg[10] +   \
                  q2.w * dwreg[11] + q3.x * dwreg[12] + q3.y * dwreg[13] + \
                  q3.z * dwreg[14] + q3.w * dwreg[15];                     \
      dtv = (xdt > 15.f) ? xdt : __logf(1.f + __expf(xdt));                \
    }                                                                      \
    float du = dtv * u;                                                    \
    DA8(FASTA)                                                             \
    float4 B0 = *(const float4*)(row + 16);                                \
    float4 B1 = *(const float4*)(row + 20);                                \
    float4 C0 = *(const float4*)(row + 24);                                \
    float4 C1 = *(const float4*)(row + 28);                                \
    h[0] = dA[0] * h[0] + du * B0.x; h[1] = dA[1] * h[1] + du * B0.y;      \
    h[2] = dA[2] * h[2] + du * B0.z; h[3] = dA[3] * h[3] + du * B0.w;      \
    h[4] = dA[4] * h[4] + du * B1.x; h[5] = dA[5] * h[5] + du * B1.y;      \
    h[6] = dA[6] * h[6] + du * B1.z; h[7] = dA[7] * h[7] + du * B1.w;      \
    float y = C0.x * h[0] + C0.y * h[1] + C0.z * h[2] + C0.w * h[3] +      \
              C1.x * h[4] + C1.y * h[5] + C1.z * h[6] + C1.w * h[7] +      \
              u * Dv;                                                      \
    if (dir == 0) {                                                        \
      ycomb[((size_t)b * L_SEQ + t) * DIM + d] = f2bf(y);                  \
    } else {                                                               \
      size_t o = ((size_t)b * L_SEQ + (L_SEQ - 1 - t)) * DIM + d;          \
      float prev = bf2f(ycomb[o]);                                         \
      ycomb[o] = f2bf(0.5f * (prev + y));                                  \
    }                                                                      \
  }

  if (MODE) {
    if (fastA) { P2_GRP(1) } else { P2_GRP(0) }
  } else {
    if (fastA) {
      for (int tl = 0; tl < CLH; ++tl) P2_STEP(1)
    } else {
      for (int tl = 0; tl < CLH; ++tl) P2_STEP(0)
    }
  }
#undef P2_STEP
#undef P2_GRP
}

// ------- combine: v=(yf+yb)/2 (MERGED) or v=ycomb; LN*silu(z) -> xz x-cols --
template <int MERGED>
__global__ __launch_bounds__(256) void combine_ln(
    const unsigned short* __restrict__ ycomb,
    const unsigned short* __restrict__ ybu,
    unsigned short* __restrict__ xz,
    const float* __restrict__ onw, const float* __restrict__ onb) {
  int m = blockIdx.x * 4 + (threadIdx.x >> 6);
  int lane = threadIdx.x & 63;
  ushort4 y4 = *(const ushort4*)&ycomb[(size_t)m * DIM + lane * 4];
  float v0 = bf2f(y4.x), v1 = bf2f(y4.y), v2 = bf2f(y4.z), v3 = bf2f(y4.w);
  if (MERGED) {
    int b = m >> 14, l = m & (L_SEQ - 1);
    size_t fo = ((size_t)S_TOT + ((size_t)b << 14) + (L_SEQ - 1 - l)) * DIM +
                lane * 4;
    ushort4 yb4 = *(const ushort4*)&ybu[fo];
    v0 = 0.5f * (v0 + bf2f(yb4.x)); v1 = 0.5f * (v1 + bf2f(yb4.y));
    v2 = 0.5f * (v2 + bf2f(yb4.z)); v3 = 0.5f * (v3 + bf2f(yb4.w));
  }
  float s = v0 + v1 + v2 + v3;
  float s2 = v0 * v0 + v1 * v1 + v2 * v2 + v3 * v3;
  for (int off = 32; off; off >>= 1) {
    s += __shfl_xor(s, off);
    s2 += __shfl_xor(s2, off);
  }
  float mean = s * (1.0f / DIM);
  float var = s2 * (1.0f / DIM) - mean * mean;
  float rstd = rsqrtf(var + 1e-5f);
  ushort4 z4 = *(const ushort4*)&xz[(size_t)m * 512 + 256 + lane * 4];
  float zf[4] = {bf2f(z4.x), bf2f(z4.y), bf2f(z4.z), bf2f(z4.w)};
  float vf[4] = {v0, v1, v2, v3};
  ushort4 out;
  unsigned short* op = (unsigned short*)&out;
  for (int j = 0; j < 4; ++j) {
    int c = lane * 4 + j;
    float ln = (vf[j] - mean) * rstd * onw[c] + onb[c];
    op[j] = f2bf(ln * (zf[j] * rcpf(1.f + __expf(-zf[j]))));
  }
  *(ushort4*)&xz[(size_t)m * 512 + lane * 4] = out;
}

extern "C" void kernel_launch(void* const* d_in, const int* in_sizes, int n_in,
                              void* d_out, int out_size, void* d_ws, size_t ws_size,
                              hipStream_t stream) {
  const float* input0 = (const float*)d_in[0];
  const float* input1 = (const float*)d_in[1];
  const float* norm0_w = (const float*)d_in[2];
  const float* norm0_b = (const float*)d_in[3];
  const float* norm1_w = (const float*)d_in[4];
  const float* norm1_b = (const float*)d_in[5];
  const float* in_proj_w = (const float*)d_in[6];
  const float* in_proj_extra_w = (const float*)d_in[7];
  const float* convx_w = (const float*)d_in[8];
  const float* convx_b = (const float*)d_in[9];
  const float* conve_w = (const float*)d_in[10];
  const float* conve_b = (const float*)d_in[11];
  const float* convx_w_r = (const float*)d_in[12];
  const float* convx_b_r = (const float*)d_in[13];
  const float* conve_w_r = (const float*)d_in[14];
  const float* conve_b_r = (const float*)d_in[15];
  const float* xproj_w = (const float*)d_in[16];
  const float* xproj_w_r = (const float*)d_in[17];
  const float* dtproj_w = (const float*)d_in[18];
  const float* dtproj_b = (const float*)d_in[19];
  const float* dtproj_w_r = (const float*)d_in[20];
  const float* dtproj_b_r = (const float*)d_in[21];
  const float* A_log = (const float*)d_in[22];
  const float* A_log_r = (const float*)d_in[23];
  const float* Dp = (const float*)d_in[24];
  const float* Dp_r = (const float*)d_in[25];
  const float* outnorm_w = (const float*)d_in[26];
  const float* outnorm_b = (const float*)d_in[27];
  const float* outproj_w = (const float*)d_in[28];

  // ---- workspace layout (bytes); base 76,021,760 + tier B 67,108,864 ----
  char* w = (char*)d_ws;
  unsigned short* xz    = (unsigned short*)(w + 0);          // 33,554,432 B
  unsigned short* h0    = (unsigned short*)(w + 33554432);   // 16,777,216 B
  unsigned short* ycomb = (unsigned short*)(w + 33554432);   // same region, later
  float* Qc   = (float*)(w + 33554432);                      // pass1->mid
  unsigned short* xe    = (unsigned short*)(w + 50331648);   // 16,777,216 B
  float* Pc   = (float*)(w + 50331648);                      // aliases xe after xproj
  unsigned short* dbl2 = (unsigned short*)(w + 67108864);    // 4,194,304 B (bf16)
  unsigned short* wb = (unsigned short*)(w + 75497472);      // 524,288 B bf16 weights
  unsigned short* wb_in  = wb;
  unsigned short* wb_ex  = wb + 131072;
  unsigned short* wb_out = wb + 196608;
  unsigned short* u_arr  = (unsigned short*)(w + 76021760);  // 33,554,432 B (tier B)
  unsigned short* dt_arr = (unsigned short*)(w + 109576192); // 33,554,432 B (tier B)
  const bool big = ws_size >= 76021760ULL + 67108864ULL;     // 143,130,624
  // h1: tier B -> parked in u_arr region (dead until dtu); tier A -> xz region
  unsigned short* h1 = big ? u_arr : xz;

  ln_norm<<<dim3(S_TOT / 4, 2), 256, 0, stream>>>(
      input0, input1, norm0_w, norm0_b, norm1_w, norm1_b, h0, h1,
      in_proj_w, in_proj_extra_w, outproj_w, wb);
  if (big) {
    gemm_in<<<dim3(12, 512), 256, 0, stream>>>(h0, h1, wb_in, wb_ex, xz, xe);
  } else {
    gemm64<1, 0><<<dim3(4, 512), 256, 0, stream>>>(h1, DIM, wb_ex, xe, nullptr, 256);
    gemm64<1, 0><<<dim3(8, 512), 256, 0, stream>>>(h0, DIM, wb_in, xz, nullptr, 512);
  }
  xproj_mfma<<<dim3(512, 2), 256, 0, stream>>>(
      xe, conve_w, conve_b, conve_w_r, conve_b_r, xproj_w, xproj_w_r, dbl2);
  if (big) {
    dtu_compute<<<dim3(2048), 256, 0, stream>>>(
        dbl2, dtproj_w, dtproj_w_r, dtproj_b, dtproj_b_r, dt_arr,
        xz, convx_w, convx_b, convx_w_r, convx_b_r, u_arr);
    scan_pass1<1><<<dim3(NCH, 2, 2), 256, 0, stream>>>(
        xz, dbl2, u_arr, dt_arr, convx_w, convx_b, convx_w_r, convx_b_r,
        dtproj_w, dtproj_b, dtproj_w_r, dtproj_b_r, A_log, A_log_r, Pc, Qc);
  } else {
    scan_pass1<0><<<dim3(NCH, 2, 2), 256, 0, stream>>>(
        xz, dbl2, u_arr, dt_arr, convx_w, convx_b, convx_w_r, convx_b_r,
        dtproj_w, dtproj_b, dtproj_w_r, dtproj_b_r, A_log, A_log_r, Pc, Qc);
  }
  scan_mid<<<dim3(32), 256, 0, stream>>>(Pc, Qc);
  if (big) {
    scan_pass2<1><<<dim3(NCH, 2, 2), 256, 0, stream>>>(
        xz, dbl2, u_arr, dt_arr, convx_w, convx_b, convx_w_r, convx_b_r,
        dtproj_w, dtproj_b, dtproj_w_r, dtproj_b_r, A_log, A_log_r,
        Dp, Dp_r, Pc, ycomb, 0);
    combine_ln<1><<<dim3(S_TOT / 4), 256, 0, stream>>>(
        ycomb, u_arr, xz, outnorm_w, outnorm_b);
  } else {
    for (int dir = 0; dir < 2; ++dir)
      scan_pass2<0><<<dim3(NCH, 2), 256, 0, stream>>>(
          xz, dbl2, u_arr, dt_arr, convx_w, convx_b, convx_w_r, convx_b_r,
          dtproj_w, dtproj_b, dtproj_w_r, dtproj_b_r, A_log, A_log_r,
          Dp, Dp_r, Pc, ycomb, dir);
    combine_ln<0><<<dim3(S_TOT / 4), 256, 0, stream>>>(
        ycomb, nullptr, xz, outnorm_w, outnorm_b);
  }
  gemm64<0, 1><<<dim3(4, 512), 256, 0, stream>>>(
      xz, 512, wb_out, d_out, input0, 256);
}

// Round 22
// 207.725 us; speedup vs baseline: 1.1450x; 1.0339x over previous
//
#include <hip/hip_runtime.h>
#include <math.h>

#define L_SEQ 16384
#define DIM 256
#define NST 8
#define RNK 16
#define S_TOT 32768   // B*L
#define NCH 512
#define CLH 32

typedef __attribute__((ext_vector_type(8))) short bf16x8;
typedef __attribute__((ext_vector_type(4))) float f32x4;

__device__ __forceinline__ float bf2f(unsigned short u) {
  union { unsigned int i; float f; } v; v.i = ((unsigned int)u) << 16; return v.f;
}
__device__ __forceinline__ unsigned short f2bf(float x) {
  union { float f; unsigned int i; } v; v.f = x;
  unsigned int r = v.i + 0x7fffu + ((v.i >> 16) & 1u);
  return (unsigned short)(r >> 16);
}
__device__ __forceinline__ float rcpf(float x) {
  return __builtin_amdgcn_rcpf(x);
}

// ---- fused LayerNorm -> bf16 (wave/row, 4 rows/blk) + weight conversion ----
__global__ __launch_bounds__(256) void ln_norm(
    const float* __restrict__ in0, const float* __restrict__ in1,
    const float* __restrict__ w0, const float* __restrict__ b0,
    const float* __restrict__ w1, const float* __restrict__ b1,
    unsigned short* __restrict__ h0, unsigned short* __restrict__ h1,
    const float* __restrict__ pw0, const float* __restrict__ pw1,
    const float* __restrict__ pw2, unsigned short* __restrict__ wbout) {
  int which = blockIdx.y;
  if (which == 0 && blockIdx.x < 1024) {
    int i = blockIdx.x * 256 + threadIdx.x;
    if (i < 131072) wbout[i] = f2bf(pw0[i]);
    else if (i < 196608) wbout[i] = f2bf(pw1[i - 131072]);
    else wbout[i] = f2bf(pw2[i - 196608]);
  }
  int row = blockIdx.x * 4 + (threadIdx.x >> 6);
  int lane = threadIdx.x & 63;
  const float* x = (which ? in1 : in0) + (size_t)row * DIM;
  const float* w = which ? w1 : w0;
  const float* b = which ? b1 : b0;
  unsigned short* h = which ? h1 : h0;
  float4 v = *(const float4*)&x[lane * 4];
  float s = v.x + v.y + v.z + v.w;
  float s2 = v.x * v.x + v.y * v.y + v.z * v.z + v.w * v.w;
  for (int off = 32; off; off >>= 1) {
    s += __shfl_xor(s, off);
    s2 += __shfl_xor(s2, off);
  }
  float mean = s * (1.0f / DIM);
  float var = s2 * (1.0f / DIM) - mean * mean;
  float rstd = rsqrtf(var + 1e-5f);
  float4 wv = *(const float4*)&w[lane * 4];
  float4 bv = *(const float4*)&b[lane * 4];
  ushort4 out;
  out.x = f2bf((v.x - mean) * rstd * wv.x + bv.x);
  out.y = f2bf((v.y - mean) * rstd * wv.y + bv.y);
  out.z = f2bf((v.z - mean) * rstd * wv.z + bv.z);
  out.w = f2bf((v.w - mean) * rstd * wv.w + bv.w);
  *(ushort4*)&h[(size_t)row * DIM + lane * 4] = out;
}

// ------- streaming bf16 GEMM, 64x64 tile, full K=256 staged once -------
template <int BF16C, int ADDIN>
__global__ __launch_bounds__(256) void gemm64(
    const unsigned short* __restrict__ A, int lda,
    const unsigned short* __restrict__ Wb,
    void* __restrict__ Cv, const float* __restrict__ addp, int Nn) {
  __shared__ unsigned short As[64 * 256];
  __shared__ unsigned short Ws[64 * 256];
  int tid = threadIdx.x;
  int n0 = blockIdx.x * 64, m0 = blockIdx.y * 64;
  for (int i = 0; i < 8; ++i) {
    int f8 = tid + i * 256;
    int r = f8 >> 5, c8 = (f8 & 31) * 8;
    int sc = c8 ^ ((r & 7) << 3);
    *(uint4*)&As[r * 256 + sc] = *(const uint4*)&A[(size_t)(m0 + r) * lda + c8];
    *(uint4*)&Ws[r * 256 + sc] = *(const uint4*)&Wb[(size_t)(n0 + r) * 256 + c8];
  }
  __syncthreads();
  int wid = tid >> 6, lane = tid & 63;
  int wm = wid >> 1, wn = wid & 1;
  int l15 = lane & 15, lk = (lane >> 4) * 8;
  f32x4 acc[2][2] = {};
  for (int ks = 0; ks < 8; ++ks) {
    int kcol = ks * 32 + lk;
    bf16x8 af[2], bf_[2];
    for (int mf = 0; mf < 2; ++mf) {
      int row = wm * 32 + mf * 16 + l15;
      af[mf] = *(const bf16x8*)&As[row * 256 + (kcol ^ ((row & 7) << 3))];
    }
    for (int nf = 0; nf < 2; ++nf) {
      int row = wn * 32 + nf * 16 + l15;
      bf_[nf] = *(const bf16x8*)&Ws[row * 256 + (kcol ^ ((row & 7) << 3))];
    }
    for (int mf = 0; mf < 2; ++mf)
      for (int nf = 0; nf < 2; ++nf)
        acc[mf][nf] = __builtin_amdgcn_mfma_f32_16x16x32_bf16(
            af[mf], bf_[nf], acc[mf][nf], 0, 0, 0);
  }
  for (int mf = 0; mf < 2; ++mf)
    for (int nf = 0; nf < 2; ++nf) {
      int row = m0 + wm * 32 + mf * 16 + (lane >> 4) * 4;
      int col = n0 + wn * 32 + nf * 16 + l15;
      for (int v = 0; v < 4; ++v) {
        size_t off = (size_t)(row + v) * Nn + col;
        float val = acc[mf][nf][v];
        if (ADDIN) val += addp[off];
        if (BF16C) ((unsigned short*)Cv)[off] = f2bf(val);
        else       ((float*)Cv)[off] = val;
      }
    }
}

// ---- input GEMMs, A-resident: block owns one A-panel, loops n-tiles ------
// blocks 0..511: xz = h0 @ wb_in^T (8 n-tiles); 512..1023: xe = h1 @ wb_ex^T (4)
__global__ __launch_bounds__(256) void gemm_in2(
    const unsigned short* __restrict__ h0, const unsigned short* __restrict__ h1,
    const unsigned short* __restrict__ wb_in, const unsigned short* __restrict__ wb_ex,
    unsigned short* __restrict__ xzOut, unsigned short* __restrict__ xeOut) {
  __shared__ unsigned short As[64 * 256];
  __shared__ unsigned short Ws[64 * 256];
  int tid = threadIdx.x;
  bool isX = blockIdx.x < 512;
  const unsigned short* A = isX ? h0 : h1;
  const unsigned short* Wb = isX ? wb_in : wb_ex;
  unsigned short* Cv = isX ? xzOut : xeOut;
  int Nn = isX ? 512 : 256;
  int NT = isX ? 8 : 4;
  int m0 = (isX ? (int)blockIdx.x : (int)blockIdx.x - 512) * 64;
  // stage A once (first loop barrier covers it)
  for (int i = 0; i < 8; ++i) {
    int f8 = tid + i * 256;
    int r = f8 >> 5, c8 = (f8 & 31) * 8;
    int sc = c8 ^ ((r & 7) << 3);
    *(uint4*)&As[r * 256 + sc] = *(const uint4*)&A[(size_t)(m0 + r) * 256 + c8];
  }
  int wid = tid >> 6, lane = tid & 63;
  int wm = wid >> 1, wn = wid & 1;
  int l15 = lane & 15, lk = (lane >> 4) * 8;
  for (int nt = 0; nt < NT; ++nt) {
    int n0 = nt * 64;
    for (int i = 0; i < 8; ++i) {
      int f8 = tid + i * 256;
      int r = f8 >> 5, c8 = (f8 & 31) * 8;
      int sc = c8 ^ ((r & 7) << 3);
      *(uint4*)&Ws[r * 256 + sc] = *(const uint4*)&Wb[(size_t)(n0 + r) * 256 + c8];
    }
    __syncthreads();
    f32x4 acc[2][2] = {};
    for (int ks = 0; ks < 8; ++ks) {
      int kcol = ks * 32 + lk;
      bf16x8 af[2], bf_[2];
      for (int mf = 0; mf < 2; ++mf) {
        int row = wm * 32 + mf * 16 + l15;
        af[mf] = *(const bf16x8*)&As[row * 256 + (kcol ^ ((row & 7) << 3))];
      }
      for (int nf = 0; nf < 2; ++nf) {
        int row = wn * 32 + nf * 16 + l15;
        bf_[nf] = *(const bf16x8*)&Ws[row * 256 + (kcol ^ ((row & 7) << 3))];
      }
      for (int mf = 0; mf < 2; ++mf)
        for (int nf = 0; nf < 2; ++nf)
          acc[mf][nf] = __builtin_amdgcn_mfma_f32_16x16x32_bf16(
              af[mf], bf_[nf], acc[mf][nf], 0, 0, 0);
    }
    for (int mf = 0; mf < 2; ++mf)
      for (int nf = 0; nf < 2; ++nf) {
        int row = m0 + wm * 32 + mf * 16 + (lane >> 4) * 4;
        int col = n0 + wn * 32 + nf * 16 + l15;
        for (int v = 0; v < 4; ++v) {
          size_t off = (size_t)(row + v) * Nn + col;
          Cv[off] = f2bf(acc[mf][nf][v]);
        }
      }
    __syncthreads();
  }
}

// -------- conv(xe)+silu -> MFMA projection to dbl(32) bf16, 64 rows/block --
__global__ __launch_bounds__(256) void xproj_mfma(
    const unsigned short* __restrict__ xe,
    const float* __restrict__ conve_w, const float* __restrict__ conve_b,
    const float* __restrict__ conve_w_r, const float* __restrict__ conve_b_r,
    const float* __restrict__ xproj_w, const float* __restrict__ xproj_w_r,
    unsigned short* __restrict__ dbl2) {
  __shared__ unsigned short ecS[64 * 256];
  __shared__ unsigned short xwS[32 * 256];
  int chunk = blockIdx.x;
  int dir = blockIdx.y;
  int b = chunk >> 8;
  int t0 = (chunk & 255) * 64;
  int tid = threadIdx.x;
  const float* cw = dir ? conve_w_r : conve_w;
  const float* cb = dir ? conve_b_r : conve_b;
  const float* xw = dir ? xproj_w_r : xproj_w;

  for (int i = tid; i < 32 * 256; i += 256) {
    int o = i >> 8, dd = i & 255;
    xwS[o * 256 + (((dd & ~7) ^ ((o & 7) << 3)) | (dd & 7))] = f2bf(xw[i]);
  }

  {
    int c = tid;
    float w0 = cw[c * 4 + 0], w1 = cw[c * 4 + 1], w2 = cw[c * 4 + 2],
          w3 = cw[c * 4 + 3], bias = cb[c];
    size_t bL = (size_t)b * L_SEQ;
    auto loadx = [&](int t) -> float {
      if (t < 0) return 0.f;
      int src = dir ? (L_SEQ - 1 - t) : t;
      return bf2f(xe[(bL + src) * DIM + c]);
    };
    float xm3 = loadx(t0 - 3), xm2 = loadx(t0 - 2), xm1 = loadx(t0 - 1);
    const unsigned short* xp =
        &xe[(bL + (dir ? (L_SEQ - 1 - t0) : t0)) * DIM + c];
    int xstep = dir ? -DIM : DIM;
    int cbase = c & ~7, clow = c & 7;
    for (int t4 = 0; t4 < 64; t4 += 4) {
      float xin4[4];
      for (int j = 0; j < 4; ++j) xin4[j] = bf2f(xp[(ptrdiff_t)j * xstep]);
      xp += (ptrdiff_t)4 * xstep;
      for (int j = 0; j < 4; ++j) {
        int tl = t4 + j;
        float xin = xin4[j];
        float pre = w0 * xm3 + w1 * xm2 + w2 * xm1 + w3 * xin + bias;
        float u = pre * rcpf(1.f + __expf(-pre));
        xm3 = xm2; xm2 = xm1; xm1 = xin;
        ecS[tl * 256 + ((cbase ^ ((tl & 7) << 3)) | clow)] = f2bf(u);
      }
    }
  }
  __syncthreads();

  int wid = tid >> 6, lane = tid & 63;
  int l15 = lane & 15, lk = (lane >> 4) * 8;
  f32x4 acc[2] = {};
  for (int kk = 0; kk < 8; ++kk) {
    int kcol = kk * 32 + lk;
    int row = wid * 16 + l15;
    bf16x8 af = *(const bf16x8*)&ecS[row * 256 + (kcol ^ ((row & 7) << 3))];
    for (int ni = 0; ni < 2; ++ni) {
      int o = ni * 16 + l15;
      bf16x8 bfr = *(const bf16x8*)&xwS[o * 256 + (kcol ^ ((o & 7) << 3))];
      acc[ni] = __builtin_amdgcn_mfma_f32_16x16x32_bf16(af, bfr, acc[ni], 0, 0, 0);
    }
  }
  size_t mbase = (size_t)dir * S_TOT + (size_t)chunk * 64;
  int rloc = wid * 16 + (lane >> 4) * 4;
  for (int ni = 0; ni < 2; ++ni) {
    int o = ni * 16 + l15;
    for (int v = 0; v < 4; ++v)
      dbl2[(mbase + rloc + v) * 32 + o] = f2bf(acc[ni][v]);
  }
}

// ---- merged: blocks 0..1023 = dt_mfma; blocks 1024..2047 = u_compute ------
__global__ __launch_bounds__(256) void dtu_compute(
    const unsigned short* __restrict__ dbl2,
    const float* __restrict__ dtw, const float* __restrict__ dtw_r,
    const float* __restrict__ dtb, const float* __restrict__ dtb_r,
    unsigned short* __restrict__ dt_arr,
    const unsigned short* __restrict__ xz,
    const float* __restrict__ convx_w, const float* __restrict__ convx_b,
    const float* __restrict__ convx_w_r, const float* __restrict__ convx_b_r,
    unsigned short* __restrict__ u_arr) {
  __shared__ unsigned short dtwS[256 * 32];
  __shared__ unsigned short dtrS[64 * 32];
  __shared__ unsigned short outS[64 * 256];
  int tid = threadIdx.x;
  if (blockIdx.x < 1024) {
    int m0 = blockIdx.x * 64;
    int dir = (blockIdx.x >= 512) ? 1 : 0;
    const float* dw = dir ? dtw_r : dtw;
    const float* db = dir ? dtb_r : dtb;
    {
      uint4 z; z.x = 0; z.y = 0; z.z = 0; z.w = 0;
      for (int i = tid; i < 1280; i += 256) {
        if (i < 1024) ((uint4*)dtwS)[i] = z;
        else          ((uint4*)dtrS)[i - 1024] = z;
      }
    }
    __syncthreads();
    for (int it = 0; it < 4; ++it) {
      int idx = tid + it * 256;
      int c = idx >> 2, k4 = idx & 3;
      float4 v = *(const float4*)&dw[c * 16 + k4 * 4];
      uint2 pk;
      pk.x = (unsigned int)f2bf(v.x) | ((unsigned int)f2bf(v.y) << 16);
      pk.y = (unsigned int)f2bf(v.z) | ((unsigned int)f2bf(v.w) << 16);
      int byte = c * 64 + (((k4 >> 1) ^ (c & 3)) << 4) + ((k4 & 1) << 3);
      *(uint2*)((char*)dtwS + byte) = pk;
    }
    {
      int r = tid >> 2, k4 = tid & 3;
      uint2 pk = *(const uint2*)&dbl2[(size_t)(m0 + r) * 32 + k4 * 4];
      int byte = r * 64 + (((k4 >> 1) ^ (r & 3)) << 4) + ((k4 & 1) << 3);
      *(uint2*)((char*)dtrS + byte) = pk;
    }
    __syncthreads();
    int wid = tid >> 6, lane = tid & 63;
    int l15 = lane & 15, lkc = lane >> 4;
    bf16x8 af[4];
    for (int mi = 0; mi < 4; ++mi) {
      int r = mi * 16 + l15;
      af[mi] = *(const bf16x8*)((char*)dtrS + r * 64 + ((lkc ^ (r & 3)) << 4));
    }
    f32x4 acc[4][4] = {};
    for (int ni = 0; ni < 4; ++ni) {
      int c = (wid * 4 + ni) * 16 + l15;
      bf16x8 bfr = *(const bf16x8*)((char*)dtwS + c * 64 + ((lkc ^ (c & 3)) << 4));
      for (int mi = 0; mi < 4; ++mi)
        acc[mi][ni] = __builtin_amdgcn_mfma_f32_16x16x32_bf16(
            af[mi], bfr, acc[mi][ni], 0, 0, 0);
    }
    for (int ni = 0; ni < 4; ++ni) {
      int c = (wid * 4 + ni) * 16 + l15;
      float bias_ = db[c];
      int cb_ = c & ~7, cl_ = c & 7;
      for (int mi = 0; mi < 4; ++mi) {
        int rb = mi * 16 + (lane >> 4) * 4;
        for (int v = 0; v < 4; ++v) {
          int r = rb + v;
          float xdt = acc[mi][ni][v] + bias_;
          float dtv = (xdt > 15.f) ? xdt : __logf(1.f + __expf(xdt));
          outS[r * 256 + ((cb_ ^ ((r & 7) << 3)) | cl_)] = f2bf(dtv);
        }
      }
    }
    __syncthreads();
    for (int it = 0; it < 8; ++it) {
      int i = tid + it * 256;
      int r = i >> 5, cg = (i & 31) * 8;
      uint4 val = *(const uint4*)&outS[r * 256 + (cg ^ ((r & 7) << 3))];
      *(uint4*)&dt_arr[(size_t)(m0 + r) * 256 + cg] = val;
    }
  } else {
    int chunk = blockIdx.x - 1024;
    int b = chunk >> 9;
    int t0 = (chunk & 511) * 32;
    int c = tid;
    float w0 = convx_w[c * 4 + 0], w1 = convx_w[c * 4 + 1],
          w2 = convx_w[c * 4 + 2], w3 = convx_w[c * 4 + 3], bias = convx_b[c];
    float w0r = convx_w_r[c * 4 + 0], w1r = convx_w_r[c * 4 + 1],
          w2r = convx_w_r[c * 4 + 2], w3r = convx_w_r[c * 4 + 3],
          biasr = convx_b_r[c];
    size_t bL = (size_t)b * L_SEQ;
    auto ld = [&](int t) -> float {
      if (t < 0 || t >= L_SEQ) return 0.f;
      return bf2f(xz[(bL + t) * 512 + c]);
    };
    float x3 = ld(t0 - 3), x2 = ld(t0 - 2), x1 = ld(t0 - 1);
    unsigned short* op0 = &u_arr[(bL + t0) * DIM + c];
    unsigned short* op1 =
        &u_arr[((size_t)S_TOT + bL + (L_SEQ - 1 - t0)) * DIM + c];
    for (int tg = 0; tg < 36; tg += 4) {
      float xin4[4];
      for (int j = 0; j < 4; ++j) xin4[j] = ld(t0 + tg + j);
      for (int j = 0; j < 4; ++j) {
        int tl = tg + j;
        float xin = xin4[j];
        if (tl < 32) {
          float pre = w0 * x3 + w1 * x2 + w2 * x1 + w3 * xin + bias;
          op0[(size_t)tl * DIM] = f2bf(pre * rcpf(1.f + __expf(-pre)));
        }
        if (tl >= 3 && tl < 35) {
          float prer = w0r * xin + w1r * x1 + w2r * x2 + w3r * x3 + biasr;
          int s = tl - 3;
          *(op1 - (ptrdiff_t)s * DIM) = f2bf(prer * rcpf(1.f + __expf(-prer)));
        }
        x3 = x2; x2 = x1; x1 = xin;
      }
    }
  }
}

// dA[0..7] = exp(dtv*Ar[n]); FASTA: Ar[n] == -(n+1) verified
#define DA8(FASTA)                                                    \
  float dA[NST];                                                      \
  if (FASTA) {                                                        \
    float e1 = __expf(-dtv);                                          \
    dA[0] = e1;                                                       \
    for (int n = 1; n < NST; ++n) dA[n] = dA[n - 1] * e1;             \
  } else {                                                            \
    for (int n = 0; n < NST; ++n) dA[n] = __expf(dtv * Ar[n]);        \
  }

// ---------------- scan pass 1: per-chunk affine summaries ----------------
template <int USE_UDT>
__global__ __launch_bounds__(256) void scan_pass1(
    const unsigned short* __restrict__ xz, const unsigned short* __restrict__ dbl2,
    const unsigned short* __restrict__ u_arr,
    const unsigned short* __restrict__ dt_arr,
    const float* __restrict__ convx_w, const float* __restrict__ convx_b,
    const float* __restrict__ convx_w_r, const float* __restrict__ convx_b_r,
    const float* __restrict__ dtproj_w, const float* __restrict__ dtproj_b,
    const float* __restrict__ dtproj_w_r, const float* __restrict__ dtproj_b_r,
    const float* __restrict__ A_log, const float* __restrict__ A_log_r,
    float* __restrict__ Pc, float* __restrict__ Qc) {
  int chunk = blockIdx.x, b = blockIdx.y, dir = blockIdx.z;
  int d = threadIdx.x;
  const float* al = dir ? A_log_r : A_log;
  float w0 = 0.f, w1 = 0.f, w2 = 0.f, w3 = 0.f, bias = 0.f, dbias = 0.f;
  float dwreg[RNK];
  if (!USE_UDT) {
    const float* cw = dir ? convx_w_r : convx_w;
    const float* cb = dir ? convx_b_r : convx_b;
    const float* dw = dir ? dtproj_w_r : dtproj_w;
    const float* dbp = dir ? dtproj_b_r : dtproj_b;
    w0 = cw[d * 4 + 0]; w1 = cw[d * 4 + 1]; w2 = cw[d * 4 + 2];
    w3 = cw[d * 4 + 3]; bias = cb[d]; dbias = dbp[d];
    for (int r = 0; r < RNK; ++r) dwreg[r] = dw[d * RNK + r];
  }
  float Ar[NST];
  bool fa = true;
  for (int n = 0; n < NST; ++n) {
    Ar[n] = -__expf(al[d * NST + n]);
    fa = fa && (fabsf(Ar[n] + (float)(n + 1)) < 1e-4f * (float)(n + 1));
  }
  bool fastA = (__ballot(fa) == ~0ULL);

  __shared__ float dblS[CLH][32];
  int t0 = chunk * CLH;
  size_t dtbase = (size_t)dir * S_TOT + (size_t)b * L_SEQ;
  if (USE_UDT) {
    int i = d;
    dblS[i >> 3][i & 7] =
        bf2f(dbl2[(dtbase + t0 + (i >> 3)) * 32 + 16 + (i & 7)]);
  } else {
    for (int i = d; i < CLH * 32; i += 256)
      dblS[i >> 5][i & 31] = bf2f(dbl2[(dtbase + t0) * 32 + i]);
  }
  __syncthreads();
  auto loadx = [&](int t) -> float {
    if (t < 0) return 0.f;
    int srct = dir ? (L_SEQ - 1 - t) : t;
    return bf2f(xz[((size_t)b * L_SEQ + srct) * 512 + d]);
  };
  float xm3 = 0.f, xm2 = 0.f, xm1 = 0.f;
  if (!USE_UDT) { xm3 = loadx(t0 - 3); xm2 = loadx(t0 - 2); xm1 = loadx(t0 - 1); }
  const unsigned short* up = &u_arr[(dtbase + t0) * DIM + d];
  const unsigned short* dtp = &dt_arr[(dtbase + t0) * DIM + d];
  float Q[NST];
  for (int n = 0; n < NST; ++n) Q[n] = 0.f;
  float sdt = 0.f;
  const int BOFF = USE_UDT ? 0 : 16;

#define P1_GRP(FASTA)                                                      \
  for (int t8 = 0; t8 < CLH; t8 += 8) {                                    \
    float uu[8], dd[8];                                                    \
    for (int j = 0; j < 8; ++j) {                                          \
      uu[j] = bf2f(up[(size_t)j * DIM]);                                   \
      dd[j] = bf2f(dtp[(size_t)j * DIM]);                                  \
    }                                                                      \
    up += 8 * DIM; dtp += 8 * DIM;                                         \
    for (int j = 0; j < 8; ++j) {                                          \
      const float* row = dblS[t8 + j];                                     \
      float u = uu[j], dtv = dd[j];                                        \
      float du = dtv * u;                                                  \
      sdt += dtv;                                                          \
      DA8(FASTA)                                                           \
      float4 B0 = *(const float4*)(row);                                   \
      float4 B1 = *(const float4*)(row + 4);                               \
      Q[0] = dA[0] * Q[0] + du * B0.x; Q[1] = dA[1] * Q[1] + du * B0.y;    \
      Q[2] = dA[2] * Q[2] + du * B0.z; Q[3] = dA[3] * Q[3] + du * B0.w;    \
      Q[4] = dA[4] * Q[4] + du * B1.x; Q[5] = dA[5] * Q[5] + du * B1.y;    \
      Q[6] = dA[6] * Q[6] + du * B1.z; Q[7] = dA[7] * Q[7] + du * B1.w;    \
    }                                                                      \
  }

#define P1_STEP(FASTA)                                                     \
  {                                                                        \
    const float* row = dblS[tl];                                           \
    float u, dtv;                                                          \
    {                                                                      \
      float xin = loadx(t0 + tl);                                          \
      float pre = w0 * xm3 + w1 * xm2 + w2 * xm1 + w3 * xin + bias;        \
      u = pre * rcpf(1.f + __expf(-pre));                                  \
      xm3 = xm2; xm2 = xm1; xm1 = xin;                                     \
      float4 q0 = *(const float4*)(row);                                   \
      float4 q1 = *(const float4*)(row + 4);                               \
      float4 q2 = *(const float4*)(row + 8);                               \
      float4 q3 = *(const float4*)(row + 12);                              \
      float xdt = dbias + q0.x * dwreg[0] + q0.y * dwreg[1] +              \
                  q0.z * dwreg[2] + q0.w * dwreg[3] + q1.x * dwreg[4] +    \
                  q1.y * dwreg[5] + q1.z * dwreg[6] + q1.w * dwreg[7] +    \
                  q2.x * dwreg[8] + q2.y * dwreg[9] + q2.z * dwreg[10] +   \
                  q2.w * dwreg[11] + q3.x * dwreg[12] + q3.y * dwreg[13] + \
                  q3.z * dwreg[14] + q3.w * dwreg[15];                     \
      dtv = (xdt > 15.f) ? xdt : __logf(1.f + __expf(xdt));                \
    }                                                                      \
    float du = dtv * u;                                                    \
    sdt += dtv;                                                            \
    DA8(FASTA)                                                             \
    float4 B0 = *(const float4*)(row + BOFF);                              \
    float4 B1 = *(const float4*)(row + BOFF + 4);                          \
    Q[0] = dA[0] * Q[0] + du * B0.x; Q[1] = dA[1] * Q[1] + du * B0.y;      \
    Q[2] = dA[2] * Q[2] + du * B0.z; Q[3] = dA[3] * Q[3] + du * B0.w;      \
    Q[4] = dA[4] * Q[4] + du * B1.x; Q[5] = dA[5] * Q[5] + du * B1.y;      \
    Q[6] = dA[6] * Q[6] + du * B1.z; Q[7] = dA[7] * Q[7] + du * B1.w;      \
  }

  if (USE_UDT) {
    if (fastA) { P1_GRP(1) } else { P1_GRP(0) }
  } else {
    if (fastA) {
      for (int tl = 0; tl < CLH; ++tl) P1_STEP(1)
    } else {
      for (int tl = 0; tl < CLH; ++tl) P1_STEP(0)
    }
  }
#undef P1_STEP
#undef P1_GRP

  float P[NST];
  if (fastA) {
    float E = __expf(-sdt);
    P[0] = E;
    for (int n = 1; n < NST; ++n) P[n] = P[n - 1] * E;
  } else {
    for (int n = 0; n < NST; ++n) P[n] = __expf(Ar[n] * sdt);
  }
  size_t obase = ((((size_t)(dir * 2 + b)) * NCH + chunk) * DIM + d) * NST;
  for (int n = 0; n < NST; ++n) { Pc[obase + n] = P[n]; Qc[obase + n] = Q[n]; }
}

// -------- scan mid: sequential over chunk summaries; Hinit in-place in Pc --
__global__ __launch_bounds__(256) void scan_mid(
    float* __restrict__ Pc, const float* __restrict__ Qc) {
  int idx = blockIdx.x * 256 + threadIdx.x;
  int dn = idx & 2047;
  int db_ = idx >> 11;
  size_t base = (size_t)db_ * NCH * 2048 + dn;
  float h = 0.f;
  for (int c0 = 0; c0 < NCH; c0 += 8) {
    size_t off = base + (size_t)c0 * 2048;
    float P[8], Q[8];
#pragma unroll
    for (int j = 0; j < 8; ++j) {
      P[j] = Pc[off + (size_t)j * 2048];
      Q[j] = Qc[off + (size_t)j * 2048];
    }
#pragma unroll
    for (int j = 0; j < 8; ++j) {
      Pc[off + (size_t)j * 2048] = h;
      h = P[j] * h + Q[j];
    }
  }
}

// ---------------- scan pass 2 ----------------
template <int MODE>
__global__ __launch_bounds__(256) void scan_pass2(
    const unsigned short* __restrict__ xz, const unsigned short* __restrict__ dbl2,
    unsigned short* __restrict__ u_arr,
    const unsigned short* __restrict__ dt_arr,
    const float* __restrict__ convx_w, const float* __restrict__ convx_b,
    const float* __restrict__ convx_w_r, const float* __restrict__ convx_b_r,
    const float* __restrict__ dtproj_w, const float* __restrict__ dtproj_b,
    const float* __restrict__ dtproj_w_r, const float* __restrict__ dtproj_b_r,
    const float* __restrict__ A_log, const float* __restrict__ A_log_r,
    const float* __restrict__ Dp, const float* __restrict__ Dp_r,
    const float* __restrict__ Hinit, unsigned short* __restrict__ ycomb,
    int dirParam) {
  int chunk = blockIdx.x, b = blockIdx.y;
  int dir = MODE ? blockIdx.z : dirParam;
  int d = threadIdx.x;
  const float* al = dir ? A_log_r : A_log;
  float Dv = (dir ? Dp_r : Dp)[d];
  float w0 = 0.f, w1 = 0.f, w2 = 0.f, w3 = 0.f, bias = 0.f, dbias = 0.f;
  float dwreg[RNK];
  if (!MODE) {
    const float* cw = dir ? convx_w_r : convx_w;
    const float* cb = dir ? convx_b_r : convx_b;
    const float* dw = dir ? dtproj_w_r : dtproj_w;
    const float* dbp = dir ? dtproj_b_r : dtproj_b;
    w0 = cw[d * 4 + 0]; w1 = cw[d * 4 + 1]; w2 = cw[d * 4 + 2];
    w3 = cw[d * 4 + 3]; bias = cb[d];
    dbias = dbp[d];
    for (int r = 0; r < RNK; ++r) dwreg[r] = dw[d * RNK + r];
  }
  float Ar[NST];
  bool fa = true;
  for (int n = 0; n < NST; ++n) {
    Ar[n] = -__expf(al[d * NST + n]);
    fa = fa && (fabsf(Ar[n] + (float)(n + 1)) < 1e-4f * (float)(n + 1));
  }
  bool fastA = (__ballot(fa) == ~0ULL);

  __shared__ float dblS[CLH][32];
  int t0 = chunk * CLH;
  size_t dtbase = (size_t)dir * S_TOT + (size_t)b * L_SEQ;
  if (MODE) {
    for (int i = d; i < CLH * 16; i += 256)
      dblS[i >> 4][i & 15] =
          bf2f(dbl2[(dtbase + t0 + (i >> 4)) * 32 + 16 + (i & 15)]);
  } else {
    for (int i = d; i < CLH * 32; i += 256)
      dblS[i >> 5][i & 31] = bf2f(dbl2[(dtbase + t0) * 32 + i]);
  }
  __syncthreads();
  auto loadx = [&](int t) -> float {
    if (t < 0) return 0.f;
    int srct = dir ? (L_SEQ - 1 - t) : t;
    return bf2f(xz[((size_t)b * L_SEQ + srct) * 512 + d]);
  };
  float xm3 = 0.f, xm2 = 0.f, xm1 = 0.f;
  if (!MODE) { xm3 = loadx(t0 - 3); xm2 = loadx(t0 - 2); xm1 = loadx(t0 - 1); }
  float h[NST];
  size_t hbase = ((((size_t)(dir * 2 + b)) * NCH + chunk) * DIM + d) * NST;
  for (int n = 0; n < NST; ++n) h[n] = Hinit[hbase + n];
  unsigned short* up = &u_arr[(dtbase + t0) * DIM + d];
  const unsigned short* dtp = &dt_arr[(dtbase + t0) * DIM + d];
  unsigned short* yc = &ycomb[((size_t)b * L_SEQ + t0) * DIM + d];

#define P2_GRP(FASTA)                                                      \
  for (int t8 = 0; t8 < CLH; t8 += 8) {                                    \
    float uu[8], dd[8];                                                    \
    for (int j = 0; j < 8; ++j) {                                          \
      uu[j] = bf2f(up[(size_t)j * DIM]);                                   \
      dd[j] = bf2f(dtp[(size_t)j * DIM]);                                  \
    }                                                                      \
    for (int j = 0; j < 8; ++j) {                                          \
      const float* row = dblS[t8 + j];                                     \
      float u = uu[j], dtv = dd[j];                                        \
      float du = dtv * u;                                                  \
      DA8(FASTA)                                                           \
      float4 B0 = *(const float4*)(row);                                   \
      float4 B1 = *(const float4*)(row + 4);                               \
      float4 C0 = *(const float4*)(row + 8);                               \
      float4 C1 = *(const float4*)(row + 12);                              \
      h[0] = dA[0] * h[0] + du * B0.x; h[1] = dA[1] * h[1] + du * B0.y;    \
      h[2] = dA[2] * h[2] + du * B0.z; h[3] = dA[3] * h[3] + du * B0.w;    \
      h[4] = dA[4] * h[4] + du * B1.x; h[5] = dA[5] * h[5] + du * B1.y;    \
      h[6] = dA[6] * h[6] + du * B1.z; h[7] = dA[7] * h[7] + du * B1.w;    \
      float y = C0.x * h[0] + C0.y * h[1] + C0.z * h[2] + C0.w * h[3] +    \
                C1.x * h[4] + C1.y * h[5] + C1.z * h[6] + C1.w * h[7] +    \
                u * Dv;                                                    \
      if (dir == 0) yc[(size_t)j * DIM] = f2bf(y);                         \
      else          up[(size_t)j * DIM] = f2bf(y);                         \
    }                                                                      \
    up += 8 * DIM; dtp += 8 * DIM; yc += 8 * DIM;                          \
  }

#define P2_STEP(FASTA)                                                     \
  {                                                                        \
    int t = t0 + tl;                                                       \
    const float* row = dblS[tl];                                           \
    float u, dtv;                                                          \
    {                                                                      \
      float xin = loadx(t);                                                \
      float pre = w0 * xm3 + w1 * xm2 + w2 * xm1 + w3 * xin + bias;        \
      u = pre * rcpf(1.f + __expf(-pre));                                  \
      xm3 = xm2; xm2 = xm1; xm1 = xin;                                     \
      float4 q0 = *(const float4*)(row);                                   \
      float4 q1 = *(const float4*)(row + 4);                               \
      float4 q2 = *(const float4*)(row + 8);                               \
      float4 q3 = *(const float4*)(row + 12);                              \
      float xdt = dbias + q0.x * dwreg[0] + q0.y * dwreg[1] +              \
                  q0.z * dwreg[2] + q0.w * dwreg[3] + q1.x * dwreg[4] +    \
                  q1.y * dwreg[5] + q1.z * dwreg[6] + q1.w * dwreg[7] +    \
                  q2.x * dwreg[8] + q2.y * dwreg[9] + q2.z * dwreg[10] +   \
                  q2.w * dwreg[11] + q3.x * dwreg[12] + q3.y * dwreg[13] + \
                  q3.z * dwreg[14] + q3.w * dwreg[15];                     \
      dtv = (xdt > 15.f) ? xdt : __logf(1.f + __expf(xdt));                \
    }                                                                      \
    float du = dtv * u;                                                    \
    DA8(FASTA)                                                             \
    float4 B0 = *(const float4*)(row + 16);                                \
    float4 B1 = *(const float4*)(row + 20);                                \
    float4 C0 = *(const float4*)(row + 24);                                \
    float4 C1 = *(const float4*)(row + 28);                                \
    h[0] = dA[0] * h[0] + du * B0.x; h[1] = dA[1] * h[1] + du * B0.y;      \
    h[2] = dA[2] * h[2] + du * B0.z; h[3] = dA[3] * h[3] + du * B0.w;      \
    h[4] = dA[4] * h[4] + du * B1.x; h[5] = dA[5] * h[5] + du * B1.y;      \
    h[6] = dA[6] * h[6] + du * B1.z; h[7] = dA[7] * h[7] + du * B1.w;      \
    float y = C0.x * h[0] + C0.y * h[1] + C0.z * h[2] + C0.w * h[3] +      \
              C1.x * h[4] + C1.y * h[5] + C1.z * h[6] + C1.w * h[7] +      \
              u * Dv;                                                      \
    if (dir == 0) {                                                        \
      ycomb[((size_t)b * L_SEQ + t) * DIM + d] = f2bf(y);                  \
    } else {                                                               \
      size_t o = ((size_t)b * L_SEQ + (L_SEQ - 1 - t)) * DIM + d;          \
      float prev = bf2f(ycomb[o]);                                         \
      ycomb[o] = f2bf(0.5f * (prev + y));                                  \
    }                                                                      \
  }

  if (MODE) {
    if (fastA) { P2_GRP(1) } else { P2_GRP(0) }
  } else {
    if (fastA) {
      for (int tl = 0; tl < CLH; ++tl) P2_STEP(1)
    } else {
      for (int tl = 0; tl < CLH; ++tl) P2_STEP(0)
    }
  }
#undef P2_STEP
#undef P2_GRP
}

// ------- combine: v=(yf+yb)/2 (MERGED) or v=ycomb; LN*silu(z) -> xz x-cols --
template <int MERGED>
__global__ __launch_bounds__(256) void combine_ln(
    const unsigned short* __restrict__ ycomb,
    const unsigned short* __restrict__ ybu,
    unsigned short* __restrict__ xz,
    const float* __restrict__ onw, const float* __restrict__ onb) {
  int m = blockIdx.x * 4 + (threadIdx.x >> 6);
  int lane = threadIdx.x & 63;
  ushort4 y4 = *(const ushort4*)&ycomb[(size_t)m * DIM + lane * 4];
  float v0 = bf2f(y4.x), v1 = bf2f(y4.y), v2 = bf2f(y4.z), v3 = bf2f(y4.w);
  if (MERGED) {
    int b = m >> 14, l = m & (L_SEQ - 1);
    size_t fo = ((size_t)S_TOT + ((size_t)b << 14) + (L_SEQ - 1 - l)) * DIM +
                lane * 4;
    ushort4 yb4 = *(const ushort4*)&ybu[fo];
    v0 = 0.5f * (v0 + bf2f(yb4.x)); v1 = 0.5f * (v1 + bf2f(yb4.y));
    v2 = 0.5f * (v2 + bf2f(yb4.z)); v3 = 0.5f * (v3 + bf2f(yb4.w));
  }
  float s = v0 + v1 + v2 + v3;
  float s2 = v0 * v0 + v1 * v1 + v2 * v2 + v3 * v3;
  for (int off = 32; off; off >>= 1) {
    s += __shfl_xor(s, off);
    s2 += __shfl_xor(s2, off);
  }
  float mean = s * (1.0f / DIM);
  float var = s2 * (1.0f / DIM) - mean * mean;
  float rstd = rsqrtf(var + 1e-5f);
  ushort4 z4 = *(const ushort4*)&xz[(size_t)m * 512 + 256 + lane * 4];
  float zf[4] = {bf2f(z4.x), bf2f(z4.y), bf2f(z4.z), bf2f(z4.w)};
  float vf[4] = {v0, v1, v2, v3};
  ushort4 out;
  unsigned short* op = (unsigned short*)&out;
  for (int j = 0; j < 4; ++j) {
    int c = lane * 4 + j;
    float ln = (vf[j] - mean) * rstd * onw[c] + onb[c];
    op[j] = f2bf(ln * (zf[j] * rcpf(1.f + __expf(-zf[j]))));
  }
  *(ushort4*)&xz[(size_t)m * 512 + lane * 4] = out;
}

extern "C" void kernel_launch(void* const* d_in, const int* in_sizes, int n_in,
                              void* d_out, int out_size, void* d_ws, size_t ws_size,
                              hipStream_t stream) {
  const float* input0 = (const float*)d_in[0];
  const float* input1 = (const float*)d_in[1];
  const float* norm0_w = (const float*)d_in[2];
  const float* norm0_b = (const float*)d_in[3];
  const float* norm1_w = (const float*)d_in[4];
  const float* norm1_b = (const float*)d_in[5];
  const float* in_proj_w = (const float*)d_in[6];
  const float* in_proj_extra_w = (const float*)d_in[7];
  const float* convx_w = (const float*)d_in[8];
  const float* convx_b = (const float*)d_in[9];
  const float* conve_w = (const float*)d_in[10];
  const float* conve_b = (const float*)d_in[11];
  const float* convx_w_r = (const float*)d_in[12];
  const float* convx_b_r = (const float*)d_in[13];
  const float* conve_w_r = (const float*)d_in[14];
  const float* conve_b_r = (const float*)d_in[15];
  const float* xproj_w = (const float*)d_in[16];
  const float* xproj_w_r = (const float*)d_in[17];
  const float* dtproj_w = (const float*)d_in[18];
  const float* dtproj_b = (const float*)d_in[19];
  const float* dtproj_w_r = (const float*)d_in[20];
  const float* dtproj_b_r = (const float*)d_in[21];
  const float* A_log = (const float*)d_in[22];
  const float* A_log_r = (const float*)d_in[23];
  const float* Dp = (const float*)d_in[24];
  const float* Dp_r = (const float*)d_in[25];
  const float* outnorm_w = (const float*)d_in[26];
  const float* outnorm_b = (const float*)d_in[27];
  const float* outproj_w = (const float*)d_in[28];

  // ---- workspace layout (bytes); base 76,021,760 + tier B 67,108,864 ----
  char* w = (char*)d_ws;
  unsigned short* xz    = (unsigned short*)(w + 0);          // 33,554,432 B
  unsigned short* h0    = (unsigned short*)(w + 33554432);   // 16,777,216 B
  unsigned short* ycomb = (unsigned short*)(w + 33554432);   // same region, later
  float* Qc   = (float*)(w + 33554432);                      // pass1->mid
  unsigned short* xe    = (unsigned short*)(w + 50331648);   // 16,777,216 B
  float* Pc   = (float*)(w + 50331648);                      // aliases xe after xproj
  unsigned short* dbl2 = (unsigned short*)(w + 67108864);    // 4,194,304 B (bf16)
  unsigned short* wb = (unsigned short*)(w + 75497472);      // 524,288 B bf16 weights
  unsigned short* wb_in  = wb;
  unsigned short* wb_ex  = wb + 131072;
  unsigned short* wb_out = wb + 196608;
  unsigned short* u_arr  = (unsigned short*)(w + 76021760);  // 33,554,432 B (tier B)
  unsigned short* dt_arr = (unsigned short*)(w + 109576192); // 33,554,432 B (tier B)
  const bool big = ws_size >= 76021760ULL + 67108864ULL;     // 143,130,624
  // h1: tier B -> parked in u_arr region (dead until dtu); tier A -> xz region
  unsigned short* h1 = big ? u_arr : xz;

  ln_norm<<<dim3(S_TOT / 4, 2), 256, 0, stream>>>(
      input0, input1, norm0_w, norm0_b, norm1_w, norm1_b, h0, h1,
      in_proj_w, in_proj_extra_w, outproj_w, wb);
  if (big) {
    gemm_in2<<<dim3(1024), 256, 0, stream>>>(h0, h1, wb_in, wb_ex, xz, xe);
  } else {
    gemm64<1, 0><<<dim3(4, 512), 256, 0, stream>>>(h1, DIM, wb_ex, xe, nullptr, 256);
    gemm64<1, 0><<<dim3(8, 512), 256, 0, stream>>>(h0, DIM, wb_in, xz, nullptr, 512);
  }
  xproj_mfma<<<dim3(512, 2), 256, 0, stream>>>(
      xe, conve_w, conve_b, conve_w_r, conve_b_r, xproj_w, xproj_w_r, dbl2);
  if (big) {
    dtu_compute<<<dim3(2048), 256, 0, stream>>>(
        dbl2, dtproj_w, dtproj_w_r, dtproj_b, dtproj_b_r, dt_arr,
        xz, convx_w, convx_b, convx_w_r, convx_b_r, u_arr);
    scan_pass1<1><<<dim3(NCH, 2, 2), 256, 0, stream>>>(
        xz, dbl2, u_arr, dt_arr, convx_w, convx_b, convx_w_r, convx_b_r,
        dtproj_w, dtproj_b, dtproj_w_r, dtproj_b_r, A_log, A_log_r, Pc, Qc);
  } else {
    scan_pass1<0><<<dim3(NCH, 2, 2), 256, 0, stream>>>(
        xz, dbl2, u_arr, dt_arr, convx_w, convx_b, convx_w_r, convx_b_r,
        dtproj_w, dtproj_b, dtproj_w_r, dtproj_b_r, A_log, A_log_r, Pc, Qc);
  }
  scan_mid<<<dim3(32), 256, 0, stream>>>(Pc, Qc);
  if (big) {
    scan_pass2<1><<<dim3(NCH, 2, 2), 256, 0, stream>>>(
        xz, dbl2, u_arr, dt_arr, convx_w, convx_b, convx_w_r, convx_b_r,
        dtproj_w, dtproj_b, dtproj_w_r, dtproj_b_r, A_log, A_log_r,
        Dp, Dp_r, Pc, ycomb, 0);
    combine_ln<1><<<dim3(S_TOT / 4), 256, 0, stream>>>(
        ycomb, u_arr, xz, outnorm_w, outnorm_b);
  } else {
    for (int dir = 0; dir < 2; ++dir)
      scan_pass2<0><<<dim3(NCH, 2), 256, 0, stream>>>(
          xz, dbl2, u_arr, dt_arr, convx_w, convx_b, convx_w_r, convx_b_r,
          dtproj_w, dtproj_b, dtproj_w_r, dtproj_b_r, A_log, A_log_r,
          Dp, Dp_r, Pc, ycomb, dir);
    combine_ln<0><<<dim3(S_TOT / 4), 256, 0, stream>>>(
        ycomb, nullptr, xz, outnorm_w, outnorm_b);
  }
  gemm64<0, 1><<<dim3(4, 512), 256, 0, stream>>>(
      xz, 512, wb_out, d_out, input0, 256);
}

// Round 23
// 201.366 us; speedup vs baseline: 1.1812x; 1.0316x over previous
//
#include <hip/hip_runtime.h>
#include <math.h>

#define L_SEQ 16384
#define DIM 256
#define NST 8
#define RNK 16
#define S_TOT 32768   // B*L
#define NCH 512
#define CLH 32

typedef __attribute__((ext_vector_type(8))) short bf16x8;
typedef __attribute__((ext_vector_type(4))) float f32x4;

__device__ __forceinline__ float bf2f(unsigned short u) {
  union { unsigned int i; float f; } v; v.i = ((unsigned int)u) << 16; return v.f;
}
__device__ __forceinline__ unsigned short f2bf(float x) {
  union { float f; unsigned int i; } v; v.f = x;
  unsigned int r = v.i + 0x7fffu + ((v.i >> 16) & 1u);
  return (unsigned short)(r >> 16);
}
__device__ __forceinline__ float rcpf(float x) {
  return __builtin_amdgcn_rcpf(x);
}

// ---- fused LayerNorm -> bf16 (wave/row, 4 rows/blk) + weight conversion ----
__global__ __launch_bounds__(256) void ln_norm(
    const float* __restrict__ in0, const float* __restrict__ in1,
    const float* __restrict__ w0, const float* __restrict__ b0,
    const float* __restrict__ w1, const float* __restrict__ b1,
    unsigned short* __restrict__ h0, unsigned short* __restrict__ h1,
    const float* __restrict__ pw0, const float* __restrict__ pw1,
    const float* __restrict__ pw2, unsigned short* __restrict__ wbout) {
  int which = blockIdx.y;
  if (which == 0 && blockIdx.x < 1024) {
    int i = blockIdx.x * 256 + threadIdx.x;
    if (i < 131072) wbout[i] = f2bf(pw0[i]);
    else if (i < 196608) wbout[i] = f2bf(pw1[i - 131072]);
    else wbout[i] = f2bf(pw2[i - 196608]);
  }
  int row = blockIdx.x * 4 + (threadIdx.x >> 6);
  int lane = threadIdx.x & 63;
  const float* x = (which ? in1 : in0) + (size_t)row * DIM;
  const float* w = which ? w1 : w0;
  const float* b = which ? b1 : b0;
  unsigned short* h = which ? h1 : h0;
  float4 v = *(const float4*)&x[lane * 4];
  float s = v.x + v.y + v.z + v.w;
  float s2 = v.x * v.x + v.y * v.y + v.z * v.z + v.w * v.w;
  for (int off = 32; off; off >>= 1) {
    s += __shfl_xor(s, off);
    s2 += __shfl_xor(s2, off);
  }
  float mean = s * (1.0f / DIM);
  float var = s2 * (1.0f / DIM) - mean * mean;
  float rstd = rsqrtf(var + 1e-5f);
  float4 wv = *(const float4*)&w[lane * 4];
  float4 bv = *(const float4*)&b[lane * 4];
  ushort4 out;
  out.x = f2bf((v.x - mean) * rstd * wv.x + bv.x);
  out.y = f2bf((v.y - mean) * rstd * wv.y + bv.y);
  out.z = f2bf((v.z - mean) * rstd * wv.z + bv.z);
  out.w = f2bf((v.w - mean) * rstd * wv.w + bv.w);
  *(ushort4*)&h[(size_t)row * DIM + lane * 4] = out;
}

// ------- streaming bf16 GEMM, 64x64 tile, full K=256 staged once -------
template <int BF16C, int ADDIN>
__global__ __launch_bounds__(256) void gemm64(
    const unsigned short* __restrict__ A, int lda,
    const unsigned short* __restrict__ Wb,
    void* __restrict__ Cv, const float* __restrict__ addp, int Nn) {
  __shared__ unsigned short As[64 * 256];
  __shared__ unsigned short Ws[64 * 256];
  int tid = threadIdx.x;
  int n0 = blockIdx.x * 64, m0 = blockIdx.y * 64;
  for (int i = 0; i < 8; ++i) {
    int f8 = tid + i * 256;
    int r = f8 >> 5, c8 = (f8 & 31) * 8;
    int sc = c8 ^ ((r & 7) << 3);
    *(uint4*)&As[r * 256 + sc] = *(const uint4*)&A[(size_t)(m0 + r) * lda + c8];
    *(uint4*)&Ws[r * 256 + sc] = *(const uint4*)&Wb[(size_t)(n0 + r) * 256 + c8];
  }
  __syncthreads();
  int wid = tid >> 6, lane = tid & 63;
  int wm = wid >> 1, wn = wid & 1;
  int l15 = lane & 15, lk = (lane >> 4) * 8;
  f32x4 acc[2][2] = {};
  for (int ks = 0; ks < 8; ++ks) {
    int kcol = ks * 32 + lk;
    bf16x8 af[2], bf_[2];
    for (int mf = 0; mf < 2; ++mf) {
      int row = wm * 32 + mf * 16 + l15;
      af[mf] = *(const bf16x8*)&As[row * 256 + (kcol ^ ((row & 7) << 3))];
    }
    for (int nf = 0; nf < 2; ++nf) {
      int row = wn * 32 + nf * 16 + l15;
      bf_[nf] = *(const bf16x8*)&Ws[row * 256 + (kcol ^ ((row & 7) << 3))];
    }
    for (int mf = 0; mf < 2; ++mf)
      for (int nf = 0; nf < 2; ++nf)
        acc[mf][nf] = __builtin_amdgcn_mfma_f32_16x16x32_bf16(
            af[mf], bf_[nf], acc[mf][nf], 0, 0, 0);
  }
  for (int mf = 0; mf < 2; ++mf)
    for (int nf = 0; nf < 2; ++nf) {
      int row = m0 + wm * 32 + mf * 16 + (lane >> 4) * 4;
      int col = n0 + wn * 32 + nf * 16 + l15;
      for (int v = 0; v < 4; ++v) {
        size_t off = (size_t)(row + v) * Nn + col;
        float val = acc[mf][nf][v];
        if (ADDIN) val += addp[off];
        if (BF16C) ((unsigned short*)Cv)[off] = f2bf(val);
        else       ((float*)Cv)[off] = val;
      }
    }
}

// ---- input GEMMs, A-resident: block owns one A-panel, loops n-tiles ------
__global__ __launch_bounds__(256) void gemm_in2(
    const unsigned short* __restrict__ h0, const unsigned short* __restrict__ h1,
    const unsigned short* __restrict__ wb_in, const unsigned short* __restrict__ wb_ex,
    unsigned short* __restrict__ xzOut, unsigned short* __restrict__ xeOut) {
  __shared__ unsigned short As[64 * 256];
  __shared__ unsigned short Ws[64 * 256];
  int tid = threadIdx.x;
  bool isX = blockIdx.x < 512;
  const unsigned short* A = isX ? h0 : h1;
  const unsigned short* Wb = isX ? wb_in : wb_ex;
  unsigned short* Cv = isX ? xzOut : xeOut;
  int Nn = isX ? 512 : 256;
  int NT = isX ? 8 : 4;
  int m0 = (isX ? (int)blockIdx.x : (int)blockIdx.x - 512) * 64;
  for (int i = 0; i < 8; ++i) {
    int f8 = tid + i * 256;
    int r = f8 >> 5, c8 = (f8 & 31) * 8;
    int sc = c8 ^ ((r & 7) << 3);
    *(uint4*)&As[r * 256 + sc] = *(const uint4*)&A[(size_t)(m0 + r) * 256 + c8];
  }
  int wid = tid >> 6, lane = tid & 63;
  int wm = wid >> 1, wn = wid & 1;
  int l15 = lane & 15, lk = (lane >> 4) * 8;
  for (int nt = 0; nt < NT; ++nt) {
    int n0 = nt * 64;
    for (int i = 0; i < 8; ++i) {
      int f8 = tid + i * 256;
      int r = f8 >> 5, c8 = (f8 & 31) * 8;
      int sc = c8 ^ ((r & 7) << 3);
      *(uint4*)&Ws[r * 256 + sc] = *(const uint4*)&Wb[(size_t)(n0 + r) * 256 + c8];
    }
    __syncthreads();
    f32x4 acc[2][2] = {};
    for (int ks = 0; ks < 8; ++ks) {
      int kcol = ks * 32 + lk;
      bf16x8 af[2], bf_[2];
      for (int mf = 0; mf < 2; ++mf) {
        int row = wm * 32 + mf * 16 + l15;
        af[mf] = *(const bf16x8*)&As[row * 256 + (kcol ^ ((row & 7) << 3))];
      }
      for (int nf = 0; nf < 2; ++nf) {
        int row = wn * 32 + nf * 16 + l15;
        bf_[nf] = *(const bf16x8*)&Ws[row * 256 + (kcol ^ ((row & 7) << 3))];
      }
      for (int mf = 0; mf < 2; ++mf)
        for (int nf = 0; nf < 2; ++nf)
          acc[mf][nf] = __builtin_amdgcn_mfma_f32_16x16x32_bf16(
              af[mf], bf_[nf], acc[mf][nf], 0, 0, 0);
    }
    for (int mf = 0; mf < 2; ++mf)
      for (int nf = 0; nf < 2; ++nf) {
        int row = m0 + wm * 32 + mf * 16 + (lane >> 4) * 4;
        int col = n0 + wn * 32 + nf * 16 + l15;
        for (int v = 0; v < 4; ++v) {
          size_t off = (size_t)(row + v) * Nn + col;
          Cv[off] = f2bf(acc[mf][nf][v]);
        }
      }
    __syncthreads();
  }
}

// ---- output GEMM, A-resident: block owns one m-panel (yg from xz cols 0..255),
//      loops 4 n-tiles; fp32 out + residual ----------------------------------
__global__ __launch_bounds__(256) void gemm_out2(
    const unsigned short* __restrict__ xz,
    const unsigned short* __restrict__ Wb,
    float* __restrict__ outp, const float* __restrict__ addp) {
  __shared__ unsigned short As[64 * 256];
  __shared__ unsigned short Ws[64 * 256];
  int tid = threadIdx.x;
  int m0 = (int)blockIdx.x * 64;
  for (int i = 0; i < 8; ++i) {
    int f8 = tid + i * 256;
    int r = f8 >> 5, c8 = (f8 & 31) * 8;
    int sc = c8 ^ ((r & 7) << 3);
    *(uint4*)&As[r * 256 + sc] = *(const uint4*)&xz[(size_t)(m0 + r) * 512 + c8];
  }
  int wid = tid >> 6, lane = tid & 63;
  int wm = wid >> 1, wn = wid & 1;
  int l15 = lane & 15, lk = (lane >> 4) * 8;
  for (int nt = 0; nt < 4; ++nt) {
    int n0 = nt * 64;
    for (int i = 0; i < 8; ++i) {
      int f8 = tid + i * 256;
      int r = f8 >> 5, c8 = (f8 & 31) * 8;
      int sc = c8 ^ ((r & 7) << 3);
      *(uint4*)&Ws[r * 256 + sc] = *(const uint4*)&Wb[(size_t)(n0 + r) * 256 + c8];
    }
    __syncthreads();
    f32x4 acc[2][2] = {};
    for (int ks = 0; ks < 8; ++ks) {
      int kcol = ks * 32 + lk;
      bf16x8 af[2], bf_[2];
      for (int mf = 0; mf < 2; ++mf) {
        int row = wm * 32 + mf * 16 + l15;
        af[mf] = *(const bf16x8*)&As[row * 256 + (kcol ^ ((row & 7) << 3))];
      }
      for (int nf = 0; nf < 2; ++nf) {
        int row = wn * 32 + nf * 16 + l15;
        bf_[nf] = *(const bf16x8*)&Ws[row * 256 + (kcol ^ ((row & 7) << 3))];
      }
      for (int mf = 0; mf < 2; ++mf)
        for (int nf = 0; nf < 2; ++nf)
          acc[mf][nf] = __builtin_amdgcn_mfma_f32_16x16x32_bf16(
              af[mf], bf_[nf], acc[mf][nf], 0, 0, 0);
    }
    for (int mf = 0; mf < 2; ++mf)
      for (int nf = 0; nf < 2; ++nf) {
        int row = m0 + wm * 32 + mf * 16 + (lane >> 4) * 4;
        int col = n0 + wn * 32 + nf * 16 + l15;
        for (int v = 0; v < 4; ++v) {
          size_t off = (size_t)(row + v) * 256 + col;
          outp[off] = acc[mf][nf][v] + addp[off];
        }
      }
    __syncthreads();
  }
}

// -------- conv(xe)+silu -> MFMA projection to dbl(32) bf16, 64 rows/block --
__global__ __launch_bounds__(256) void xproj_mfma(
    const unsigned short* __restrict__ xe,
    const float* __restrict__ conve_w, const float* __restrict__ conve_b,
    const float* __restrict__ conve_w_r, const float* __restrict__ conve_b_r,
    const float* __restrict__ xproj_w, const float* __restrict__ xproj_w_r,
    unsigned short* __restrict__ dbl2) {
  __shared__ unsigned short ecS[64 * 256];
  __shared__ unsigned short xwS[32 * 256];
  int chunk = blockIdx.x;
  int dir = blockIdx.y;
  int b = chunk >> 8;
  int t0 = (chunk & 255) * 64;
  int tid = threadIdx.x;
  const float* cw = dir ? conve_w_r : conve_w;
  const float* cb = dir ? conve_b_r : conve_b;
  const float* xw = dir ? xproj_w_r : xproj_w;

  for (int i = tid; i < 32 * 256; i += 256) {
    int o = i >> 8, dd = i & 255;
    xwS[o * 256 + (((dd & ~7) ^ ((o & 7) << 3)) | (dd & 7))] = f2bf(xw[i]);
  }

  {
    int c = tid;
    float w0 = cw[c * 4 + 0], w1 = cw[c * 4 + 1], w2 = cw[c * 4 + 2],
          w3 = cw[c * 4 + 3], bias = cb[c];
    size_t bL = (size_t)b * L_SEQ;
    auto loadx = [&](int t) -> float {
      if (t < 0) return 0.f;
      int src = dir ? (L_SEQ - 1 - t) : t;
      return bf2f(xe[(bL + src) * DIM + c]);
    };
    float xm3 = loadx(t0 - 3), xm2 = loadx(t0 - 2), xm1 = loadx(t0 - 1);
    const unsigned short* xp =
        &xe[(bL + (dir ? (L_SEQ - 1 - t0) : t0)) * DIM + c];
    int xstep = dir ? -DIM : DIM;
    int cbase = c & ~7, clow = c & 7;
    for (int t4 = 0; t4 < 64; t4 += 4) {
      float xin4[4];
      for (int j = 0; j < 4; ++j) xin4[j] = bf2f(xp[(ptrdiff_t)j * xstep]);
      xp += (ptrdiff_t)4 * xstep;
      for (int j = 0; j < 4; ++j) {
        int tl = t4 + j;
        float xin = xin4[j];
        float pre = w0 * xm3 + w1 * xm2 + w2 * xm1 + w3 * xin + bias;
        float u = pre * rcpf(1.f + __expf(-pre));
        xm3 = xm2; xm2 = xm1; xm1 = xin;
        ecS[tl * 256 + ((cbase ^ ((tl & 7) << 3)) | clow)] = f2bf(u);
      }
    }
  }
  __syncthreads();

  int wid = tid >> 6, lane = tid & 63;
  int l15 = lane & 15, lk = (lane >> 4) * 8;
  f32x4 acc[2] = {};
  for (int kk = 0; kk < 8; ++kk) {
    int kcol = kk * 32 + lk;
    int row = wid * 16 + l15;
    bf16x8 af = *(const bf16x8*)&ecS[row * 256 + (kcol ^ ((row & 7) << 3))];
    for (int ni = 0; ni < 2; ++ni) {
      int o = ni * 16 + l15;
      bf16x8 bfr = *(const bf16x8*)&xwS[o * 256 + (kcol ^ ((o & 7) << 3))];
      acc[ni] = __builtin_amdgcn_mfma_f32_16x16x32_bf16(af, bfr, acc[ni], 0, 0, 0);
    }
  }
  size_t mbase = (size_t)dir * S_TOT + (size_t)chunk * 64;
  int rloc = wid * 16 + (lane >> 4) * 4;
  for (int ni = 0; ni < 2; ++ni) {
    int o = ni * 16 + l15;
    for (int v = 0; v < 4; ++v)
      dbl2[(mbase + rloc + v) * 32 + o] = f2bf(acc[ni][v]);
  }
}

// ---- merged: blocks 0..1023 = dt_mfma; blocks 1024..2047 = u_compute ------
__global__ __launch_bounds__(256) void dtu_compute(
    const unsigned short* __restrict__ dbl2,
    const float* __restrict__ dtw, const float* __restrict__ dtw_r,
    const float* __restrict__ dtb, const float* __restrict__ dtb_r,
    unsigned short* __restrict__ dt_arr,
    const unsigned short* __restrict__ xz,
    const float* __restrict__ convx_w, const float* __restrict__ convx_b,
    const float* __restrict__ convx_w_r, const float* __restrict__ convx_b_r,
    unsigned short* __restrict__ u_arr) {
  __shared__ unsigned short dtwS[256 * 32];
  __shared__ unsigned short dtrS[64 * 32];
  __shared__ unsigned short outS[64 * 256];
  int tid = threadIdx.x;
  if (blockIdx.x < 1024) {
    int m0 = blockIdx.x * 64;
    int dir = (blockIdx.x >= 512) ? 1 : 0;
    const float* dw = dir ? dtw_r : dtw;
    const float* db = dir ? dtb_r : dtb;
    {
      uint4 z; z.x = 0; z.y = 0; z.z = 0; z.w = 0;
      for (int i = tid; i < 1280; i += 256) {
        if (i < 1024) ((uint4*)dtwS)[i] = z;
        else          ((uint4*)dtrS)[i - 1024] = z;
      }
    }
    __syncthreads();
    for (int it = 0; it < 4; ++it) {
      int idx = tid + it * 256;
      int c = idx >> 2, k4 = idx & 3;
      float4 v = *(const float4*)&dw[c * 16 + k4 * 4];
      uint2 pk;
      pk.x = (unsigned int)f2bf(v.x) | ((unsigned int)f2bf(v.y) << 16);
      pk.y = (unsigned int)f2bf(v.z) | ((unsigned int)f2bf(v.w) << 16);
      int byte = c * 64 + (((k4 >> 1) ^ (c & 3)) << 4) + ((k4 & 1) << 3);
      *(uint2*)((char*)dtwS + byte) = pk;
    }
    {
      int r = tid >> 2, k4 = tid & 3;
      uint2 pk = *(const uint2*)&dbl2[(size_t)(m0 + r) * 32 + k4 * 4];
      int byte = r * 64 + (((k4 >> 1) ^ (r & 3)) << 4) + ((k4 & 1) << 3);
      *(uint2*)((char*)dtrS + byte) = pk;
    }
    __syncthreads();
    int wid = tid >> 6, lane = tid & 63;
    int l15 = lane & 15, lkc = lane >> 4;
    bf16x8 af[4];
    for (int mi = 0; mi < 4; ++mi) {
      int r = mi * 16 + l15;
      af[mi] = *(const bf16x8*)((char*)dtrS + r * 64 + ((lkc ^ (r & 3)) << 4));
    }
    f32x4 acc[4][4] = {};
    for (int ni = 0; ni < 4; ++ni) {
      int c = (wid * 4 + ni) * 16 + l15;
      bf16x8 bfr = *(const bf16x8*)((char*)dtwS + c * 64 + ((lkc ^ (c & 3)) << 4));
      for (int mi = 0; mi < 4; ++mi)
        acc[mi][ni] = __builtin_amdgcn_mfma_f32_16x16x32_bf16(
            af[mi], bfr, acc[mi][ni], 0, 0, 0);
    }
    for (int ni = 0; ni < 4; ++ni) {
      int c = (wid * 4 + ni) * 16 + l15;
      float bias_ = db[c];
      int cb_ = c & ~7, cl_ = c & 7;
      for (int mi = 0; mi < 4; ++mi) {
        int rb = mi * 16 + (lane >> 4) * 4;
        for (int v = 0; v < 4; ++v) {
          int r = rb + v;
          float xdt = acc[mi][ni][v] + bias_;
          float dtv = (xdt > 15.f) ? xdt : __logf(1.f + __expf(xdt));
          outS[r * 256 + ((cb_ ^ ((r & 7) << 3)) | cl_)] = f2bf(dtv);
        }
      }
    }
    __syncthreads();
    for (int it = 0; it < 8; ++it) {
      int i = tid + it * 256;
      int r = i >> 5, cg = (i & 31) * 8;
      uint4 val = *(const uint4*)&outS[r * 256 + (cg ^ ((r & 7) << 3))];
      *(uint4*)&dt_arr[(size_t)(m0 + r) * 256 + cg] = val;
    }
  } else {
    int chunk = blockIdx.x - 1024;
    int b = chunk >> 9;
    int t0 = (chunk & 511) * 32;
    int c = tid;
    float w0 = convx_w[c * 4 + 0], w1 = convx_w[c * 4 + 1],
          w2 = convx_w[c * 4 + 2], w3 = convx_w[c * 4 + 3], bias = convx_b[c];
    float w0r = convx_w_r[c * 4 + 0], w1r = convx_w_r[c * 4 + 1],
          w2r = convx_w_r[c * 4 + 2], w3r = convx_w_r[c * 4 + 3],
          biasr = convx_b_r[c];
    size_t bL = (size_t)b * L_SEQ;
    auto ld = [&](int t) -> float {
      if (t < 0 || t >= L_SEQ) return 0.f;
      return bf2f(xz[(bL + t) * 512 + c]);
    };
    float x3 = ld(t0 - 3), x2 = ld(t0 - 2), x1 = ld(t0 - 1);
    unsigned short* op0 = &u_arr[(bL + t0) * DIM + c];
    unsigned short* op1 =
        &u_arr[((size_t)S_TOT + bL + (L_SEQ - 1 - t0)) * DIM + c];
    for (int tg = 0; tg < 36; tg += 4) {
      float xin4[4];
      for (int j = 0; j < 4; ++j) xin4[j] = ld(t0 + tg + j);
      for (int j = 0; j < 4; ++j) {
        int tl = tg + j;
        float xin = xin4[j];
        if (tl < 32) {
          float pre = w0 * x3 + w1 * x2 + w2 * x1 + w3 * xin + bias;
          op0[(size_t)tl * DIM] = f2bf(pre * rcpf(1.f + __expf(-pre)));
        }
        if (tl >= 3 && tl < 35) {
          float prer = w0r * xin + w1r * x1 + w2r * x2 + w3r * x3 + biasr;
          int s = tl - 3;
          *(op1 - (ptrdiff_t)s * DIM) = f2bf(prer * rcpf(1.f + __expf(-prer)));
        }
        x3 = x2; x2 = x1; x1 = xin;
      }
    }
  }
}

// dA[0..7] = exp(dtv*Ar[n]); FASTA: Ar[n] == -(n+1) verified
#define DA8(FASTA)                                                    \
  float dA[NST];                                                      \
  if (FASTA) {                                                        \
    float e1 = __expf(-dtv);                                          \
    dA[0] = e1;                                                       \
    for (int n = 1; n < NST; ++n) dA[n] = dA[n - 1] * e1;             \
  } else {                                                            \
    for (int n = 0; n < NST; ++n) dA[n] = __expf(dtv * Ar[n]);        \
  }

// ---------------- scan pass 1: per-chunk affine summaries ----------------
template <int USE_UDT>
__global__ __launch_bounds__(256) void scan_pass1(
    const unsigned short* __restrict__ xz, const unsigned short* __restrict__ dbl2,
    const unsigned short* __restrict__ u_arr,
    const unsigned short* __restrict__ dt_arr,
    const float* __restrict__ convx_w, const float* __restrict__ convx_b,
    const float* __restrict__ convx_w_r, const float* __restrict__ convx_b_r,
    const float* __restrict__ dtproj_w, const float* __restrict__ dtproj_b,
    const float* __restrict__ dtproj_w_r, const float* __restrict__ dtproj_b_r,
    const float* __restrict__ A_log, const float* __restrict__ A_log_r,
    float* __restrict__ Pc, float* __restrict__ Qc) {
  int chunk = blockIdx.x, b = blockIdx.y, dir = blockIdx.z;
  int d = threadIdx.x;
  const float* al = dir ? A_log_r : A_log;
  float w0 = 0.f, w1 = 0.f, w2 = 0.f, w3 = 0.f, bias = 0.f, dbias = 0.f;
  float dwreg[RNK];
  if (!USE_UDT) {
    const float* cw = dir ? convx_w_r : convx_w;
    const float* cb = dir ? convx_b_r : convx_b;
    const float* dw = dir ? dtproj_w_r : dtproj_w;
    const float* dbp = dir ? dtproj_b_r : dtproj_b;
    w0 = cw[d * 4 + 0]; w1 = cw[d * 4 + 1]; w2 = cw[d * 4 + 2];
    w3 = cw[d * 4 + 3]; bias = cb[d]; dbias = dbp[d];
    for (int r = 0; r < RNK; ++r) dwreg[r] = dw[d * RNK + r];
  }
  float Ar[NST];
  bool fa = true;
  for (int n = 0; n < NST; ++n) {
    Ar[n] = -__expf(al[d * NST + n]);
    fa = fa && (fabsf(Ar[n] + (float)(n + 1)) < 1e-4f * (float)(n + 1));
  }
  bool fastA = (__ballot(fa) == ~0ULL);

  __shared__ float dblS[CLH][32];
  int t0 = chunk * CLH;
  size_t dtbase = (size_t)dir * S_TOT + (size_t)b * L_SEQ;
  if (USE_UDT) {
    int i = d;
    dblS[i >> 3][i & 7] =
        bf2f(dbl2[(dtbase + t0 + (i >> 3)) * 32 + 16 + (i & 7)]);
  } else {
    for (int i = d; i < CLH * 32; i += 256)
      dblS[i >> 5][i & 31] = bf2f(dbl2[(dtbase + t0) * 32 + i]);
  }
  __syncthreads();
  auto loadx = [&](int t) -> float {
    if (t < 0) return 0.f;
    int srct = dir ? (L_SEQ - 1 - t) : t;
    return bf2f(xz[((size_t)b * L_SEQ + srct) * 512 + d]);
  };
  float xm3 = 0.f, xm2 = 0.f, xm1 = 0.f;
  if (!USE_UDT) { xm3 = loadx(t0 - 3); xm2 = loadx(t0 - 2); xm1 = loadx(t0 - 1); }
  const unsigned short* up = &u_arr[(dtbase + t0) * DIM + d];
  const unsigned short* dtp = &dt_arr[(dtbase + t0) * DIM + d];
  float Q[NST];
  for (int n = 0; n < NST; ++n) Q[n] = 0.f;
  float sdt = 0.f;
  const int BOFF = USE_UDT ? 0 : 16;

#define P1_GRP(FASTA)                                                      \
  for (int t8 = 0; t8 < CLH; t8 += 8) {                                    \
    float uu[8], dd[8];                                                    \
    for (int j = 0; j < 8; ++j) {                                          \
      uu[j] = bf2f(up[(size_t)j * DIM]);                                   \
      dd[j] = bf2f(dtp[(size_t)j * DIM]);                                  \
    }                                                                      \
    up += 8 * DIM; dtp += 8 * DIM;                                         \
    for (int j = 0; j < 8; ++j) {                                          \
      const float* row = dblS[t8 + j];                                     \
      float u = uu[j], dtv = dd[j];                                        \
      float du = dtv * u;                                                  \
      sdt += dtv;                                                          \
      DA8(FASTA)                                                           \
      float4 B0 = *(const float4*)(row);                                   \
      float4 B1 = *(const float4*)(row + 4);                               \
      Q[0] = dA[0] * Q[0] + du * B0.x; Q[1] = dA[1] * Q[1] + du * B0.y;    \
      Q[2] = dA[2] * Q[2] + du * B0.z; Q[3] = dA[3] * Q[3] + du * B0.w;    \
      Q[4] = dA[4] * Q[4] + du * B1.x; Q[5] = dA[5] * Q[5] + du * B1.y;    \
      Q[6] = dA[6] * Q[6] + du * B1.z; Q[7] = dA[7] * Q[7] + du * B1.w;    \
    }                                                                      \
  }

#define P1_STEP(FASTA)                                                     \
  {                                                                        \
    const float* row = dblS[tl];                                           \
    float u, dtv;                                                          \
    {                                                                      \
      float xin = loadx(t0 + tl);                                          \
      float pre = w0 * xm3 + w1 * xm2 + w2 * xm1 + w3 * xin + bias;        \
      u = pre * rcpf(1.f + __expf(-pre));                                  \
      xm3 = xm2; xm2 = xm1; xm1 = xin;                                     \
      float4 q0 = *(const float4*)(row);                                   \
      float4 q1 = *(const float4*)(row + 4);                               \
      float4 q2 = *(const float4*)(row + 8);                               \
      float4 q3 = *(const float4*)(row + 12);                              \
      float xdt = dbias + q0.x * dwreg[0] + q0.y * dwreg[1] +              \
                  q0.z * dwreg[2] + q0.w * dwreg[3] + q1.x * dwreg[4] +    \
                  q1.y * dwreg[5] + q1.z * dwreg[6] + q1.w * dwreg[7] +    \
                  q2.x * dwreg[8] + q2.y * dwreg[9] + q2.z * dwreg[10] +   \
                  q2.w * dwreg[11] + q3.x * dwreg[12] + q3.y * dwreg[13] + \
                  q3.z * dwreg[14] + q3.w * dwreg[15];                     \
      dtv = (xdt > 15.f) ? xdt : __logf(1.f + __expf(xdt));                \
    }                                                                      \
    float du = dtv * u;                                                    \
    sdt += dtv;                                                            \
    DA8(FASTA)                                                             \
    float4 B0 = *(const float4*)(row + BOFF);                              \
    float4 B1 = *(const float4*)(row + BOFF + 4);                          \
    Q[0] = dA[0] * Q[0] + du * B0.x; Q[1] = dA[1] * Q[1] + du * B0.y;      \
    Q[2] = dA[2] * Q[2] + du * B0.z; Q[3] = dA[3] * Q[3] + du * B0.w;      \
    Q[4] = dA[4] * Q[4] + du * B1.x; Q[5] = dA[5] * Q[5] + du * B1.y;      \
    Q[6] = dA[6] * Q[6] + du * B1.z; Q[7] = dA[7] * Q[7] + du * B1.w;      \
  }

  if (USE_UDT) {
    if (fastA) { P1_GRP(1) } else { P1_GRP(0) }
  } else {
    if (fastA) {
      for (int tl = 0; tl < CLH; ++tl) P1_STEP(1)
    } else {
      for (int tl = 0; tl < CLH; ++tl) P1_STEP(0)
    }
  }
#undef P1_STEP
#undef P1_GRP

  float P[NST];
  if (fastA) {
    float E = __expf(-sdt);
    P[0] = E;
    for (int n = 1; n < NST; ++n) P[n] = P[n - 1] * E;
  } else {
    for (int n = 0; n < NST; ++n) P[n] = __expf(Ar[n] * sdt);
  }
  size_t obase = ((((size_t)(dir * 2 + b)) * NCH + chunk) * DIM + d) * NST;
  for (int n = 0; n < NST; ++n) { Pc[obase + n] = P[n]; Qc[obase + n] = Q[n]; }
}

// -------- scan mid: sequential over chunk summaries; Hinit in-place in Pc --
__global__ __launch_bounds__(256) void scan_mid(
    float* __restrict__ Pc, const float* __restrict__ Qc) {
  int idx = blockIdx.x * 256 + threadIdx.x;
  int dn = idx & 2047;
  int db_ = idx >> 11;
  size_t base = (size_t)db_ * NCH * 2048 + dn;
  float h = 0.f;
  for (int c0 = 0; c0 < NCH; c0 += 8) {
    size_t off = base + (size_t)c0 * 2048;
    float P[8], Q[8];
#pragma unroll
    for (int j = 0; j < 8; ++j) {
      P[j] = Pc[off + (size_t)j * 2048];
      Q[j] = Qc[off + (size_t)j * 2048];
    }
#pragma unroll
    for (int j = 0; j < 8; ++j) {
      Pc[off + (size_t)j * 2048] = h;
      h = P[j] * h + Q[j];
    }
  }
}

// ---------------- scan pass 2 ----------------
template <int MODE>
__global__ __launch_bounds__(256) void scan_pass2(
    const unsigned short* __restrict__ xz, const unsigned short* __restrict__ dbl2,
    unsigned short* __restrict__ u_arr,
    const unsigned short* __restrict__ dt_arr,
    const float* __restrict__ convx_w, const float* __restrict__ convx_b,
    const float* __restrict__ convx_w_r, const float* __restrict__ convx_b_r,
    const float* __restrict__ dtproj_w, const float* __restrict__ dtproj_b,
    const float* __restrict__ dtproj_w_r, const float* __restrict__ dtproj_b_r,
    const float* __restrict__ A_log, const float* __restrict__ A_log_r,
    const float* __restrict__ Dp, const float* __restrict__ Dp_r,
    const float* __restrict__ Hinit, unsigned short* __restrict__ ycomb,
    int dirParam) {
  int chunk = blockIdx.x, b = blockIdx.y;
  int dir = MODE ? blockIdx.z : dirParam;
  int d = threadIdx.x;
  const float* al = dir ? A_log_r : A_log;
  float Dv = (dir ? Dp_r : Dp)[d];
  float w0 = 0.f, w1 = 0.f, w2 = 0.f, w3 = 0.f, bias = 0.f, dbias = 0.f;
  float dwreg[RNK];
  if (!MODE) {
    const float* cw = dir ? convx_w_r : convx_w;
    const float* cb = dir ? convx_b_r : convx_b;
    const float* dw = dir ? dtproj_w_r : dtproj_w;
    const float* dbp = dir ? dtproj_b_r : dtproj_b;
    w0 = cw[d * 4 + 0]; w1 = cw[d * 4 + 1]; w2 = cw[d * 4 + 2];
    w3 = cw[d * 4 + 3]; bias = cb[d];
    dbias = dbp[d];
    for (int r = 0; r < RNK; ++r) dwreg[r] = dw[d * RNK + r];
  }
  float Ar[NST];
  bool fa = true;
  for (int n = 0; n < NST; ++n) {
    Ar[n] = -__expf(al[d * NST + n]);
    fa = fa && (fabsf(Ar[n] + (float)(n + 1)) < 1e-4f * (float)(n + 1));
  }
  bool fastA = (__ballot(fa) == ~0ULL);

  __shared__ float dblS[CLH][32];
  int t0 = chunk * CLH;
  size_t dtbase = (size_t)dir * S_TOT + (size_t)b * L_SEQ;
  if (MODE) {
    for (int i = d; i < CLH * 16; i += 256)
      dblS[i >> 4][i & 15] =
          bf2f(dbl2[(dtbase + t0 + (i >> 4)) * 32 + 16 + (i & 15)]);
  } else {
    for (int i = d; i < CLH * 32; i += 256)
      dblS[i >> 5][i & 31] = bf2f(dbl2[(dtbase + t0) * 32 + i]);
  }
  __syncthreads();
  auto loadx = [&](int t) -> float {
    if (t < 0) return 0.f;
    int srct = dir ? (L_SEQ - 1 - t) : t;
    return bf2f(xz[((size_t)b * L_SEQ + srct) * 512 + d]);
  };
  float xm3 = 0.f, xm2 = 0.f, xm1 = 0.f;
  if (!MODE) { xm3 = loadx(t0 - 3); xm2 = loadx(t0 - 2); xm1 = loadx(t0 - 1); }
  float h[NST];
  size_t hbase = ((((size_t)(dir * 2 + b)) * NCH + chunk) * DIM + d) * NST;
  for (int n = 0; n < NST; ++n) h[n] = Hinit[hbase + n];
  unsigned short* up = &u_arr[(dtbase + t0) * DIM + d];
  const unsigned short* dtp = &dt_arr[(dtbase + t0) * DIM + d];
  unsigned short* yc = &ycomb[((size_t)b * L_SEQ + t0) * DIM + d];

#define P2_GRP(FASTA)                                                      \
  for (int t8 = 0; t8 < CLH; t8 += 8) {                                    \
    float uu[8], dd[8];                                                    \
    for (int j = 0; j < 8; ++j) {                                          \
      uu[j] = bf2f(up[(size_t)j * DIM]);                                   \
      dd[j] = bf2f(dtp[(size_t)j * DIM]);                                  \
    }                                                                      \
    for (int j = 0; j < 8; ++j) {                                          \
      const float* row = dblS[t8 + j];                                     \
      float u = uu[j], dtv = dd[j];                                        \
      float du = dtv * u;                                                  \
      DA8(FASTA)                                                           \
      float4 B0 = *(const float4*)(row);                                   \
      float4 B1 = *(const float4*)(row + 4);                               \
      float4 C0 = *(const float4*)(row + 8);                               \
      float4 C1 = *(const float4*)(row + 12);                              \
      h[0] = dA[0] * h[0] + du * B0.x; h[1] = dA[1] * h[1] + du * B0.y;    \
      h[2] = dA[2] * h[2] + du * B0.z; h[3] = dA[3] * h[3] + du * B0.w;    \
      h[4] = dA[4] * h[4] + du * B1.x; h[5] = dA[5] * h[5] + du * B1.y;    \
      h[6] = dA[6] * h[6] + du * B1.z; h[7] = dA[7] * h[7] + du * B1.w;    \
      float y = C0.x * h[0] + C0.y * h[1] + C0.z * h[2] + C0.w * h[3] +    \
                C1.x * h[4] + C1.y * h[5] + C1.z * h[6] + C1.w * h[7] +    \
                u * Dv;                                                    \
      if (dir == 0) yc[(size_t)j * DIM] = f2bf(y);                         \
      else          up[(size_t)j * DIM] = f2bf(y);                         \
    }                                                                      \
    up += 8 * DIM; dtp += 8 * DIM; yc += 8 * DIM;                          \
  }

#define P2_STEP(FASTA)                                                     \
  {                                                                        \
    int t = t0 + tl;                                                       \
    const float* row = dblS[tl];                                           \
    float u, dtv;                                                          \
    {                                                                      \
      float xin = loadx(t);                                                \
      float pre = w0 * xm3 + w1 * xm2 + w2 * xm1 + w3 * xin + bias;        \
      u = pre * rcpf(1.f + __expf(-pre));                                  \
      xm3 = xm2; xm2 = xm1; xm1 = xin;                                     \
      float4 q0 = *(const float4*)(row);                                   \
      float4 q1 = *(const float4*)(row + 4);                               \
      float4 q2 = *(const float4*)(row + 8);                               \
      float4 q3 = *(const float4*)(row + 12);                              \
      float xdt = dbias + q0.x * dwreg[0] + q0.y * dwreg[1] +              \
                  q0.z * dwreg[2] + q0.w * dwreg[3] + q1.x * dwreg[4] +    \
                  q1.y * dwreg[5] + q1.z * dwreg[6] + q1.w * dwreg[7] +    \
                  q2.x * dwreg[8] + q2.y * dwreg[9] + q2.z * dwreg[10] +   \
                  q2.w * dwreg[11] + q3.x * dwreg[12] + q3.y * dwreg[13] + \
                  q3.z * dwreg[14] + q3.w * dwreg[15];                     \
      dtv = (xdt > 15.f) ? xdt : __logf(1.f + __expf(xdt));                \
    }                                                                      \
    float du = dtv * u;                                                    \
    DA8(FASTA)                                                             \
    float4 B0 = *(const float4*)(row + 16);                                \
    float4 B1 = *(const float4*)(row + 20);                                \
    float4 C0 = *(const float4*)(row + 24);                                \
    float4 C1 = *(const float4*)(row + 28);                                \
    h[0] = dA[0] * h[0] + du * B0.x; h[1] = dA[1] * h[1] + du * B0.y;      \
    h[2] = dA[2] * h[2] + du * B0.z; h[3] = dA[3] * h[3] + du * B0.w;      \
    h[4] = dA[4] * h[4] + du * B1.x; h[5] = dA[5] * h[5] + du * B1.y;      \
    h[6] = dA[6] * h[6] + du * B1.z; h[7] = dA[7] * h[7] + du * B1.w;      \
    float y = C0.x * h[0] + C0.y * h[1] + C0.z * h[2] + C0.w * h[3] +      \
              C1.x * h[4] + C1.y * h[5] + C1.z * h[6] + C1.w * h[7] +      \
              u * Dv;                                                      \
    if (dir == 0) {                                                        \
      ycomb[((size_t)b * L_SEQ + t) * DIM + d] = f2bf(y);                  \
    } else {                                                               \
      size_t o = ((size_t)b * L_SEQ + (L_SEQ - 1 - t)) * DIM + d;          \
      float prev = bf2f(ycomb[o]);                                         \
      ycomb[o] = f2bf(0.5f * (prev + y));                                  \
    }                                                                      \
  }

  if (MODE) {
    if (fastA) { P2_GRP(1) } else { P2_GRP(0) }
  } else {
    if (fastA) {
      for (int tl = 0; tl < CLH; ++tl) P2_STEP(1)
    } else {
      for (int tl = 0; tl < CLH; ++tl) P2_STEP(0)
    }
  }
#undef P2_STEP
#undef P2_GRP
}

// ------- combine: v=(yf+yb)/2 (MERGED) or v=ycomb; LN*silu(z) -> xz x-cols --
template <int MERGED>
__global__ __launch_bounds__(256) void combine_ln(
    const unsigned short* __restrict__ ycomb,
    const unsigned short* __restrict__ ybu,
    unsigned short* __restrict__ xz,
    const float* __restrict__ onw, const float* __restrict__ onb) {
  int m = blockIdx.x * 4 + (threadIdx.x >> 6);
  int lane = threadIdx.x & 63;
  ushort4 y4 = *(const ushort4*)&ycomb[(size_t)m * DIM + lane * 4];
  float v0 = bf2f(y4.x), v1 = bf2f(y4.y), v2 = bf2f(y4.z), v3 = bf2f(y4.w);
  if (MERGED) {
    int b = m >> 14, l = m & (L_SEQ - 1);
    size_t fo = ((size_t)S_TOT + ((size_t)b << 14) + (L_SEQ - 1 - l)) * DIM +
                lane * 4;
    ushort4 yb4 = *(const ushort4*)&ybu[fo];
    v0 = 0.5f * (v0 + bf2f(yb4.x)); v1 = 0.5f * (v1 + bf2f(yb4.y));
    v2 = 0.5f * (v2 + bf2f(yb4.z)); v3 = 0.5f * (v3 + bf2f(yb4.w));
  }
  float s = v0 + v1 + v2 + v3;
  float s2 = v0 * v0 + v1 * v1 + v2 * v2 + v3 * v3;
  for (int off = 32; off; off >>= 1) {
    s += __shfl_xor(s, off);
    s2 += __shfl_xor(s2, off);
  }
  float mean = s * (1.0f / DIM);
  float var = s2 * (1.0f / DIM) - mean * mean;
  float rstd = rsqrtf(var + 1e-5f);
  ushort4 z4 = *(const ushort4*)&xz[(size_t)m * 512 + 256 + lane * 4];
  float zf[4] = {bf2f(z4.x), bf2f(z4.y), bf2f(z4.z), bf2f(z4.w)};
  float vf[4] = {v0, v1, v2, v3};
  ushort4 out;
  unsigned short* op = (unsigned short*)&out;
  for (int j = 0; j < 4; ++j) {
    int c = lane * 4 + j;
    float ln = (vf[j] - mean) * rstd * onw[c] + onb[c];
    op[j] = f2bf(ln * (zf[j] * rcpf(1.f + __expf(-zf[j]))));
  }
  *(ushort4*)&xz[(size_t)m * 512 + lane * 4] = out;
}

extern "C" void kernel_launch(void* const* d_in, const int* in_sizes, int n_in,
                              void* d_out, int out_size, void* d_ws, size_t ws_size,
                              hipStream_t stream) {
  const float* input0 = (const float*)d_in[0];
  const float* input1 = (const float*)d_in[1];
  const float* norm0_w = (const float*)d_in[2];
  const float* norm0_b = (const float*)d_in[3];
  const float* norm1_w = (const float*)d_in[4];
  const float* norm1_b = (const float*)d_in[5];
  const float* in_proj_w = (const float*)d_in[6];
  const float* in_proj_extra_w = (const float*)d_in[7];
  const float* convx_w = (const float*)d_in[8];
  const float* convx_b = (const float*)d_in[9];
  const float* conve_w = (const float*)d_in[10];
  const float* conve_b = (const float*)d_in[11];
  const float* convx_w_r = (const float*)d_in[12];
  const float* convx_b_r = (const float*)d_in[13];
  const float* conve_w_r = (const float*)d_in[14];
  const float* conve_b_r = (const float*)d_in[15];
  const float* xproj_w = (const float*)d_in[16];
  const float* xproj_w_r = (const float*)d_in[17];
  const float* dtproj_w = (const float*)d_in[18];
  const float* dtproj_b = (const float*)d_in[19];
  const float* dtproj_w_r = (const float*)d_in[20];
  const float* dtproj_b_r = (const float*)d_in[21];
  const float* A_log = (const float*)d_in[22];
  const float* A_log_r = (const float*)d_in[23];
  const float* Dp = (const float*)d_in[24];
  const float* Dp_r = (const float*)d_in[25];
  const float* outnorm_w = (const float*)d_in[26];
  const float* outnorm_b = (const float*)d_in[27];
  const float* outproj_w = (const float*)d_in[28];

  // ---- workspace layout (bytes); base 76,021,760 + tier B 67,108,864 ----
  char* w = (char*)d_ws;
  unsigned short* xz    = (unsigned short*)(w + 0);          // 33,554,432 B
  unsigned short* h0    = (unsigned short*)(w + 33554432);   // 16,777,216 B
  unsigned short* ycomb = (unsigned short*)(w + 33554432);   // same region, later
  float* Qc   = (float*)(w + 33554432);                      // pass1->mid
  unsigned short* xe    = (unsigned short*)(w + 50331648);   // 16,777,216 B
  float* Pc   = (float*)(w + 50331648);                      // aliases xe after xproj
  unsigned short* dbl2 = (unsigned short*)(w + 67108864);    // 4,194,304 B (bf16)
  unsigned short* wb = (unsigned short*)(w + 75497472);      // 524,288 B bf16 weights
  unsigned short* wb_in  = wb;
  unsigned short* wb_ex  = wb + 131072;
  unsigned short* wb_out = wb + 196608;
  unsigned short* u_arr  = (unsigned short*)(w + 76021760);  // 33,554,432 B (tier B)
  unsigned short* dt_arr = (unsigned short*)(w + 109576192); // 33,554,432 B (tier B)
  const bool big = ws_size >= 76021760ULL + 67108864ULL;     // 143,130,624
  unsigned short* h1 = big ? u_arr : xz;

  ln_norm<<<dim3(S_TOT / 4, 2), 256, 0, stream>>>(
      input0, input1, norm0_w, norm0_b, norm1_w, norm1_b, h0, h1,
      in_proj_w, in_proj_extra_w, outproj_w, wb);
  if (big) {
    gemm_in2<<<dim3(1024), 256, 0, stream>>>(h0, h1, wb_in, wb_ex, xz, xe);
  } else {
    gemm64<1, 0><<<dim3(4, 512), 256, 0, stream>>>(h1, DIM, wb_ex, xe, nullptr, 256);
    gemm64<1, 0><<<dim3(8, 512), 256, 0, stream>>>(h0, DIM, wb_in, xz, nullptr, 512);
  }
  xproj_mfma<<<dim3(512, 2), 256, 0, stream>>>(
      xe, conve_w, conve_b, conve_w_r, conve_b_r, xproj_w, xproj_w_r, dbl2);
  if (big) {
    dtu_compute<<<dim3(2048), 256, 0, stream>>>(
        dbl2, dtproj_w, dtproj_w_r, dtproj_b, dtproj_b_r, dt_arr,
        xz, convx_w, convx_b, convx_w_r, convx_b_r, u_arr);
    scan_pass1<1><<<dim3(NCH, 2, 2), 256, 0, stream>>>(
        xz, dbl2, u_arr, dt_arr, convx_w, convx_b, convx_w_r, convx_b_r,
        dtproj_w, dtproj_b, dtproj_w_r, dtproj_b_r, A_log, A_log_r, Pc, Qc);
  } else {
    scan_pass1<0><<<dim3(NCH, 2, 2), 256, 0, stream>>>(
        xz, dbl2, u_arr, dt_arr, convx_w, convx_b, convx_w_r, convx_b_r,
        dtproj_w, dtproj_b, dtproj_w_r, dtproj_b_r, A_log, A_log_r, Pc, Qc);
  }
  scan_mid<<<dim3(32), 256, 0, stream>>>(Pc, Qc);
  if (big) {
    scan_pass2<1><<<dim3(NCH, 2, 2), 256, 0, stream>>>(
        xz, dbl2, u_arr, dt_arr, convx_w, convx_b, convx_w_r, convx_b_r,
        dtproj_w, dtproj_b, dtproj_w_r, dtproj_b_r, A_log, A_log_r,
        Dp, Dp_r, Pc, ycomb, 0);
    combine_ln<1><<<dim3(S_TOT / 4), 256, 0, stream>>>(
        ycomb, u_arr, xz, outnorm_w, outnorm_b);
    gemm_out2<<<dim3(512), 256, 0, stream>>>(
        xz, wb_out, (float*)d_out, input0);
  } else {
    for (int dir = 0; dir < 2; ++dir)
      scan_pass2<0><<<dim3(NCH, 2), 256, 0, stream>>>(
          xz, dbl2, u_arr, dt_arr, convx_w, convx_b, convx_w_r, convx_b_r,
          dtproj_w, dtproj_b, dtproj_w_r, dtproj_b_r, A_log, A_log_r,
          Dp, Dp_r, Pc, ycomb, dir);
    combine_ln<0><<<dim3(S_TOT / 4), 256, 0, stream>>>(
        ycomb, nullptr, xz, outnorm_w, outnorm_b);
    gemm64<0, 1><<<dim3(4, 512), 256, 0, stream>>>(
        xz, 512, wb_out, d_out, input0, 256);
  }
}

// Round 24
// 194.368 us; speedup vs baseline: 1.2237x; 1.0360x over previous
//
#include <hip/hip_runtime.h>
#include <math.h>

#define L_SEQ 16384
#define DIM 256
#define NST 8
#define RNK 16
#define S_TOT 32768   // B*L
#define NCH 512
#define CLH 32

typedef __attribute__((ext_vector_type(8))) short bf16x8;
typedef __attribute__((ext_vector_type(4))) float f32x4;

__device__ __forceinline__ float bf2f(unsigned short u) {
  union { unsigned int i; float f; } v; v.i = ((unsigned int)u) << 16; return v.f;
}
__device__ __forceinline__ unsigned short f2bf(float x) {
  union { float f; unsigned int i; } v; v.f = x;
  unsigned int r = v.i + 0x7fffu + ((v.i >> 16) & 1u);
  return (unsigned short)(r >> 16);
}
__device__ __forceinline__ float rcpf(float x) {
  return __builtin_amdgcn_rcpf(x);
}

// ---- fused LayerNorm -> bf16 (wave/row, 4 rows/blk) + weight conversion ----
__global__ __launch_bounds__(256) void ln_norm(
    const float* __restrict__ in0, const float* __restrict__ in1,
    const float* __restrict__ w0, const float* __restrict__ b0,
    const float* __restrict__ w1, const float* __restrict__ b1,
    unsigned short* __restrict__ h0, unsigned short* __restrict__ h1,
    const float* __restrict__ pw0, const float* __restrict__ pw1,
    const float* __restrict__ pw2, unsigned short* __restrict__ wbout) {
  int which = blockIdx.y;
  if (which == 0 && blockIdx.x < 1024) {
    int i = blockIdx.x * 256 + threadIdx.x;
    if (i < 131072) wbout[i] = f2bf(pw0[i]);
    else if (i < 196608) wbout[i] = f2bf(pw1[i - 131072]);
    else wbout[i] = f2bf(pw2[i - 196608]);
  }
  int row = blockIdx.x * 4 + (threadIdx.x >> 6);
  int lane = threadIdx.x & 63;
  const float* x = (which ? in1 : in0) + (size_t)row * DIM;
  const float* w = which ? w1 : w0;
  const float* b = which ? b1 : b0;
  unsigned short* h = which ? h1 : h0;
  float4 v = *(const float4*)&x[lane * 4];
  float s = v.x + v.y + v.z + v.w;
  float s2 = v.x * v.x + v.y * v.y + v.z * v.z + v.w * v.w;
  for (int off = 32; off; off >>= 1) {
    s += __shfl_xor(s, off);
    s2 += __shfl_xor(s2, off);
  }
  float mean = s * (1.0f / DIM);
  float var = s2 * (1.0f / DIM) - mean * mean;
  float rstd = rsqrtf(var + 1e-5f);
  float4 wv = *(const float4*)&w[lane * 4];
  float4 bv = *(const float4*)&b[lane * 4];
  ushort4 out;
  out.x = f2bf((v.x - mean) * rstd * wv.x + bv.x);
  out.y = f2bf((v.y - mean) * rstd * wv.y + bv.y);
  out.z = f2bf((v.z - mean) * rstd * wv.z + bv.z);
  out.w = f2bf((v.w - mean) * rstd * wv.w + bv.w);
  *(ushort4*)&h[(size_t)row * DIM + lane * 4] = out;
}

// ------- streaming bf16 GEMM, 64x64 tile, full K=256 staged once -------
template <int BF16C, int ADDIN>
__global__ __launch_bounds__(256) void gemm64(
    const unsigned short* __restrict__ A, int lda,
    const unsigned short* __restrict__ Wb,
    void* __restrict__ Cv, const float* __restrict__ addp, int Nn) {
  __shared__ unsigned short As[64 * 256];
  __shared__ unsigned short Ws[64 * 256];
  int tid = threadIdx.x;
  int n0 = blockIdx.x * 64, m0 = blockIdx.y * 64;
  for (int i = 0; i < 8; ++i) {
    int f8 = tid + i * 256;
    int r = f8 >> 5, c8 = (f8 & 31) * 8;
    int sc = c8 ^ ((r & 7) << 3);
    *(uint4*)&As[r * 256 + sc] = *(const uint4*)&A[(size_t)(m0 + r) * lda + c8];
    *(uint4*)&Ws[r * 256 + sc] = *(const uint4*)&Wb[(size_t)(n0 + r) * 256 + c8];
  }
  __syncthreads();
  int wid = tid >> 6, lane = tid & 63;
  int wm = wid >> 1, wn = wid & 1;
  int l15 = lane & 15, lk = (lane >> 4) * 8;
  f32x4 acc[2][2] = {};
  for (int ks = 0; ks < 8; ++ks) {
    int kcol = ks * 32 + lk;
    bf16x8 af[2], bf_[2];
    for (int mf = 0; mf < 2; ++mf) {
      int row = wm * 32 + mf * 16 + l15;
      af[mf] = *(const bf16x8*)&As[row * 256 + (kcol ^ ((row & 7) << 3))];
    }
    for (int nf = 0; nf < 2; ++nf) {
      int row = wn * 32 + nf * 16 + l15;
      bf_[nf] = *(const bf16x8*)&Ws[row * 256 + (kcol ^ ((row & 7) << 3))];
    }
    for (int mf = 0; mf < 2; ++mf)
      for (int nf = 0; nf < 2; ++nf)
        acc[mf][nf] = __builtin_amdgcn_mfma_f32_16x16x32_bf16(
            af[mf], bf_[nf], acc[mf][nf], 0, 0, 0);
  }
  for (int mf = 0; mf < 2; ++mf)
    for (int nf = 0; nf < 2; ++nf) {
      int row = m0 + wm * 32 + mf * 16 + (lane >> 4) * 4;
      int col = n0 + wn * 32 + nf * 16 + l15;
      for (int v = 0; v < 4; ++v) {
        size_t off = (size_t)(row + v) * Nn + col;
        float val = acc[mf][nf][v];
        if (ADDIN) val += addp[off];
        if (BF16C) ((unsigned short*)Cv)[off] = f2bf(val);
        else       ((float*)Cv)[off] = val;
      }
    }
}

// ---- input GEMMs, A-resident: block owns one A-panel, loops n-tiles ------
__global__ __launch_bounds__(256) void gemm_in2(
    const unsigned short* __restrict__ h0, const unsigned short* __restrict__ h1,
    const unsigned short* __restrict__ wb_in, const unsigned short* __restrict__ wb_ex,
    unsigned short* __restrict__ xzOut, unsigned short* __restrict__ xeOut) {
  __shared__ unsigned short As[64 * 256];
  __shared__ unsigned short Ws[64 * 256];
  int tid = threadIdx.x;
  bool isX = blockIdx.x < 512;
  const unsigned short* A = isX ? h0 : h1;
  const unsigned short* Wb = isX ? wb_in : wb_ex;
  unsigned short* Cv = isX ? xzOut : xeOut;
  int Nn = isX ? 512 : 256;
  int NT = isX ? 8 : 4;
  int m0 = (isX ? (int)blockIdx.x : (int)blockIdx.x - 512) * 64;
  for (int i = 0; i < 8; ++i) {
    int f8 = tid + i * 256;
    int r = f8 >> 5, c8 = (f8 & 31) * 8;
    int sc = c8 ^ ((r & 7) << 3);
    *(uint4*)&As[r * 256 + sc] = *(const uint4*)&A[(size_t)(m0 + r) * 256 + c8];
  }
  int wid = tid >> 6, lane = tid & 63;
  int wm = wid >> 1, wn = wid & 1;
  int l15 = lane & 15, lk = (lane >> 4) * 8;
  for (int nt = 0; nt < NT; ++nt) {
    int n0 = nt * 64;
    for (int i = 0; i < 8; ++i) {
      int f8 = tid + i * 256;
      int r = f8 >> 5, c8 = (f8 & 31) * 8;
      int sc = c8 ^ ((r & 7) << 3);
      *(uint4*)&Ws[r * 256 + sc] = *(const uint4*)&Wb[(size_t)(n0 + r) * 256 + c8];
    }
    __syncthreads();
    f32x4 acc[2][2] = {};
    for (int ks = 0; ks < 8; ++ks) {
      int kcol = ks * 32 + lk;
      bf16x8 af[2], bf_[2];
      for (int mf = 0; mf < 2; ++mf) {
        int row = wm * 32 + mf * 16 + l15;
        af[mf] = *(const bf16x8*)&As[row * 256 + (kcol ^ ((row & 7) << 3))];
      }
      for (int nf = 0; nf < 2; ++nf) {
        int row = wn * 32 + nf * 16 + l15;
        bf_[nf] = *(const bf16x8*)&Ws[row * 256 + (kcol ^ ((row & 7) << 3))];
      }
      for (int mf = 0; mf < 2; ++mf)
        for (int nf = 0; nf < 2; ++nf)
          acc[mf][nf] = __builtin_amdgcn_mfma_f32_16x16x32_bf16(
              af[mf], bf_[nf], acc[mf][nf], 0, 0, 0);
    }
    for (int mf = 0; mf < 2; ++mf)
      for (int nf = 0; nf < 2; ++nf) {
        int row = m0 + wm * 32 + mf * 16 + (lane >> 4) * 4;
        int col = n0 + wn * 32 + nf * 16 + l15;
        for (int v = 0; v < 4; ++v) {
          size_t off = (size_t)(row + v) * Nn + col;
          Cv[off] = f2bf(acc[mf][nf][v]);
        }
      }
    __syncthreads();
  }
}

// ---- fused output: combine (yf+flip(yb))/2 -> LN -> *silu(z) into As once
//      per m-panel (A-resident), then 4 n-tiles of MFMA + fp32 out + residual.
//      Row stats: each row owned by one 32-lane group; butterfly leaves sums
//      in ALL lanes -> no LDS stats, no second pass.
__global__ __launch_bounds__(256) void gemm_out3(
    const unsigned short* __restrict__ ycomb,
    const unsigned short* __restrict__ ybu,
    const unsigned short* __restrict__ xz,
    const float* __restrict__ onw, const float* __restrict__ onb,
    const unsigned short* __restrict__ Wb,
    float* __restrict__ outp, const float* __restrict__ addp) {
  __shared__ unsigned short As[64 * 256];
  __shared__ unsigned short Ws[64 * 256];
  int tid = threadIdx.x;
  int m0 = (int)blockIdx.x * 64;
  for (int i = 0; i < 8; ++i) {
    int f8 = tid + i * 256;
    int r = f8 >> 5, c8 = (f8 & 31) * 8;
    int sc = c8 ^ ((r & 7) << 3);
    int m = m0 + r;
    int b = m >> 14, l = m & (L_SEQ - 1);
    const unsigned short* pf = &ycomb[(size_t)m * DIM + c8];
    const unsigned short* pb =
        &ybu[((size_t)S_TOT + ((size_t)b << 14) + (L_SEQ - 1 - l)) * DIM + c8];
    ushort4 f0 = *(const ushort4*)pf, f1 = *(const ushort4*)(pf + 4);
    ushort4 b0 = *(const ushort4*)pb, b1 = *(const ushort4*)(pb + 4);
    float v[8];
    v[0] = 0.5f * (bf2f(f0.x) + bf2f(b0.x));
    v[1] = 0.5f * (bf2f(f0.y) + bf2f(b0.y));
    v[2] = 0.5f * (bf2f(f0.z) + bf2f(b0.z));
    v[3] = 0.5f * (bf2f(f0.w) + bf2f(b0.w));
    v[4] = 0.5f * (bf2f(f1.x) + bf2f(b1.x));
    v[5] = 0.5f * (bf2f(f1.y) + bf2f(b1.y));
    v[6] = 0.5f * (bf2f(f1.z) + bf2f(b1.z));
    v[7] = 0.5f * (bf2f(f1.w) + bf2f(b1.w));
    float s = 0.f, s2 = 0.f;
    for (int j = 0; j < 8; ++j) { s += v[j]; s2 += v[j] * v[j]; }
    for (int off = 16; off; off >>= 1) {   // 32-lane row-group reduce
      s += __shfl_xor(s, off);
      s2 += __shfl_xor(s2, off);
    }
    float mean = s * (1.0f / DIM);
    float var = s2 * (1.0f / DIM) - mean * mean;
    float rstd = rsqrtf(var + 1e-5f);
    const unsigned short* pz = &xz[(size_t)m * 512 + 256 + c8];
    ushort4 z0 = *(const ushort4*)pz, z1 = *(const ushort4*)(pz + 4);
    float zf[8] = {bf2f(z0.x), bf2f(z0.y), bf2f(z0.z), bf2f(z0.w),
                   bf2f(z1.x), bf2f(z1.y), bf2f(z1.z), bf2f(z1.w)};
    float4 w0v = *(const float4*)&onw[c8];
    float4 w1v = *(const float4*)&onw[c8 + 4];
    float4 bb0 = *(const float4*)&onb[c8];
    float4 bb1 = *(const float4*)&onb[c8 + 4];
    float wv[8] = {w0v.x, w0v.y, w0v.z, w0v.w, w1v.x, w1v.y, w1v.z, w1v.w};
    float bv[8] = {bb0.x, bb0.y, bb0.z, bb0.w, bb1.x, bb1.y, bb1.z, bb1.w};
    unsigned int o[4];
    for (int jj = 0; jj < 4; ++jj) {
      int j0 = jj * 2, j1 = jj * 2 + 1;
      float ln0 = (v[j0] - mean) * rstd * wv[j0] + bv[j0];
      float ln1 = (v[j1] - mean) * rstd * wv[j1] + bv[j1];
      float g0 = ln0 * (zf[j0] * rcpf(1.f + __expf(-zf[j0])));
      float g1 = ln1 * (zf[j1] * rcpf(1.f + __expf(-zf[j1])));
      o[jj] = (unsigned int)f2bf(g0) | ((unsigned int)f2bf(g1) << 16);
    }
    uint4 pk; pk.x = o[0]; pk.y = o[1]; pk.z = o[2]; pk.w = o[3];
    *(uint4*)&As[r * 256 + sc] = pk;
  }
  int wid = tid >> 6, lane = tid & 63;
  int wm = wid >> 1, wn = wid & 1;
  int l15 = lane & 15, lk = (lane >> 4) * 8;
  for (int nt = 0; nt < 4; ++nt) {
    int n0 = nt * 64;
    for (int i = 0; i < 8; ++i) {
      int f8 = tid + i * 256;
      int r = f8 >> 5, c8 = (f8 & 31) * 8;
      int sc = c8 ^ ((r & 7) << 3);
      *(uint4*)&Ws[r * 256 + sc] = *(const uint4*)&Wb[(size_t)(n0 + r) * 256 + c8];
    }
    __syncthreads();
    f32x4 acc[2][2] = {};
    for (int ks = 0; ks < 8; ++ks) {
      int kcol = ks * 32 + lk;
      bf16x8 af[2], bf_[2];
      for (int mf = 0; mf < 2; ++mf) {
        int row = wm * 32 + mf * 16 + l15;
        af[mf] = *(const bf16x8*)&As[row * 256 + (kcol ^ ((row & 7) << 3))];
      }
      for (int nf = 0; nf < 2; ++nf) {
        int row = wn * 32 + nf * 16 + l15;
        bf_[nf] = *(const bf16x8*)&Ws[row * 256 + (kcol ^ ((row & 7) << 3))];
      }
      for (int mf = 0; mf < 2; ++mf)
        for (int nf = 0; nf < 2; ++nf)
          acc[mf][nf] = __builtin_amdgcn_mfma_f32_16x16x32_bf16(
              af[mf], bf_[nf], acc[mf][nf], 0, 0, 0);
    }
    for (int mf = 0; mf < 2; ++mf)
      for (int nf = 0; nf < 2; ++nf) {
        int row = m0 + wm * 32 + mf * 16 + (lane >> 4) * 4;
        int col = n0 + wn * 32 + nf * 16 + l15;
        for (int v = 0; v < 4; ++v) {
          size_t off = (size_t)(row + v) * 256 + col;
          outp[off] = acc[mf][nf][v] + addp[off];
        }
      }
    __syncthreads();
  }
}

// -------- conv(xe)+silu -> MFMA projection to dbl(32) bf16, 64 rows/block --
__global__ __launch_bounds__(256) void xproj_mfma(
    const unsigned short* __restrict__ xe,
    const float* __restrict__ conve_w, const float* __restrict__ conve_b,
    const float* __restrict__ conve_w_r, const float* __restrict__ conve_b_r,
    const float* __restrict__ xproj_w, const float* __restrict__ xproj_w_r,
    unsigned short* __restrict__ dbl2) {
  __shared__ unsigned short ecS[64 * 256];
  __shared__ unsigned short xwS[32 * 256];
  int chunk = blockIdx.x;
  int dir = blockIdx.y;
  int b = chunk >> 8;
  int t0 = (chunk & 255) * 64;
  int tid = threadIdx.x;
  const float* cw = dir ? conve_w_r : conve_w;
  const float* cb = dir ? conve_b_r : conve_b;
  const float* xw = dir ? xproj_w_r : xproj_w;

  for (int i = tid; i < 32 * 256; i += 256) {
    int o = i >> 8, dd = i & 255;
    xwS[o * 256 + (((dd & ~7) ^ ((o & 7) << 3)) | (dd & 7))] = f2bf(xw[i]);
  }

  {
    int c = tid;
    float w0 = cw[c * 4 + 0], w1 = cw[c * 4 + 1], w2 = cw[c * 4 + 2],
          w3 = cw[c * 4 + 3], bias = cb[c];
    size_t bL = (size_t)b * L_SEQ;
    auto loadx = [&](int t) -> float {
      if (t < 0) return 0.f;
      int src = dir ? (L_SEQ - 1 - t) : t;
      return bf2f(xe[(bL + src) * DIM + c]);
    };
    float xm3 = loadx(t0 - 3), xm2 = loadx(t0 - 2), xm1 = loadx(t0 - 1);
    const unsigned short* xp =
        &xe[(bL + (dir ? (L_SEQ - 1 - t0) : t0)) * DIM + c];
    int xstep = dir ? -DIM : DIM;
    int cbase = c & ~7, clow = c & 7;
    for (int t4 = 0; t4 < 64; t4 += 4) {
      float xin4[4];
      for (int j = 0; j < 4; ++j) xin4[j] = bf2f(xp[(ptrdiff_t)j * xstep]);
      xp += (ptrdiff_t)4 * xstep;
      for (int j = 0; j < 4; ++j) {
        int tl = t4 + j;
        float xin = xin4[j];
        float pre = w0 * xm3 + w1 * xm2 + w2 * xm1 + w3 * xin + bias;
        float u = pre * rcpf(1.f + __expf(-pre));
        xm3 = xm2; xm2 = xm1; xm1 = xin;
        ecS[tl * 256 + ((cbase ^ ((tl & 7) << 3)) | clow)] = f2bf(u);
      }
    }
  }
  __syncthreads();

  int wid = tid >> 6, lane = tid & 63;
  int l15 = lane & 15, lk = (lane >> 4) * 8;
  f32x4 acc[2] = {};
  for (int kk = 0; kk < 8; ++kk) {
    int kcol = kk * 32 + lk;
    int row = wid * 16 + l15;
    bf16x8 af = *(const bf16x8*)&ecS[row * 256 + (kcol ^ ((row & 7) << 3))];
    for (int ni = 0; ni < 2; ++ni) {
      int o = ni * 16 + l15;
      bf16x8 bfr = *(const bf16x8*)&xwS[o * 256 + (kcol ^ ((o & 7) << 3))];
      acc[ni] = __builtin_amdgcn_mfma_f32_16x16x32_bf16(af, bfr, acc[ni], 0, 0, 0);
    }
  }
  size_t mbase = (size_t)dir * S_TOT + (size_t)chunk * 64;
  int rloc = wid * 16 + (lane >> 4) * 4;
  for (int ni = 0; ni < 2; ++ni) {
    int o = ni * 16 + l15;
    for (int v = 0; v < 4; ++v)
      dbl2[(mbase + rloc + v) * 32 + o] = f2bf(acc[ni][v]);
  }
}

// ---- merged: blocks 0..1023 = dt_mfma; blocks 1024..2047 = u_compute ------
__global__ __launch_bounds__(256) void dtu_compute(
    const unsigned short* __restrict__ dbl2,
    const float* __restrict__ dtw, const float* __restrict__ dtw_r,
    const float* __restrict__ dtb, const float* __restrict__ dtb_r,
    unsigned short* __restrict__ dt_arr,
    const unsigned short* __restrict__ xz,
    const float* __restrict__ convx_w, const float* __restrict__ convx_b,
    const float* __restrict__ convx_w_r, const float* __restrict__ convx_b_r,
    unsigned short* __restrict__ u_arr) {
  __shared__ unsigned short dtwS[256 * 32];
  __shared__ unsigned short dtrS[64 * 32];
  __shared__ unsigned short outS[64 * 256];
  int tid = threadIdx.x;
  if (blockIdx.x < 1024) {
    int m0 = blockIdx.x * 64;
    int dir = (blockIdx.x >= 512) ? 1 : 0;
    const float* dw = dir ? dtw_r : dtw;
    const float* db = dir ? dtb_r : dtb;
    {
      uint4 z; z.x = 0; z.y = 0; z.z = 0; z.w = 0;
      for (int i = tid; i < 1280; i += 256) {
        if (i < 1024) ((uint4*)dtwS)[i] = z;
        else          ((uint4*)dtrS)[i - 1024] = z;
      }
    }
    __syncthreads();
    for (int it = 0; it < 4; ++it) {
      int idx = tid + it * 256;
      int c = idx >> 2, k4 = idx & 3;
      float4 v = *(const float4*)&dw[c * 16 + k4 * 4];
      uint2 pk;
      pk.x = (unsigned int)f2bf(v.x) | ((unsigned int)f2bf(v.y) << 16);
      pk.y = (unsigned int)f2bf(v.z) | ((unsigned int)f2bf(v.w) << 16);
      int byte = c * 64 + (((k4 >> 1) ^ (c & 3)) << 4) + ((k4 & 1) << 3);
      *(uint2*)((char*)dtwS + byte) = pk;
    }
    {
      int r = tid >> 2, k4 = tid & 3;
      uint2 pk = *(const uint2*)&dbl2[(size_t)(m0 + r) * 32 + k4 * 4];
      int byte = r * 64 + (((k4 >> 1) ^ (r & 3)) << 4) + ((k4 & 1) << 3);
      *(uint2*)((char*)dtrS + byte) = pk;
    }
    __syncthreads();
    int wid = tid >> 6, lane = tid & 63;
    int l15 = lane & 15, lkc = lane >> 4;
    bf16x8 af[4];
    for (int mi = 0; mi < 4; ++mi) {
      int r = mi * 16 + l15;
      af[mi] = *(const bf16x8*)((char*)dtrS + r * 64 + ((lkc ^ (r & 3)) << 4));
    }
    f32x4 acc[4][4] = {};
    for (int ni = 0; ni < 4; ++ni) {
      int c = (wid * 4 + ni) * 16 + l15;
      bf16x8 bfr = *(const bf16x8*)((char*)dtwS + c * 64 + ((lkc ^ (c & 3)) << 4));
      for (int mi = 0; mi < 4; ++mi)
        acc[mi][ni] = __builtin_amdgcn_mfma_f32_16x16x32_bf16(
            af[mi], bfr, acc[mi][ni], 0, 0, 0);
    }
    for (int ni = 0; ni < 4; ++ni) {
      int c = (wid * 4 + ni) * 16 + l15;
      float bias_ = db[c];
      int cb_ = c & ~7, cl_ = c & 7;
      for (int mi = 0; mi < 4; ++mi) {
        int rb = mi * 16 + (lane >> 4) * 4;
        for (int v = 0; v < 4; ++v) {
          int r = rb + v;
          float xdt = acc[mi][ni][v] + bias_;
          float dtv = (xdt > 15.f) ? xdt : __logf(1.f + __expf(xdt));
          outS[r * 256 + ((cb_ ^ ((r & 7) << 3)) | cl_)] = f2bf(dtv);
        }
      }
    }
    __syncthreads();
    for (int it = 0; it < 8; ++it) {
      int i = tid + it * 256;
      int r = i >> 5, cg = (i & 31) * 8;
      uint4 val = *(const uint4*)&outS[r * 256 + (cg ^ ((r & 7) << 3))];
      *(uint4*)&dt_arr[(size_t)(m0 + r) * 256 + cg] = val;
    }
  } else {
    int chunk = blockIdx.x - 1024;
    int b = chunk >> 9;
    int t0 = (chunk & 511) * 32;
    int c = tid;
    float w0 = convx_w[c * 4 + 0], w1 = convx_w[c * 4 + 1],
          w2 = convx_w[c * 4 + 2], w3 = convx_w[c * 4 + 3], bias = convx_b[c];
    float w0r = convx_w_r[c * 4 + 0], w1r = convx_w_r[c * 4 + 1],
          w2r = convx_w_r[c * 4 + 2], w3r = convx_w_r[c * 4 + 3],
          biasr = convx_b_r[c];
    size_t bL = (size_t)b * L_SEQ;
    auto ld = [&](int t) -> float {
      if (t < 0 || t >= L_SEQ) return 0.f;
      return bf2f(xz[(bL + t) * 512 + c]);
    };
    float x3 = ld(t0 - 3), x2 = ld(t0 - 2), x1 = ld(t0 - 1);
    unsigned short* op0 = &u_arr[(bL + t0) * DIM + c];
    unsigned short* op1 =
        &u_arr[((size_t)S_TOT + bL + (L_SEQ - 1 - t0)) * DIM + c];
    for (int tg = 0; tg < 36; tg += 4) {
      float xin4[4];
      for (int j = 0; j < 4; ++j) xin4[j] = ld(t0 + tg + j);
      for (int j = 0; j < 4; ++j) {
        int tl = tg + j;
        float xin = xin4[j];
        if (tl < 32) {
          float pre = w0 * x3 + w1 * x2 + w2 * x1 + w3 * xin + bias;
          op0[(size_t)tl * DIM] = f2bf(pre * rcpf(1.f + __expf(-pre)));
        }
        if (tl >= 3 && tl < 35) {
          float prer = w0r * xin + w1r * x1 + w2r * x2 + w3r * x3 + biasr;
          int s = tl - 3;
          *(op1 - (ptrdiff_t)s * DIM) = f2bf(prer * rcpf(1.f + __expf(-prer)));
        }
        x3 = x2; x2 = x1; x1 = xin;
      }
    }
  }
}

// dA[0..7] = exp(dtv*Ar[n]); FASTA: Ar[n] == -(n+1) verified
#define DA8(FASTA)                                                    \
  float dA[NST];                                                      \
  if (FASTA) {                                                        \
    float e1 = __expf(-dtv);                                          \
    dA[0] = e1;                                                       \
    for (int n = 1; n < NST; ++n) dA[n] = dA[n - 1] * e1;             \
  } else {                                                            \
    for (int n = 0; n < NST; ++n) dA[n] = __expf(dtv * Ar[n]);        \
  }

// ---------------- scan pass 1: per-chunk affine summaries ----------------
template <int USE_UDT>
__global__ __launch_bounds__(256) void scan_pass1(
    const unsigned short* __restrict__ xz, const unsigned short* __restrict__ dbl2,
    const unsigned short* __restrict__ u_arr,
    const unsigned short* __restrict__ dt_arr,
    const float* __restrict__ convx_w, const float* __restrict__ convx_b,
    const float* __restrict__ convx_w_r, const float* __restrict__ convx_b_r,
    const float* __restrict__ dtproj_w, const float* __restrict__ dtproj_b,
    const float* __restrict__ dtproj_w_r, const float* __restrict__ dtproj_b_r,
    const float* __restrict__ A_log, const float* __restrict__ A_log_r,
    float* __restrict__ Pc, float* __restrict__ Qc) {
  int chunk = blockIdx.x, b = blockIdx.y, dir = blockIdx.z;
  int d = threadIdx.x;
  const float* al = dir ? A_log_r : A_log;
  float w0 = 0.f, w1 = 0.f, w2 = 0.f, w3 = 0.f, bias = 0.f, dbias = 0.f;
  float dwreg[RNK];
  if (!USE_UDT) {
    const float* cw = dir ? convx_w_r : convx_w;
    const float* cb = dir ? convx_b_r : convx_b;
    const float* dw = dir ? dtproj_w_r : dtproj_w;
    const float* dbp = dir ? dtproj_b_r : dtproj_b;
    w0 = cw[d * 4 + 0]; w1 = cw[d * 4 + 1]; w2 = cw[d * 4 + 2];
    w3 = cw[d * 4 + 3]; bias = cb[d]; dbias = dbp[d];
    for (int r = 0; r < RNK; ++r) dwreg[r] = dw[d * RNK + r];
  }
  float Ar[NST];
  bool fa = true;
  for (int n = 0; n < NST; ++n) {
    Ar[n] = -__expf(al[d * NST + n]);
    fa = fa && (fabsf(Ar[n] + (float)(n + 1)) < 1e-4f * (float)(n + 1));
  }
  bool fastA = (__ballot(fa) == ~0ULL);

  __shared__ float dblS[CLH][32];
  int t0 = chunk * CLH;
  size_t dtbase = (size_t)dir * S_TOT + (size_t)b * L_SEQ;
  if (USE_UDT) {
    int i = d;
    dblS[i >> 3][i & 7] =
        bf2f(dbl2[(dtbase + t0 + (i >> 3)) * 32 + 16 + (i & 7)]);
  } else {
    for (int i = d; i < CLH * 32; i += 256)
      dblS[i >> 5][i & 31] = bf2f(dbl2[(dtbase + t0) * 32 + i]);
  }
  __syncthreads();
  auto loadx = [&](int t) -> float {
    if (t < 0) return 0.f;
    int srct = dir ? (L_SEQ - 1 - t) : t;
    return bf2f(xz[((size_t)b * L_SEQ + srct) * 512 + d]);
  };
  float xm3 = 0.f, xm2 = 0.f, xm1 = 0.f;
  if (!USE_UDT) { xm3 = loadx(t0 - 3); xm2 = loadx(t0 - 2); xm1 = loadx(t0 - 1); }
  const unsigned short* up = &u_arr[(dtbase + t0) * DIM + d];
  const unsigned short* dtp = &dt_arr[(dtbase + t0) * DIM + d];
  float Q[NST];
  for (int n = 0; n < NST; ++n) Q[n] = 0.f;
  float sdt = 0.f;
  const int BOFF = USE_UDT ? 0 : 16;

#define P1_GRP(FASTA)                                                      \
  for (int t8 = 0; t8 < CLH; t8 += 8) {                                    \
    float uu[8], dd[8];                                                    \
    for (int j = 0; j < 8; ++j) {                                          \
      uu[j] = bf2f(up[(size_t)j * DIM]);                                   \
      dd[j] = bf2f(dtp[(size_t)j * DIM]);                                  \
    }                                                                      \
    up += 8 * DIM; dtp += 8 * DIM;                                         \
    for (int j = 0; j < 8; ++j) {                                          \
      const float* row = dblS[t8 + j];                                     \
      float u = uu[j], dtv = dd[j];                                        \
      float du = dtv * u;                                                  \
      sdt += dtv;                                                          \
      DA8(FASTA)                                                           \
      float4 B0 = *(const float4*)(row);                                   \
      float4 B1 = *(const float4*)(row + 4);                               \
      Q[0] = dA[0] * Q[0] + du * B0.x; Q[1] = dA[1] * Q[1] + du * B0.y;    \
      Q[2] = dA[2] * Q[2] + du * B0.z; Q[3] = dA[3] * Q[3] + du * B0.w;    \
      Q[4] = dA[4] * Q[4] + du * B1.x; Q[5] = dA[5] * Q[5] + du * B1.y;    \
      Q[6] = dA[6] * Q[6] + du * B1.z; Q[7] = dA[7] * Q[7] + du * B1.w;    \
    }                                                                      \
  }

#define P1_STEP(FASTA)                                                     \
  {                                                                        \
    const float* row = dblS[tl];                                           \
    float u, dtv;                                                          \
    {                                                                      \
      float xin = loadx(t0 + tl);                                          \
      float pre = w0 * xm3 + w1 * xm2 + w2 * xm1 + w3 * xin + bias;        \
      u = pre * rcpf(1.f + __expf(-pre));                                  \
      xm3 = xm2; xm2 = xm1; xm1 = xin;                                     \
      float4 q0 = *(const float4*)(row);                                   \
      float4 q1 = *(const float4*)(row + 4);                               \
      float4 q2 = *(const float4*)(row + 8);                               \
      float4 q3 = *(const float4*)(row + 12);                              \
      float xdt = dbias + q0.x * dwreg[0] + q0.y * dwreg[1] +              \
                  q0.z * dwreg[2] + q0.w * dwreg[3] + q1.x * dwreg[4] +    \
                  q1.y * dwreg[5] + q1.z * dwreg[6] + q1.w * dwreg[7] +    \
                  q2.x * dwreg[8] + q2.y * dwreg[9] + q2.z * dwreg[10] +   \
                  q2.w * dwreg[11] + q3.x * dwreg[12] + q3.y * dwreg[13] + \
                  q3.z * dwreg[14] + q3.w * dwreg[15];                     \
      dtv = (xdt > 15.f) ? xdt : __logf(1.f + __expf(xdt));                \
    }                                                                      \
    float du = dtv * u;                                                    \
    sdt += dtv;                                                            \
    DA8(FASTA)                                                             \
    float4 B0 = *(const float4*)(row + BOFF);                              \
    float4 B1 = *(const float4*)(row + BOFF + 4);                          \
    Q[0] = dA[0] * Q[0] + du * B0.x; Q[1] = dA[1] * Q[1] + du * B0.y;      \
    Q[2] = dA[2] * Q[2] + du * B0.z; Q[3] = dA[3] * Q[3] + du * B0.w;      \
    Q[4] = dA[4] * Q[4] + du * B1.x; Q[5] = dA[5] * Q[5] + du * B1.y;      \
    Q[6] = dA[6] * Q[6] + du * B1.z; Q[7] = dA[7] * Q[7] + du * B1.w;      \
  }

  if (USE_UDT) {
    if (fastA) { P1_GRP(1) } else { P1_GRP(0) }
  } else {
    if (fastA) {
      for (int tl = 0; tl < CLH; ++tl) P1_STEP(1)
    } else {
      for (int tl = 0; tl < CLH; ++tl) P1_STEP(0)
    }
  }
#undef P1_STEP
#undef P1_GRP

  float P[NST];
  if (fastA) {
    float E = __expf(-sdt);
    P[0] = E;
    for (int n = 1; n < NST; ++n) P[n] = P[n - 1] * E;
  } else {
    for (int n = 0; n < NST; ++n) P[n] = __expf(Ar[n] * sdt);
  }
  size_t obase = ((((size_t)(dir * 2 + b)) * NCH + chunk) * DIM + d) * NST;
  for (int n = 0; n < NST; ++n) { Pc[obase + n] = P[n]; Qc[obase + n] = Q[n]; }
}

// -------- scan mid: sequential over chunk summaries; Hinit in-place in Pc --
__global__ __launch_bounds__(256) void scan_mid(
    float* __restrict__ Pc, const float* __restrict__ Qc) {
  int idx = blockIdx.x * 256 + threadIdx.x;
  int dn = idx & 2047;
  int db_ = idx >> 11;
  size_t base = (size_t)db_ * NCH * 2048 + dn;
  float h = 0.f;
  for (int c0 = 0; c0 < NCH; c0 += 8) {
    size_t off = base + (size_t)c0 * 2048;
    float P[8], Q[8];
#pragma unroll
    for (int j = 0; j < 8; ++j) {
      P[j] = Pc[off + (size_t)j * 2048];
      Q[j] = Qc[off + (size_t)j * 2048];
    }
#pragma unroll
    for (int j = 0; j < 8; ++j) {
      Pc[off + (size_t)j * 2048] = h;
      h = P[j] * h + Q[j];
    }
  }
}

// ---------------- scan pass 2 ----------------
template <int MODE>
__global__ __launch_bounds__(256) void scan_pass2(
    const unsigned short* __restrict__ xz, const unsigned short* __restrict__ dbl2,
    unsigned short* __restrict__ u_arr,
    const unsigned short* __restrict__ dt_arr,
    const float* __restrict__ convx_w, const float* __restrict__ convx_b,
    const float* __restrict__ convx_w_r, const float* __restrict__ convx_b_r,
    const float* __restrict__ dtproj_w, const float* __restrict__ dtproj_b,
    const float* __restrict__ dtproj_w_r, const float* __restrict__ dtproj_b_r,
    const float* __restrict__ A_log, const float* __restrict__ A_log_r,
    const float* __restrict__ Dp, const float* __restrict__ Dp_r,
    const float* __restrict__ Hinit, unsigned short* __restrict__ ycomb,
    int dirParam) {
  int chunk = blockIdx.x, b = blockIdx.y;
  int dir = MODE ? blockIdx.z : dirParam;
  int d = threadIdx.x;
  const float* al = dir ? A_log_r : A_log;
  float Dv = (dir ? Dp_r : Dp)[d];
  float w0 = 0.f, w1 = 0.f, w2 = 0.f, w3 = 0.f, bias = 0.f, dbias = 0.f;
  float dwreg[RNK];
  if (!MODE) {
    const float* cw = dir ? convx_w_r : convx_w;
    const float* cb = dir ? convx_b_r : convx_b;
    const float* dw = dir ? dtproj_w_r : dtproj_w;
    const float* dbp = dir ? dtproj_b_r : dtproj_b;
    w0 = cw[d * 4 + 0]; w1 = cw[d * 4 + 1]; w2 = cw[d * 4 + 2];
    w3 = cw[d * 4 + 3]; bias = cb[d];
    dbias = dbp[d];
    for (int r = 0; r < RNK; ++r) dwreg[r] = dw[d * RNK + r];
  }
  float Ar[NST];
  bool fa = true;
  for (int n = 0; n < NST; ++n) {
    Ar[n] = -__expf(al[d * NST + n]);
    fa = fa && (fabsf(Ar[n] + (float)(n + 1)) < 1e-4f * (float)(n + 1));
  }
  bool fastA = (__ballot(fa) == ~0ULL);

  __shared__ float dblS[CLH][32];
  int t0 = chunk * CLH;
  size_t dtbase = (size_t)dir * S_TOT + (size_t)b * L_SEQ;
  if (MODE) {
    for (int i = d; i < CLH * 16; i += 256)
      dblS[i >> 4][i & 15] =
          bf2f(dbl2[(dtbase + t0 + (i >> 4)) * 32 + 16 + (i & 15)]);
  } else {
    for (int i = d; i < CLH * 32; i += 256)
      dblS[i >> 5][i & 31] = bf2f(dbl2[(dtbase + t0) * 32 + i]);
  }
  __syncthreads();
  auto loadx = [&](int t) -> float {
    if (t < 0) return 0.f;
    int srct = dir ? (L_SEQ - 1 - t) : t;
    return bf2f(xz[((size_t)b * L_SEQ + srct) * 512 + d]);
  };
  float xm3 = 0.f, xm2 = 0.f, xm1 = 0.f;
  if (!MODE) { xm3 = loadx(t0 - 3); xm2 = loadx(t0 - 2); xm1 = loadx(t0 - 1); }
  float h[NST];
  size_t hbase = ((((size_t)(dir * 2 + b)) * NCH + chunk) * DIM + d) * NST;
  for (int n = 0; n < NST; ++n) h[n] = Hinit[hbase + n];
  unsigned short* up = &u_arr[(dtbase + t0) * DIM + d];
  const unsigned short* dtp = &dt_arr[(dtbase + t0) * DIM + d];
  unsigned short* yc = &ycomb[((size_t)b * L_SEQ + t0) * DIM + d];

#define P2_GRP(FASTA)                                                      \
  for (int t8 = 0; t8 < CLH; t8 += 8) {                                    \
    float uu[8], dd[8];                                                    \
    for (int j = 0; j < 8; ++j) {                                          \
      uu[j] = bf2f(up[(size_t)j * DIM]);                                   \
      dd[j] = bf2f(dtp[(size_t)j * DIM]);                                  \
    }                                                                      \
    for (int j = 0; j < 8; ++j) {                                          \
      const float* row = dblS[t8 + j];                                     \
      float u = uu[j], dtv = dd[j];                                        \
      float du = dtv * u;                                                  \
      DA8(FASTA)                                                           \
      float4 B0 = *(const float4*)(row);                                   \
      float4 B1 = *(const float4*)(row + 4);                               \
      float4 C0 = *(const float4*)(row + 8);                               \
      float4 C1 = *(const float4*)(row + 12);                              \
      h[0] = dA[0] * h[0] + du * B0.x; h[1] = dA[1] * h[1] + du * B0.y;    \
      h[2] = dA[2] * h[2] + du * B0.z; h[3] = dA[3] * h[3] + du * B0.w;    \
      h[4] = dA[4] * h[4] + du * B1.x; h[5] = dA[5] * h[5] + du * B1.y;    \
      h[6] = dA[6] * h[6] + du * B1.z; h[7] = dA[7] * h[7] + du * B1.w;    \
      float y = C0.x * h[0] + C0.y * h[1] + C0.z * h[2] + C0.w * h[3] +    \
                C1.x * h[4] + C1.y * h[5] + C1.z * h[6] + C1.w * h[7] +    \
                u * Dv;                                                    \
      if (dir == 0) yc[(size_t)j * DIM] = f2bf(y);                         \
      else          up[(size_t)j * DIM] = f2bf(y);                         \
    }                                                                      \
    up += 8 * DIM; dtp += 8 * DIM; yc += 8 * DIM;                          \
  }

#define P2_STEP(FASTA)                                                     \
  {                                                                        \
    int t = t0 + tl;                                                       \
    const float* row = dblS[tl];                                           \
    float u, dtv;                                                          \
    {                                                                      \
      float xin = loadx(t);                                                \
      float pre = w0 * xm3 + w1 * xm2 + w2 * xm1 + w3 * xin + bias;        \
      u = pre * rcpf(1.f + __expf(-pre));                                  \
      xm3 = xm2; xm2 = xm1; xm1 = xin;                                     \
      float4 q0 = *(const float4*)(row);                                   \
      float4 q1 = *(const float4*)(row + 4);                               \
      float4 q2 = *(const float4*)(row + 8);                               \
      float4 q3 = *(const float4*)(row + 12);                              \
      float xdt = dbias + q0.x * dwreg[0] + q0.y * dwreg[1] +              \
                  q0.z * dwreg[2] + q0.w * dwreg[3] + q1.x * dwreg[4] +    \
                  q1.y * dwreg[5] + q1.z * dwreg[6] + q1.w * dwreg[7] +    \
                  q2.x * dwreg[8] + q2.y * dwreg[9] + q2.z * dwreg[10] +   \
                  q2.w * dwreg[11] + q3.x * dwreg[12] + q3.y * dwreg[13] + \
                  q3.z * dwreg[14] + q3.w * dwreg[15];                     \
      dtv = (xdt > 15.f) ? xdt : __logf(1.f + __expf(xdt));                \
    }                                                                      \
    float du = dtv * u;                                                    \
    DA8(FASTA)                                                             \
    float4 B0 = *(const float4*)(row + 16);                                \
    float4 B1 = *(const float4*)(row + 20);                                \
    float4 C0 = *(const float4*)(row + 24);                                \
    float4 C1 = *(const float4*)(row + 28);                                \
    h[0] = dA[0] * h[0] + du * B0.x; h[1] = dA[1] * h[1] + du * B0.y;      \
    h[2] = dA[2] * h[2] + du * B0.z; h[3] = dA[3] * h[3] + du * B0.w;      \
    h[4] = dA[4] * h[4] + du * B1.x; h[5] = dA[5] * h[5] + du * B1.y;      \
    h[6] = dA[6] * h[6] + du * B1.z; h[7] = dA[7] * h[7] + du * B1.w;      \
    float y = C0.x * h[0] + C0.y * h[1] + C0.z * h[2] + C0.w * h[3] +      \
              C1.x * h[4] + C1.y * h[5] + C1.z * h[6] + C1.w * h[7] +      \
              u * Dv;                                                      \
    if (dir == 0) {                                                        \
      ycomb[((size_t)b * L_SEQ + t) * DIM + d] = f2bf(y);                  \
    } else {                                                               \
      size_t o = ((size_t)b * L_SEQ + (L_SEQ - 1 - t)) * DIM + d;          \
      float prev = bf2f(ycomb[o]);                                         \
      ycomb[o] = f2bf(0.5f * (prev + y));                                  \
    }                                                                      \
  }

  if (MODE) {
    if (fastA) { P2_GRP(1) } else { P2_GRP(0) }
  } else {
    if (fastA) {
      for (int tl = 0; tl < CLH; ++tl) P2_STEP(1)
    } else {
      for (int tl = 0; tl < CLH; ++tl) P2_STEP(0)
    }
  }
#undef P2_STEP
#undef P2_GRP
}

// ------- combine (tier A only): LN(ycomb)*silu(z) -> xz x-cols -------------
__global__ __launch_bounds__(256) void combine_ln(
    const unsigned short* __restrict__ ycomb,
    unsigned short* __restrict__ xz,
    const float* __restrict__ onw, const float* __restrict__ onb) {
  int m = blockIdx.x * 4 + (threadIdx.x >> 6);
  int lane = threadIdx.x & 63;
  ushort4 y4 = *(const ushort4*)&ycomb[(size_t)m * DIM + lane * 4];
  float v0 = bf2f(y4.x), v1 = bf2f(y4.y), v2 = bf2f(y4.z), v3 = bf2f(y4.w);
  float s = v0 + v1 + v2 + v3;
  float s2 = v0 * v0 + v1 * v1 + v2 * v2 + v3 * v3;
  for (int off = 32; off; off >>= 1) {
    s += __shfl_xor(s, off);
    s2 += __shfl_xor(s2, off);
  }
  float mean = s * (1.0f / DIM);
  float var = s2 * (1.0f / DIM) - mean * mean;
  float rstd = rsqrtf(var + 1e-5f);
  ushort4 z4 = *(const ushort4*)&xz[(size_t)m * 512 + 256 + lane * 4];
  float zf[4] = {bf2f(z4.x), bf2f(z4.y), bf2f(z4.z), bf2f(z4.w)};
  float vf[4] = {v0, v1, v2, v3};
  ushort4 out;
  unsigned short* op = (unsigned short*)&out;
  for (int j = 0; j < 4; ++j) {
    int c = lane * 4 + j;
    float ln = (vf[j] - mean) * rstd * onw[c] + onb[c];
    op[j] = f2bf(ln * (zf[j] * rcpf(1.f + __expf(-zf[j]))));
  }
  *(ushort4*)&xz[(size_t)m * 512 + lane * 4] = out;
}

extern "C" void kernel_launch(void* const* d_in, const int* in_sizes, int n_in,
                              void* d_out, int out_size, void* d_ws, size_t ws_size,
                              hipStream_t stream) {
  const float* input0 = (const float*)d_in[0];
  const float* input1 = (const float*)d_in[1];
  const float* norm0_w = (const float*)d_in[2];
  const float* norm0_b = (const float*)d_in[3];
  const float* norm1_w = (const float*)d_in[4];
  const float* norm1_b = (const float*)d_in[5];
  const float* in_proj_w = (const float*)d_in[6];
  const float* in_proj_extra_w = (const float*)d_in[7];
  const float* convx_w = (const float*)d_in[8];
  const float* convx_b = (const float*)d_in[9];
  const float* conve_w = (const float*)d_in[10];
  const float* conve_b = (const float*)d_in[11];
  const float* convx_w_r = (const float*)d_in[12];
  const float* convx_b_r = (const float*)d_in[13];
  const float* conve_w_r = (const float*)d_in[14];
  const float* conve_b_r = (const float*)d_in[15];
  const float* xproj_w = (const float*)d_in[16];
  const float* xproj_w_r = (const float*)d_in[17];
  const float* dtproj_w = (const float*)d_in[18];
  const float* dtproj_b = (const float*)d_in[19];
  const float* dtproj_w_r = (const float*)d_in[20];
  const float* dtproj_b_r = (const float*)d_in[21];
  const float* A_log = (const float*)d_in[22];
  const float* A_log_r = (const float*)d_in[23];
  const float* Dp = (const float*)d_in[24];
  const float* Dp_r = (const float*)d_in[25];
  const float* outnorm_w = (const float*)d_in[26];
  const float* outnorm_b = (const float*)d_in[27];
  const float* outproj_w = (const float*)d_in[28];

  // ---- workspace layout (bytes); base 76,021,760 + tier B 67,108,864 ----
  char* w = (char*)d_ws;
  unsigned short* xz    = (unsigned short*)(w + 0);          // 33,554,432 B
  unsigned short* h0    = (unsigned short*)(w + 33554432);   // 16,777,216 B
  unsigned short* ycomb = (unsigned short*)(w + 33554432);   // same region, later
  float* Qc   = (float*)(w + 33554432);                      // pass1->mid
  unsigned short* xe    = (unsigned short*)(w + 50331648);   // 16,777,216 B
  float* Pc   = (float*)(w + 50331648);                      // aliases xe after xproj
  unsigned short* dbl2 = (unsigned short*)(w + 67108864);    // 4,194,304 B (bf16)
  unsigned short* wb = (unsigned short*)(w + 75497472);      // 524,288 B bf16 weights
  unsigned short* wb_in  = wb;
  unsigned short* wb_ex  = wb + 131072;
  unsigned short* wb_out = wb + 196608;
  unsigned short* u_arr  = (unsigned short*)(w + 76021760);  // 33,554,432 B (tier B)
  unsigned short* dt_arr = (unsigned short*)(w + 109576192); // 33,554,432 B (tier B)
  const bool big = ws_size >= 76021760ULL + 67108864ULL;     // 143,130,624
  unsigned short* h1 = big ? u_arr : xz;

  ln_norm<<<dim3(S_TOT / 4, 2), 256, 0, stream>>>(
      input0, input1, norm0_w, norm0_b, norm1_w, norm1_b, h0, h1,
      in_proj_w, in_proj_extra_w, outproj_w, wb);
  if (big) {
    gemm_in2<<<dim3(1024), 256, 0, stream>>>(h0, h1, wb_in, wb_ex, xz, xe);
  } else {
    gemm64<1, 0><<<dim3(4, 512), 256, 0, stream>>>(h1, DIM, wb_ex, xe, nullptr, 256);
    gemm64<1, 0><<<dim3(8, 512), 256, 0, stream>>>(h0, DIM, wb_in, xz, nullptr, 512);
  }
  xproj_mfma<<<dim3(512, 2), 256, 0, stream>>>(
      xe, conve_w, conve_b, conve_w_r, conve_b_r, xproj_w, xproj_w_r, dbl2);
  if (big) {
    dtu_compute<<<dim3(2048), 256, 0, stream>>>(
        dbl2, dtproj_w, dtproj_w_r, dtproj_b, dtproj_b_r, dt_arr,
        xz, convx_w, convx_b, convx_w_r, convx_b_r, u_arr);
    scan_pass1<1><<<dim3(NCH, 2, 2), 256, 0, stream>>>(
        xz, dbl2, u_arr, dt_arr, convx_w, convx_b, convx_w_r, convx_b_r,
        dtproj_w, dtproj_b, dtproj_w_r, dtproj_b_r, A_log, A_log_r, Pc, Qc);
  } else {
    scan_pass1<0><<<dim3(NCH, 2, 2), 256, 0, stream>>>(
        xz, dbl2, u_arr, dt_arr, convx_w, convx_b, convx_w_r, convx_b_r,
        dtproj_w, dtproj_b, dtproj_w_r, dtproj_b_r, A_log, A_log_r, Pc, Qc);
  }
  scan_mid<<<dim3(32), 256, 0, stream>>>(Pc, Qc);
  if (big) {
    scan_pass2<1><<<dim3(NCH, 2, 2), 256, 0, stream>>>(
        xz, dbl2, u_arr, dt_arr, convx_w, convx_b, convx_w_r, convx_b_r,
        dtproj_w, dtproj_b, dtproj_w_r, dtproj_b_r, A_log, A_log_r,
        Dp, Dp_r, Pc, ycomb, 0);
    // fused combine + LN*silu(z) + out_proj + residual, A-resident
    gemm_out3<<<dim3(512), 256, 0, stream>>>(
        ycomb, u_arr, xz, outnorm_w, outnorm_b, wb_out, (float*)d_out, input0);
  } else {
    for (int dir = 0; dir < 2; ++dir)
      scan_pass2<0><<<dim3(NCH, 2), 256, 0, stream>>>(
          xz, dbl2, u_arr, dt_arr, convx_w, convx_b, convx_w_r, convx_b_r,
          dtproj_w, dtproj_b, dtproj_w_r, dtproj_b_r, A_log, A_log_r,
          Dp, Dp_r, Pc, ycomb, dir);
    combine_ln<<<dim3(S_TOT / 4), 256, 0, stream>>>(ycomb, xz, outnorm_w, outnorm_b);
    gemm64<0, 1><<<dim3(4, 512), 256, 0, stream>>>(
        xz, 512, wb_out, d_out, input0, 256);
  }
}